// Round 3
// baseline (1346.293 us; speedup 1.0000x reference)
//
#include <hip/hip_runtime.h>
#include <hip/hip_bf16.h>

#define BB 16
#define NPG 512
#define CC 128
#define HH 8
#define LL 4
#define FFN 512
#define NCLS 4
#define DD 16
#define TT 513            // NPG + 1
#define EE 131072         // B * 8192
#define NNODES 8192       // B * NPG
#define ROWS (BB * TT)    // 8208 bias rows (g, dl)
#define ECAP 64           // entries per (g, key) row; Poisson(16), P(>64) ~ 1e-18

static constexpr size_t XROWS = (size_t)BB * TT;   // 8208
static constexpr size_t XSZ   = XROWS * CC;        // 1,050,624
static constexpr size_t MIDSZ = XROWS * FFN;       // 4,202,496

typedef unsigned short ushort_t;
typedef __attribute__((ext_vector_type(8))) short short8;
typedef __attribute__((ext_vector_type(4))) float floatx4;

__device__ __forceinline__ float gelu_exact(float v) {
    return 0.5f * v * (1.0f + erff(v * 0.70710678118654752440f));
}
__device__ __forceinline__ ushort_t f2bf(float f) {
    union { float f; unsigned u; } c; c.f = f;
    unsigned u = c.u;
    return (ushort_t)((u + 0x7FFFu + ((u >> 16) & 1u)) >> 16);   // RNE
}
__device__ __forceinline__ float dot4(float4 a, float4 b) {
    return a.x*b.x + a.y*b.y + a.z*b.z + a.w*b.w;
}
__device__ __forceinline__ void fma4(float4& o, float p, float4 v) {
    o.x = fmaf(p, v.x, o.x); o.y = fmaf(p, v.y, o.y);
    o.z = fmaf(p, v.z, o.z); o.w = fmaf(p, v.w, o.w);
}

// ---------------- degree count ----------------
__global__ __launch_bounds__(256) void deg_kernel(const int* __restrict__ ei,
                                                  int* __restrict__ deg_in,
                                                  int* __restrict__ deg_out) {
    int e = blockIdx.x * 256 + threadIdx.x;
    if (e >= EE) return;
    atomicAdd(&deg_out[ei[e]], 1);
    atomicAdd(&deg_in[ei[EE + e]], 1);
}

// ---------------- sparse-bias bucket build: rows keyed by (g, dl=key) ----------------
__global__ __launch_bounds__(256) void csr_kernel(const int* __restrict__ ei,
                                                  const int* __restrict__ ea,
                                                  int* __restrict__ cnt,
                                                  int* __restrict__ ebuf) {
    int e = blockIdx.x * 256 + threadIdx.x;
    if (e >= EE) return;
    int src = ei[e], dst = ei[EE + e];
    int g = src >> 9;
    int sl = src - (g << 9) + 1;     // query index
    int dl = dst - (g << 9) + 1;     // key index
    int a = ea[e];
    a = (a < 0) ? 0 : (a > 9 ? 9 : a);
    a += 1;                          // ebt row, 1..10
    int row = g * TT + dl;
    int pos = atomicAdd(&cnt[row], 1);
    if (pos < ECAP) ebuf[(size_t)row * ECAP + pos] = sl | (a << 16);
}

// ---------------- node encode + graph token ----------------
__global__ __launch_bounds__(256) void encode_kernel(const float* __restrict__ nf,
                                                     const float* __restrict__ Wn,
                                                     const float* __restrict__ bn,
                                                     const float* __restrict__ gt,
                                                     const float* __restrict__ ide,
                                                     const float* __restrict__ ode,
                                                     const int* __restrict__ deg_in,
                                                     const int* __restrict__ deg_out,
                                                     float* __restrict__ x) {
    int gid = blockIdx.x * 256 + threadIdx.x;
    if (gid >= (int)(XROWS * CC)) return;
    int c = gid & (CC - 1);
    int row = gid >> 7;
    int b = row / TT;
    int t = row - b * TT;
    float val;
    if (t == 0) {
        val = gt[c];
    } else {
        int i = b * NPG + t - 1;
        val = bn[c] + nf[i*3+0]*Wn[0*CC + c] + nf[i*3+1]*Wn[1*CC + c] + nf[i*3+2]*Wn[2*CC + c];
        int di = min(deg_in[i], 511);
        int dq = min(deg_out[i], 511);
        val += ide[(size_t)di * CC + c] + ode[(size_t)dq * CC + c];
    }
    x[(size_t)row * CC + c] = val;
}

// ---------------- weight transpose + bf16 convert: Wt[n][k] = W[k][n] ----------------
struct TrDesc {
    const float* src[24];
    ushort_t*    dst[24];
    int          K[24];
    int          N[24];
};
__global__ __launch_bounds__(256) void tr_kernel(TrDesc d) {
    int z = blockIdx.z;
    int K = d.K[z], N = d.N[z];
    int tot = K * N;
    const float* src = d.src[z];
    ushort_t* dst = d.dst[z];
    for (int i = blockIdx.x * 256 + threadIdx.x; i < tot; i += gridDim.x * 256) {
        int n = i / K, k = i - n * K;
        dst[i] = f2bf(src[(size_t)k * N + n]);
    }
}

// ---------------- LayerNorm (2 rows / 256-thread block), f32 in -> bf16 out ----------------
__global__ __launch_bounds__(256) void ln_kernel(const float* __restrict__ in,
                                                 ushort_t* __restrict__ out,
                                                 const float* __restrict__ gg,
                                                 const float* __restrict__ bb) {
    int tid = threadIdx.x;
    int r2 = tid >> 7;            // row within block: 0/1
    int c = tid & 127;
    int row = blockIdx.x * 2 + r2;
    float v = in[(size_t)row * CC + c];
    float s1 = v, s2 = v * v;
    #pragma unroll
    for (int m = 32; m >= 1; m >>= 1) {
        s1 += __shfl_xor(s1, m, 64);
        s2 += __shfl_xor(s2, m, 64);
    }
    __shared__ float red[8];      // [wave][2]
    int w = tid >> 6;
    if ((tid & 63) == 0) { red[w*2] = s1; red[w*2+1] = s2; }
    __syncthreads();
    int wb = r2 * 4;
    float S1 = red[wb] + red[wb+2], S2 = red[wb+1] + red[wb+3];
    float mn = S1 * (1.0f/CC);
    float var = S2 * (1.0f/CC) - mn * mn;
    float rs = rsqrtf(var + 1e-5f);
    out[(size_t)row * CC + c] = f2bf((v - mn) * rs * gg[c] + bb[c]);
}

// ---------------- MFMA bf16 GEMM: out = A[M,K](bf16) @ Wt[N,K]^T + bias ----------------
// Block 256 = 4 waves, block tile 128x128, wave tile 64x64 (16 x mfma_16x16x32).
// A frag: lane holds A[m0+(lane&15)][k0+quad*8 .. +7] (16B contiguous)
// B frag: lane holds Wt[n0+(lane&15)][k0+quad*8 .. +7] (16B contiguous)
// C/D: col=lane&15, row=quad*4+reg.
// mode: 0 = bias -> f32 out; 1 = bias + f32 residual -> f32 out; 2 = bias + gelu -> bf16 out
struct GP {
    const ushort_t* Wt[3];
    const float*    bias[3];
    float*          outF[3];
    ushort_t*       outB[3];
};
__global__ __launch_bounds__(256) void mfma_gemm(const ushort_t* __restrict__ A, GP p,
                                                 const float* __restrict__ res,
                                                 int M, int N, int K, int mode) {
    int z = blockIdx.z;
    const short* Wt = (const short*)p.Wt[z];
    const float* bias = p.bias[z];
    const short* Ab = (const short*)A;

    int wave = threadIdx.x >> 6, lane = threadIdx.x & 63;
    int lm = lane & 15, quad = lane >> 4;
    int m0 = blockIdx.y * 128 + (wave >> 1) * 64;
    int n0 = blockIdx.x * 128 + (wave & 1) * 64;

    int rA[4];
    #pragma unroll
    for (int mi = 0; mi < 4; ++mi) {
        int r = m0 + mi * 16 + lm;
        rA[mi] = r < M ? r : M - 1;
    }

    floatx4 acc[16];
    #pragma unroll
    for (int i = 0; i < 16; ++i) acc[i] = (floatx4){0.f, 0.f, 0.f, 0.f};

    #pragma unroll 2
    for (int k0 = 0; k0 < K; k0 += 32) {
        short8 af[4], bf[4];
        #pragma unroll
        for (int mi = 0; mi < 4; ++mi)
            af[mi] = *(const short8*)(Ab + (size_t)rA[mi] * K + k0 + quad * 8);
        #pragma unroll
        for (int ni = 0; ni < 4; ++ni)
            bf[ni] = *(const short8*)(Wt + (size_t)(n0 + ni * 16 + lm) * K + k0 + quad * 8);
        #pragma unroll
        for (int mi = 0; mi < 4; ++mi)
            #pragma unroll
            for (int ni = 0; ni < 4; ++ni)
                acc[mi*4+ni] = __builtin_amdgcn_mfma_f32_16x16x32_bf16(af[mi], bf[ni], acc[mi*4+ni], 0, 0, 0);
    }

    float* outF = p.outF[z];
    ushort_t* outB = p.outB[z];
    #pragma unroll
    for (int ni = 0; ni < 4; ++ni) {
        int c = n0 + ni * 16 + lm;
        float bv = bias[c];
        #pragma unroll
        for (int mi = 0; mi < 4; ++mi) {
            int rbase = m0 + mi * 16 + quad * 4;
            floatx4 a4 = acc[mi*4+ni];
            #pragma unroll
            for (int rg = 0; rg < 4; ++rg) {
                int r = rbase + rg;
                if (r >= M) continue;
                float v = a4[rg] + bv;
                if (mode == 1) v += res[(size_t)r * N + c];
                if (mode == 2) outB[(size_t)r * N + c] = f2bf(gelu_exact(v));
                else           outF[(size_t)r * N + c] = v;
            }
        }
    }
}

// ---------------- split-key fused attention w/ sparse bias ----------------
// Block 512 thr = 8 waves; grid (bh=128, qtile=9). Wave p handles keys s=p,p+8,...
// Lane = query (q0+lane). Per s: scatter this key-row's edge biases (avg ~2 hitting
// this q-tile) into a per-wave 64-slot LDS scratch (additive, exact for duplicate
// edges), add vnode bias analytically (uniform-over-s for q==0 cancels in softmax).
__global__ __launch_bounds__(512) void attn_kernel(const float* __restrict__ qb,
                                                   const float* __restrict__ kb,
                                                   const float* __restrict__ vb,
                                                   const int* __restrict__ cnt,
                                                   const int* __restrict__ ebuf,
                                                   const float* __restrict__ ebt,
                                                   const float* __restrict__ vnode,
                                                   ushort_t* __restrict__ ob) {
    int bh = blockIdx.x;
    int q0 = blockIdx.y * 64;
    int b = bh >> 3, h = bh & (HH - 1);
    int tid = threadIdx.x;
    int p = tid >> 6;          // wave / key-segment 0..7
    int lane = tid & 63;       // query within tile
    int q = q0 + lane;
    int qc = q < TT ? q : TT - 1;

    __shared__ float part[8 * 64 * 17];
    __shared__ float scratch[8][64];
    __shared__ float ebtab[88];
    __shared__ float lred[64];
    if (tid < 88) ebtab[tid] = ebt[tid];
    __syncthreads();

    const float4* qp = (const float4*)(qb + ((size_t)(b * TT + qc)) * CC + h * DD);
    float4 Q0 = qp[0], Q1 = qp[1], Q2 = qp[2], Q3 = qp[3];
    float vbh = vnode[h];

    const float* kbase = kb + (size_t)b * TT * CC + h * DD;
    const float* vbase = vb + (size_t)b * TT * CC + h * DD;
    const int* cbase = cnt + b * TT;
    const int* ebase = ebuf + (size_t)b * TT * ECAP;

    float4 o0 = make_float4(0,0,0,0), o1 = o0, o2 = o0, o3 = o0;
    float l = 0.0f;

    for (int s = p; s < TT; s += 8) {
        scratch[p][lane] = 0.0f;
        __builtin_amdgcn_wave_barrier();
        int cn = min(cbase[s], ECAP);
        if (lane < cn) {
            int e = ebase[(size_t)s * ECAP + lane];
            int sl = e & 0xFFFF, a = e >> 16;
            int loc = sl - q0;
            if (loc >= 0 && loc < 64) atomicAdd(&scratch[p][loc], ebtab[a * 8 + h]);
        }
        __builtin_amdgcn_wave_barrier();
        float bi = scratch[p][lane];
        if (s == 0 && q != 0) bi += vbh;   // q==0: uniform bias over s, cancels in softmax

        const float4* kp = (const float4*)(kbase + (size_t)s * CC);
        float sc = dot4(Q0, kp[0]) + dot4(Q1, kp[1]) + dot4(Q2, kp[2]) + dot4(Q3, kp[3]);
        float pr = __expf(fmaf(sc, 0.25f, bi));
        l += pr;
        const float4* vp = (const float4*)(vbase + (size_t)s * CC);
        fma4(o0, pr, vp[0]); fma4(o1, pr, vp[1]);
        fma4(o2, pr, vp[2]); fma4(o3, pr, vp[3]);
    }

    float* mp = &part[(p * 64 + lane) * 17];
    mp[0]=o0.x;  mp[1]=o0.y;  mp[2]=o0.z;  mp[3]=o0.w;
    mp[4]=o1.x;  mp[5]=o1.y;  mp[6]=o1.z;  mp[7]=o1.w;
    mp[8]=o2.x;  mp[9]=o2.y;  mp[10]=o2.z; mp[11]=o2.w;
    mp[12]=o3.x; mp[13]=o3.y; mp[14]=o3.z; mp[15]=o3.w;
    mp[16]=l;
    __syncthreads();

    int idx0 = tid, idx1 = tid + 512;
    int qa0 = idx0 >> 4, da0 = idx0 & 15;
    int qa1 = idx1 >> 4, da1 = idx1 & 15;
    float r0 = 0.0f, r1 = 0.0f;
    #pragma unroll
    for (int pp = 0; pp < 8; ++pp) {
        r0 += part[pp * 1088 + qa0 * 17 + da0];
        r1 += part[pp * 1088 + qa1 * 17 + da1];
    }
    if (tid < 64) {
        float ls = 0.0f;
        #pragma unroll
        for (int pp = 0; pp < 8; ++pp) ls += part[pp * 1088 + tid * 17 + 16];
        lred[tid] = 1.0f / ls;
    }
    __syncthreads();

    int qg0 = q0 + qa0;
    if (qg0 < TT) ob[((size_t)(b * TT + qg0)) * CC + h * DD + da0] = f2bf(r0 * lred[qa0]);
    int qg1 = q0 + qa1;
    if (qg1 < TT) ob[((size_t)(b * TT + qg1)) * CC + h * DD + da1] = f2bf(r1 * lred[qa1]);
}

// ---------------- final LN on graph tokens + classifier ----------------
__global__ __launch_bounds__(128) void head_kernel(const float* __restrict__ x,
                                                   const float* __restrict__ ng,
                                                   const float* __restrict__ nb,
                                                   const float* __restrict__ Wc1,
                                                   const float* __restrict__ bc1,
                                                   const float* __restrict__ Wc2,
                                                   const float* __restrict__ bc2,
                                                   float* __restrict__ out) {
    int b = blockIdx.x;
    int c = threadIdx.x;   // 128
    __shared__ float xfs[CC];
    __shared__ float c1s[64];
    __shared__ float red[4];

    float v = x[((size_t)b * TT) * CC + c];
    float s1 = v, s2 = v * v;
    #pragma unroll
    for (int m = 32; m >= 1; m >>= 1) {
        s1 += __shfl_xor(s1, m, 64);
        s2 += __shfl_xor(s2, m, 64);
    }
    int w = c >> 6;
    if ((c & 63) == 0) { red[w*2] = s1; red[w*2+1] = s2; }
    __syncthreads();
    float S1 = red[0] + red[2], S2 = red[1] + red[3];
    float mn = S1 * (1.0f/CC);
    float var = S2 * (1.0f/CC) - mn * mn;
    float rs = rsqrtf(var + 1e-5f);
    xfs[c] = (v - mn) * rs * ng[c] + nb[c];
    __syncthreads();
    if (c < 64) {
        float a = bc1[c];
        #pragma unroll 4
        for (int k = 0; k < CC; ++k) a = fmaf(xfs[k], Wc1[(size_t)k * 64 + c], a);
        c1s[c] = gelu_exact(a);
    }
    __syncthreads();
    if (c < NCLS) {
        float a = bc2[c];
        #pragma unroll 4
        for (int j = 0; j < 64; ++j) a = fmaf(c1s[j], Wc2[(size_t)j * NCLS + c], a);
        out[(size_t)b * NCLS + c] = a;
    }
}

extern "C" void kernel_launch(void* const* d_in, const int* in_sizes, int n_in,
                              void* d_out, int out_size, void* d_ws, size_t ws_size,
                              hipStream_t stream) {
    const float* node_feats = (const float*)d_in[0];
    const int*   edge_index = (const int*)d_in[1];
    const int*   edge_attr  = (const int*)d_in[2];
    const float* W_node  = (const float*)d_in[4];
    const float* b_node  = (const float*)d_in[5];
    const float* g_token = (const float*)d_in[6];
    const float* ebt     = (const float*)d_in[7];
    const float* ide     = (const float*)d_in[8];
    const float* ode     = (const float*)d_in[9];
    const float* vnode   = (const float*)d_in[10];
    const float* Wq = (const float*)d_in[11];
    const float* bq = (const float*)d_in[12];
    const float* Wk = (const float*)d_in[13];
    const float* bk = (const float*)d_in[14];
    const float* Wv = (const float*)d_in[15];
    const float* bv = (const float*)d_in[16];
    const float* Wo = (const float*)d_in[17];
    const float* bo = (const float*)d_in[18];
    const float* ln1g = (const float*)d_in[19];
    const float* ln1b = (const float*)d_in[20];
    const float* ln2g = (const float*)d_in[21];
    const float* ln2b = (const float*)d_in[22];
    const float* W1 = (const float*)d_in[23];
    const float* b1 = (const float*)d_in[24];
    const float* W2 = (const float*)d_in[25];
    const float* b2 = (const float*)d_in[26];
    const float* nfg = (const float*)d_in[27];
    const float* nfb = (const float*)d_in[28];
    const float* Wc1 = (const float*)d_in[29];
    const float* bc1 = (const float*)d_in[30];
    const float* Wc2 = (const float*)d_in[31];
    const float* bc2 = (const float*)d_in[32];
    float* out = (float*)d_out;

    // ---- workspace layout (byte-based, all chunks 16B-aligned) ----
    char* base = (char*)d_ws;
    float* x   = (float*)base;            base += XSZ * 4;
    float* qb  = (float*)base;            base += XSZ * 4;
    float* kb  = (float*)base;            base += XSZ * 4;
    float* vb_ = (float*)base;            base += XSZ * 4;
    ushort_t* hbf = (ushort_t*)base;      base += XSZ * 2;
    ushort_t* obf = (ushort_t*)base;      base += XSZ * 2;
    ushort_t* mid = (ushort_t*)base;      base += MIDSZ * 2;
    ushort_t* wtqkvo = (ushort_t*)base;   base += (size_t)16 * 16384 * 2;
    ushort_t* wt1 = (ushort_t*)base;      base += (size_t)4 * 65536 * 2;
    ushort_t* wt2 = (ushort_t*)base;      base += (size_t)4 * 65536 * 2;
    int* deg_in  = (int*)base;            base += NNODES * 4;
    int* deg_out = (int*)base;            base += NNODES * 4;
    int* cnt     = (int*)base;            base += ROWS * 4;
    int* ebuf    = (int*)base;            base += (size_t)ROWS * ECAP * 4;

    // zero deg_in + deg_out + cnt in one shot (contiguous)
    hipMemsetAsync(deg_in, 0, (size_t)(2 * NNODES + ROWS) * 4, stream);

    deg_kernel<<<EE / 256, 256, 0, stream>>>(edge_index, deg_in, deg_out);
    csr_kernel<<<EE / 256, 256, 0, stream>>>(edge_index, edge_attr, cnt, ebuf);
    encode_kernel<<<(int)((XROWS * CC + 255) / 256), 256, 0, stream>>>(
        node_feats, W_node, b_node, g_token, ide, ode, deg_in, deg_out, x);

    // weight transpose+convert: 24 matrices in one launch
    TrDesc td;
    for (int l = 0; l < LL; ++l) {
        const float* srcs[4] = {Wq + (size_t)l*CC*CC, Wk + (size_t)l*CC*CC,
                                Wv + (size_t)l*CC*CC, Wo + (size_t)l*CC*CC};
        for (int k = 0; k < 4; ++k) {
            int slot = k * 4 + l;
            td.src[slot] = srcs[k];
            td.dst[slot] = wtqkvo + (size_t)slot * 16384;
            td.K[slot] = CC; td.N[slot] = CC;
        }
        td.src[16 + l] = W1 + (size_t)l*CC*FFN;
        td.dst[16 + l] = wt1 + (size_t)l*65536;
        td.K[16 + l] = CC; td.N[16 + l] = FFN;
        td.src[20 + l] = W2 + (size_t)l*FFN*CC;
        td.dst[20 + l] = wt2 + (size_t)l*65536;
        td.K[20 + l] = FFN; td.N[20 + l] = CC;
    }
    tr_kernel<<<dim3(32, 1, 24), 256, 0, stream>>>(td);

    const int GMY = (int)((XROWS + 127) / 128);   // 65

    for (int l = 0; l < LL; ++l) {
        ln_kernel<<<(int)(XROWS / 2), 256, 0, stream>>>(x, hbf, ln1g + l*CC, ln1b + l*CC);

        GP pq = {};
        pq.Wt[0] = wtqkvo + (size_t)(0*4+l)*16384;
        pq.Wt[1] = wtqkvo + (size_t)(1*4+l)*16384;
        pq.Wt[2] = wtqkvo + (size_t)(2*4+l)*16384;
        pq.bias[0] = bq + l*CC; pq.bias[1] = bk + l*CC; pq.bias[2] = bv + l*CC;
        pq.outF[0] = qb; pq.outF[1] = kb; pq.outF[2] = vb_;
        mfma_gemm<<<dim3(1, GMY, 3), 256, 0, stream>>>(hbf, pq, nullptr, (int)XROWS, CC, CC, 0);

        attn_kernel<<<dim3(BB*HH, (TT + 63) / 64), 512, 0, stream>>>(
            qb, kb, vb_, cnt, ebuf, ebt, vnode, obf);

        GP po = {};
        po.Wt[0] = wtqkvo + (size_t)(3*4+l)*16384;
        po.bias[0] = bo + l*CC; po.outF[0] = x;
        mfma_gemm<<<dim3(1, GMY, 1), 256, 0, stream>>>(obf, po, x, (int)XROWS, CC, CC, 1);

        ln_kernel<<<(int)(XROWS / 2), 256, 0, stream>>>(x, hbf, ln2g + l*CC, ln2b + l*CC);

        GP p1 = {};
        p1.Wt[0] = wt1 + (size_t)l*65536;
        p1.bias[0] = b1 + l*FFN; p1.outB[0] = mid;
        mfma_gemm<<<dim3(4, GMY, 1), 256, 0, stream>>>(hbf, p1, nullptr, (int)XROWS, FFN, CC, 2);

        GP p2 = {};
        p2.Wt[0] = wt2 + (size_t)l*65536;
        p2.bias[0] = b2 + l*CC; p2.outF[0] = x;
        mfma_gemm<<<dim3(1, GMY, 1), 256, 0, stream>>>(mid, p2, x, (int)XROWS, CC, FFN, 1);
    }

    head_kernel<<<BB, 128, 0, stream>>>(x, nfg, nfb, Wc1, bc1, Wc2, bc2, out);
}

// Round 4
// 833.221 us; speedup vs baseline: 1.6158x; 1.6158x over previous
//
#include <hip/hip_runtime.h>
#include <hip/hip_bf16.h>

#define BB 16
#define NPG 512
#define CC 128
#define HH 8
#define LL 4
#define FFN 512
#define NCLS 4
#define DD 16
#define TT 513            // NPG + 1
#define EE 131072         // B * 8192
#define NNODES 8192       // B * NPG
#define ROWS (BB * TT)    // 8208 CSR rows keyed by (g, sl=query)
#define ECAP 64           // entries per bucket; Poisson(16), P(>=64) ~ 3e-22

static constexpr size_t XROWS = (size_t)BB * TT;   // 8208
static constexpr size_t XSZ   = XROWS * CC;        // 1,050,624
static constexpr size_t MIDSZ = XROWS * FFN;       // 4,202,496

typedef unsigned short ushort_t;
typedef __attribute__((ext_vector_type(8))) short short8;
typedef __attribute__((ext_vector_type(4))) short short4v;
typedef __attribute__((ext_vector_type(4))) float floatx4;

__device__ __forceinline__ float gelu_exact(float v) {
    return 0.5f * v * (1.0f + erff(v * 0.70710678118654752440f));
}
__device__ __forceinline__ ushort_t f2bf(float f) {
    union { float f; unsigned u; } c; c.f = f;
    unsigned u = c.u;
    return (ushort_t)((u + 0x7FFFu + ((u >> 16) & 1u)) >> 16);   // RNE
}

// ---------------- degree count + query-keyed CSR build (merged) ----------------
__global__ __launch_bounds__(256) void deg_csr_kernel(const int* __restrict__ ei,
                                                      const int* __restrict__ ea,
                                                      int* __restrict__ deg_in,
                                                      int* __restrict__ deg_out,
                                                      int* __restrict__ cnt,
                                                      int* __restrict__ ebuf) {
    int e = blockIdx.x * 256 + threadIdx.x;
    if (e >= EE) return;
    int src = ei[e], dst = ei[EE + e];
    atomicAdd(&deg_out[src], 1);
    atomicAdd(&deg_in[dst], 1);
    int g = src >> 9;
    int sl = src - (g << 9) + 1;     // query index 1..512
    int dl = dst - (g << 9) + 1;     // key   index 1..512
    int a = ea[e];
    a = (a < 0) ? 0 : (a > 9 ? 9 : a);
    a += 1;                          // ebt row 1..10
    int row = g * TT + sl;           // query-keyed bucket
    int pos = atomicAdd(&cnt[row], 1);
    if (pos < ECAP) ebuf[(size_t)row * ECAP + pos] = dl | (a << 16);
}

// ---------------- node encode + graph token ----------------
__global__ __launch_bounds__(256) void encode_kernel(const float* __restrict__ nf,
                                                     const float* __restrict__ Wn,
                                                     const float* __restrict__ bn,
                                                     const float* __restrict__ gt,
                                                     const float* __restrict__ ide,
                                                     const float* __restrict__ ode,
                                                     const int* __restrict__ deg_in,
                                                     const int* __restrict__ deg_out,
                                                     float* __restrict__ x) {
    int gid = blockIdx.x * 256 + threadIdx.x;
    if (gid >= (int)(XROWS * CC)) return;
    int c = gid & (CC - 1);
    int row = gid >> 7;
    int b = row / TT;
    int t = row - b * TT;
    float val;
    if (t == 0) {
        val = gt[c];
    } else {
        int i = b * NPG + t - 1;
        val = bn[c] + nf[i*3+0]*Wn[0*CC + c] + nf[i*3+1]*Wn[1*CC + c] + nf[i*3+2]*Wn[2*CC + c];
        int di = min(deg_in[i], 511);
        int dq = min(deg_out[i], 511);
        val += ide[(size_t)di * CC + c] + ode[(size_t)dq * CC + c];
    }
    x[(size_t)row * CC + c] = val;
}

// ---------------- weight transpose + bf16 convert: Wt[n][k] = W[k][n] ----------------
struct TrDesc {
    const float* src[24];
    ushort_t*    dst[24];
    int          K[24];
    int          N[24];
};
__global__ __launch_bounds__(256) void tr_kernel(TrDesc d) {
    int z = blockIdx.z;
    int K = d.K[z], N = d.N[z];
    int tot = K * N;
    const float* src = d.src[z];
    ushort_t* dst = d.dst[z];
    for (int i = blockIdx.x * 256 + threadIdx.x; i < tot; i += gridDim.x * 256) {
        int n = i / K, k = i - n * K;
        dst[i] = f2bf(src[(size_t)k * N + n]);
    }
}

// ---------------- LayerNorm (2 rows / 256-thread block), f32 in -> bf16 out ----------------
__global__ __launch_bounds__(256) void ln_kernel(const float* __restrict__ in,
                                                 ushort_t* __restrict__ out,
                                                 const float* __restrict__ gg,
                                                 const float* __restrict__ bb) {
    int tid = threadIdx.x;
    int r2 = tid >> 7;
    int c = tid & 127;
    int row = blockIdx.x * 2 + r2;
    float v = in[(size_t)row * CC + c];
    float s1 = v, s2 = v * v;
    #pragma unroll
    for (int m = 32; m >= 1; m >>= 1) {
        s1 += __shfl_xor(s1, m, 64);
        s2 += __shfl_xor(s2, m, 64);
    }
    __shared__ float red[8];
    int w = tid >> 6;
    if ((tid & 63) == 0) { red[w*2] = s1; red[w*2+1] = s2; }
    __syncthreads();
    int wb = r2 * 4;
    float S1 = red[wb] + red[wb+2], S2 = red[wb+1] + red[wb+3];
    float mn = S1 * (1.0f/CC);
    float var = S2 * (1.0f/CC) - mn * mn;
    float rs = rsqrtf(var + 1e-5f);
    out[(size_t)row * CC + c] = f2bf((v - mn) * rs * gg[c] + bb[c]);
}

// ---------------- per-wave 32x64-tile MFMA bf16 GEMM ----------------
// Each wave owns an independent 32(m) x 64(n) tile; 256-thr blocks = 4 waves.
// A[M,K] bf16 row-major; Wt[N,K] bf16 (pre-transposed).
// mode: 0 = (acc+bias)*scl -> bf16 ; 1 = acc+bias+res -> f32 ; 2 = gelu(acc+bias) -> bf16
struct GP {
    const ushort_t* Wt[3];
    const float*    bias[3];
    float*          outF[3];
    ushort_t*       outB[3];
    float           scl[3];
};
__global__ __launch_bounds__(256) void gemm_wave(const ushort_t* __restrict__ A, GP p,
                                                 const float* __restrict__ res,
                                                 int M, int N, int K, int mode,
                                                 int mtiles, int ntiles) {
    int z = blockIdx.z;
    int wid = blockIdx.x * 4 + (threadIdx.x >> 6);
    if (wid >= mtiles * ntiles) return;
    int tm = wid / ntiles, tn = wid - tm * ntiles;
    int m0 = tm * 32, n0 = tn * 64;
    int lane = threadIdx.x & 63, lq = lane & 15, quad = lane >> 4;
    const short* Wt = (const short*)p.Wt[z];
    const short* Ab = (const short*)A;
    const float* bias = p.bias[z];

    size_t rA[2];
    #pragma unroll
    for (int mi = 0; mi < 2; ++mi) {
        int r = m0 + mi * 16 + lq;
        rA[mi] = (size_t)(r < M ? r : M - 1) * K;
    }
    floatx4 acc[8];
    #pragma unroll
    for (int i = 0; i < 8; ++i) acc[i] = (floatx4){0.f, 0.f, 0.f, 0.f};

    for (int k0 = 0; k0 < K; k0 += 32) {
        short8 af[2], bf[4];
        #pragma unroll
        for (int mi = 0; mi < 2; ++mi)
            af[mi] = *(const short8*)(Ab + rA[mi] + k0 + quad * 8);
        #pragma unroll
        for (int ni = 0; ni < 4; ++ni)
            bf[ni] = *(const short8*)(Wt + (size_t)(n0 + ni * 16 + lq) * K + k0 + quad * 8);
        #pragma unroll
        for (int mi = 0; mi < 2; ++mi)
            #pragma unroll
            for (int ni = 0; ni < 4; ++ni)
                acc[mi*4+ni] = __builtin_amdgcn_mfma_f32_16x16x32_bf16(af[mi], bf[ni], acc[mi*4+ni], 0, 0, 0);
    }

    float scl = p.scl[z];
    float* outF = p.outF[z];
    ushort_t* outB = p.outB[z];
    #pragma unroll
    for (int ni = 0; ni < 4; ++ni) {
        int c = n0 + ni * 16 + lq;
        float bv = bias[c];
        #pragma unroll
        for (int mi = 0; mi < 2; ++mi) {
            #pragma unroll
            for (int rg = 0; rg < 4; ++rg) {
                int r = m0 + mi * 16 + quad * 4 + rg;
                if (r >= M) continue;
                float v = acc[mi*4+ni][rg] + bv;
                if (mode == 0)      outB[(size_t)r * N + c] = f2bf(v * scl);
                else if (mode == 1) outF[(size_t)r * N + c] = v + res[(size_t)r * N + c];
                else                outB[(size_t)r * N + c] = f2bf(gelu_exact(v));
            }
        }
    }
}

// ---------------- MFMA fused attention ----------------
// Block = (bh, q-half); 256 thr = 4 waves. K rows + V^T staged in LDS (bf16,
// zero-padded to 544 rows). Per 16-query tile: dense f32 bias strip built in
// LDS in 2 s-chunks (zero + scatter from query-keyed CSR), then waves split
// the 17 s-pairs (32 keys each): S^T = mfma(K-frag, Q-frag) with d padded
// 16->32; bias+exp+mask in f32; P packed bf16 through per-wave LDS (C-layout
// -> A-layout transform); O^T += mfma(V^T-frag, P^T-frag) full K=32.
// Q pre-scaled by 0.25 at the QKV epilogue (exact). Cross-wave reduce via LDS.
__global__ __launch_bounds__(256) void attn_kernel(const ushort_t* __restrict__ qb,
                                                   const ushort_t* __restrict__ kb,
                                                   const ushort_t* __restrict__ vb,
                                                   const int* __restrict__ cnt,
                                                   const int* __restrict__ ebuf,
                                                   const float* __restrict__ ebt,
                                                   const float* __restrict__ vnode,
                                                   ushort_t* __restrict__ ob) {
    int bh = blockIdx.x;
    int b = bh >> 3, h = bh & (HH - 1);
    int qhalf = blockIdx.y;
    int tid = threadIdx.x;
    int wave = tid >> 6, lane = tid & 63, lq = lane & 15, quad = lane >> 4;

    __shared__ ushort_t Ks[544 * 20];     // [s][d0..15], stride 20 (40B), rows>=513 zero
    __shared__ ushort_t Vt[16 * 552];     // [d][s], stride 552 (16B-mult), cols>=513 zero
    __shared__ float bstrip[288 * 16];    // [s - chunk_lo][qloc]
    __shared__ float pool[1280];          // per-wave 1280B: Pb (bf16 16x40) U red (f32 16x17)
    __shared__ float lred2[64];
    __shared__ float ebtab[88];

    if (tid < 88) ebtab[tid] = ebt[tid];
    float vbh = vnode[h];

    // ---- stage K and V^T ----
    const ushort_t* kbase = kb + (size_t)(b * TT) * CC + h * DD;
    const ushort_t* vbase = vb + (size_t)(b * TT) * CC + h * DD;
    for (int i = tid; i < 544 * 2; i += 256) {
        int r = i >> 1, half = i & 1;
        short8 kv = {0,0,0,0,0,0,0,0};
        short8 vv = {0,0,0,0,0,0,0,0};
        if (r < TT) {
            kv = *(const short8*)(kbase + (size_t)r * CC + half * 8);
            vv = *(const short8*)(vbase + (size_t)r * CC + half * 8);
        }
        short4v klo = __builtin_shufflevector(kv, kv, 0, 1, 2, 3);
        short4v khi = __builtin_shufflevector(kv, kv, 4, 5, 6, 7);
        *(short4v*)(Ks + r * 20 + half * 8)     = klo;
        *(short4v*)(Ks + r * 20 + half * 8 + 4) = khi;
        #pragma unroll
        for (int j = 0; j < 8; ++j)
            Vt[(half * 8 + j) * 552 + r] = (ushort_t)vv[j];
    }
    __syncthreads();

    ushort_t* Pbw = (ushort_t*)(pool + wave * 320);   // 16 rows x 40 bf16 (b128-aligned)
    float*    redw = pool + wave * 320;               // 16 d x 17 q f32 (aliased, used after)

    int qt0 = qhalf ? 17 : 0;
    int qt1 = qhalf ? 33 : 17;
    for (int qt = qt0; qt < qt1; ++qt) {
        // Q fragment (B-operand): lane holds Q[q0+lq][d = quad*8..+7], quads 2,3 zero
        int qg = qt * 16 + lq;
        int qr = qg < TT ? qg : TT - 1;
        short8 qf = {0,0,0,0,0,0,0,0};
        if (quad < 2)
            qf = *(const short8*)(qb + ((size_t)(b * TT + qr)) * CC + h * DD + quad * 8);

        floatx4 oacc = {0.f, 0.f, 0.f, 0.f};
        float lsum = 0.f;

        #pragma unroll
        for (int ch = 0; ch < 2; ++ch) {
            int slo = ch ? 288 : 0;
            int spl = ch ? 9 : 0;
            int sph = ch ? 17 : 9;
            int nrows = ch ? 256 : 288;
            // zero strip (+ vnode bias on s==0 row, chunk 0 only; q==0 skipped: uniform)
            for (int i = tid; i < 288 * 16; i += 256) {
                float v = 0.f;
                if (ch == 0 && i < 16) {
                    int q = qt * 16 + i;
                    if (q > 0 && q < TT) v = vbh;
                }
                bstrip[i] = v;
            }
            __syncthreads();
            // scatter this q-tile's edges falling in [slo, slo+nrows)
            {
                int ql = tid >> 4, s0 = tid & 15;
                int q = qt * 16 + ql;
                if (q > 0 && q < TT) {
                    int row = b * TT + q;
                    int cn = min(cnt[row], ECAP);
                    for (int sl = s0; sl < cn; sl += 16) {
                        int e = ebuf[(size_t)row * ECAP + sl];
                        int dl = e & 0xFFFF, a = e >> 16;
                        int loc = dl - slo;
                        if (loc >= 0 && loc < nrows)
                            atomicAdd(&bstrip[loc * 16 + ql], ebtab[a * 8 + h]);
                    }
                }
            }
            __syncthreads();
            // compute: waves split s-pairs of this chunk
            for (int sp = spl + wave; sp < sph; sp += 4) {
                #pragma unroll
                for (int t = 0; t < 2; ++t) {
                    int st = sp * 2 + t;
                    short8 af = {0,0,0,0,0,0,0,0};
                    if (quad < 2) {
                        const ushort_t* kp = Ks + (st * 16 + lq) * 20 + quad * 8;
                        short4v lo = *(const short4v*)kp;
                        short4v hi = *(const short4v*)(kp + 4);
                        af = __builtin_shufflevector(lo, hi, 0, 1, 2, 3, 4, 5, 6, 7);
                    }
                    floatx4 c = __builtin_amdgcn_mfma_f32_16x16x32_bf16(
                        af, qf, (floatx4){0.f, 0.f, 0.f, 0.f}, 0, 0, 0);
                    float pr[4];
                    #pragma unroll
                    for (int rg = 0; rg < 4; ++rg) {
                        int s = st * 16 + quad * 4 + rg;
                        float bi = bstrip[(s - slo) * 16 + lq];
                        float p = (s < TT) ? __expf(c[rg] + bi) : 0.f;
                        lsum += p;
                        pr[rg] = p;
                    }
                    unsigned* pw = (unsigned*)(Pbw + lq * 40 + t * 16 + quad * 4);
                    pw[0] = (unsigned)f2bf(pr[0]) | ((unsigned)f2bf(pr[1]) << 16);
                    pw[1] = (unsigned)f2bf(pr[2]) | ((unsigned)f2bf(pr[3]) << 16);
                }
                short8 vf = *(const short8*)(Vt + lq * 552 + sp * 32 + quad * 8);
                short8 pf = *(const short8*)(Pbw + lq * 40 + quad * 8);
                oacc = __builtin_amdgcn_mfma_f32_16x16x32_bf16(vf, pf, oacc, 0, 0, 0);
            }
            __syncthreads();
        }

        // reduce l across quads (lanes sharing lq)
        lsum += __shfl_xor(lsum, 16, 64);
        lsum += __shfl_xor(lsum, 32, 64);
        #pragma unroll
        for (int rg = 0; rg < 4; ++rg)
            redw[(quad * 4 + rg) * 17 + lq] = oacc[rg];
        if (quad == 0) lred2[wave * 16 + lq] = lsum;
        __syncthreads();
        // cross-wave combine + store
        {
            int q = tid & 15, d = tid >> 4;
            float o = 0.f, L = 0.f;
            #pragma unroll
            for (int w = 0; w < 4; ++w) {
                o += (pool + w * 320)[d * 17 + q];
                L += lred2[w * 16 + q];
            }
            int qq = qt * 16 + q;
            if (qq < TT)
                ob[((size_t)(b * TT + qq)) * CC + h * DD + d] = f2bf(o / L);
        }
        __syncthreads();
    }
}

// ---------------- final LN on graph tokens + classifier ----------------
__global__ __launch_bounds__(128) void head_kernel(const float* __restrict__ x,
                                                   const float* __restrict__ ng,
                                                   const float* __restrict__ nb,
                                                   const float* __restrict__ Wc1,
                                                   const float* __restrict__ bc1,
                                                   const float* __restrict__ Wc2,
                                                   const float* __restrict__ bc2,
                                                   float* __restrict__ out) {
    int b = blockIdx.x;
    int c = threadIdx.x;
    __shared__ float xfs[CC];
    __shared__ float c1s[64];
    __shared__ float red[4];

    float v = x[((size_t)b * TT) * CC + c];
    float s1 = v, s2 = v * v;
    #pragma unroll
    for (int m = 32; m >= 1; m >>= 1) {
        s1 += __shfl_xor(s1, m, 64);
        s2 += __shfl_xor(s2, m, 64);
    }
    int w = c >> 6;
    if ((c & 63) == 0) { red[w*2] = s1; red[w*2+1] = s2; }
    __syncthreads();
    float S1 = red[0] + red[2], S2 = red[1] + red[3];
    float mn = S1 * (1.0f/CC);
    float var = S2 * (1.0f/CC) - mn * mn;
    float rs = rsqrtf(var + 1e-5f);
    xfs[c] = (v - mn) * rs * ng[c] + nb[c];
    __syncthreads();
    if (c < 64) {
        float a = bc1[c];
        #pragma unroll 4
        for (int k = 0; k < CC; ++k) a = fmaf(xfs[k], Wc1[(size_t)k * 64 + c], a);
        c1s[c] = gelu_exact(a);
    }
    __syncthreads();
    if (c < NCLS) {
        float a = bc2[c];
        #pragma unroll 4
        for (int j = 0; j < 64; ++j) a = fmaf(c1s[j], Wc2[(size_t)j * NCLS + c], a);
        out[(size_t)b * NCLS + c] = a;
    }
}

extern "C" void kernel_launch(void* const* d_in, const int* in_sizes, int n_in,
                              void* d_out, int out_size, void* d_ws, size_t ws_size,
                              hipStream_t stream) {
    const float* node_feats = (const float*)d_in[0];
    const int*   edge_index = (const int*)d_in[1];
    const int*   edge_attr  = (const int*)d_in[2];
    const float* W_node  = (const float*)d_in[4];
    const float* b_node  = (const float*)d_in[5];
    const float* g_token = (const float*)d_in[6];
    const float* ebt     = (const float*)d_in[7];
    const float* ide     = (const float*)d_in[8];
    const float* ode     = (const float*)d_in[9];
    const float* vnode   = (const float*)d_in[10];
    const float* Wq = (const float*)d_in[11];
    const float* bq = (const float*)d_in[12];
    const float* Wk = (const float*)d_in[13];
    const float* bk = (const float*)d_in[14];
    const float* Wv = (const float*)d_in[15];
    const float* bv = (const float*)d_in[16];
    const float* Wo = (const float*)d_in[17];
    const float* bo = (const float*)d_in[18];
    const float* ln1g = (const float*)d_in[19];
    const float* ln1b = (const float*)d_in[20];
    const float* ln2g = (const float*)d_in[21];
    const float* ln2b = (const float*)d_in[22];
    const float* W1 = (const float*)d_in[23];
    const float* b1 = (const float*)d_in[24];
    const float* W2 = (const float*)d_in[25];
    const float* b2 = (const float*)d_in[26];
    const float* nfg = (const float*)d_in[27];
    const float* nfb = (const float*)d_in[28];
    const float* Wc1 = (const float*)d_in[29];
    const float* bc1 = (const float*)d_in[30];
    const float* Wc2 = (const float*)d_in[31];
    const float* bc2 = (const float*)d_in[32];
    float* out = (float*)d_out;

    // ---- workspace (all chunks 16B-aligned) ----
    char* base = (char*)d_ws;
    float* x      = (float*)base;     base += XSZ * 4;
    ushort_t* hbf = (ushort_t*)base;  base += XSZ * 2;
    ushort_t* qb  = (ushort_t*)base;  base += XSZ * 2;
    ushort_t* kb  = (ushort_t*)base;  base += XSZ * 2;
    ushort_t* vb_ = (ushort_t*)base;  base += XSZ * 2;
    ushort_t* obf = (ushort_t*)base;  base += XSZ * 2;
    ushort_t* mid = (ushort_t*)base;  base += MIDSZ * 2;
    ushort_t* wtqkvo = (ushort_t*)base; base += (size_t)16 * 16384 * 2;
    ushort_t* wt1 = (ushort_t*)base;  base += (size_t)4 * 65536 * 2;
    ushort_t* wt2 = (ushort_t*)base;  base += (size_t)4 * 65536 * 2;
    int* deg_in  = (int*)base;        base += NNODES * 4;
    int* deg_out = (int*)base;        base += NNODES * 4;
    int* cnt     = (int*)base;        base += (size_t)ROWS * 4;
    int* ebuf    = (int*)base;        base += (size_t)ROWS * ECAP * 4;

    hipMemsetAsync(deg_in, 0, (size_t)(2 * NNODES + ROWS) * 4, stream);
    deg_csr_kernel<<<EE / 256, 256, 0, stream>>>(edge_index, edge_attr,
                                                 deg_in, deg_out, cnt, ebuf);
    encode_kernel<<<(int)((XROWS * CC + 255) / 256), 256, 0, stream>>>(
        node_feats, W_node, b_node, g_token, ide, ode, deg_in, deg_out, x);

    TrDesc td;
    for (int l = 0; l < LL; ++l) {
        const float* srcs[4] = {Wq + (size_t)l*CC*CC, Wk + (size_t)l*CC*CC,
                                Wv + (size_t)l*CC*CC, Wo + (size_t)l*CC*CC};
        for (int k = 0; k < 4; ++k) {
            int slot = k * 4 + l;
            td.src[slot] = srcs[k];
            td.dst[slot] = wtqkvo + (size_t)slot * 16384;
            td.K[slot] = CC; td.N[slot] = CC;
        }
        td.src[16 + l] = W1 + (size_t)l*CC*FFN;
        td.dst[16 + l] = wt1 + (size_t)l*65536;
        td.K[16 + l] = CC; td.N[16 + l] = FFN;
        td.src[20 + l] = W2 + (size_t)l*FFN*CC;
        td.dst[20 + l] = wt2 + (size_t)l*65536;
        td.K[20 + l] = FFN; td.N[20 + l] = CC;
    }
    tr_kernel<<<dim3(32, 1, 24), 256, 0, stream>>>(td);

    const int MT = (int)((XROWS + 31) / 32);   // 257 m-tiles of 32 rows

    for (int l = 0; l < LL; ++l) {
        ln_kernel<<<(int)(XROWS / 2), 256, 0, stream>>>(x, hbf, ln1g + l*CC, ln1b + l*CC);

        GP pq = {};
        pq.Wt[0] = wtqkvo + (size_t)(0*4+l)*16384;
        pq.Wt[1] = wtqkvo + (size_t)(1*4+l)*16384;
        pq.Wt[2] = wtqkvo + (size_t)(2*4+l)*16384;
        pq.bias[0] = bq + l*CC; pq.bias[1] = bk + l*CC; pq.bias[2] = bv + l*CC;
        pq.outB[0] = qb; pq.outB[1] = kb; pq.outB[2] = vb_;
        pq.scl[0] = 0.25f; pq.scl[1] = 1.0f; pq.scl[2] = 1.0f;   // fold 1/sqrt(D) into Q (exact)
        gemm_wave<<<dim3((MT*2 + 3)/4, 1, 3), 256, 0, stream>>>(
            hbf, pq, nullptr, (int)XROWS, CC, CC, 0, MT, 2);

        attn_kernel<<<dim3(BB*HH, 2), 256, 0, stream>>>(
            qb, kb, vb_, cnt, ebuf, ebt, vnode, obf);

        GP po = {};
        po.Wt[0] = wtqkvo + (size_t)(3*4+l)*16384;
        po.bias[0] = bo + l*CC; po.outF[0] = x; po.scl[0] = 1.0f;
        gemm_wave<<<dim3((MT*2 + 3)/4, 1, 1), 256, 0, stream>>>(
            obf, po, x, (int)XROWS, CC, CC, 1, MT, 2);

        ln_kernel<<<(int)(XROWS / 2), 256, 0, stream>>>(x, hbf, ln2g + l*CC, ln2b + l*CC);

        GP p1 = {};
        p1.Wt[0] = wt1 + (size_t)l*65536;
        p1.bias[0] = b1 + l*FFN; p1.outB[0] = mid; p1.scl[0] = 1.0f;
        gemm_wave<<<dim3((MT*8 + 3)/4, 1, 1), 256, 0, stream>>>(
            hbf, p1, nullptr, (int)XROWS, FFN, CC, 2, MT, 8);

        GP p2 = {};
        p2.Wt[0] = wt2 + (size_t)l*65536;
        p2.bias[0] = b2 + l*CC; p2.outF[0] = x; p2.scl[0] = 1.0f;
        gemm_wave<<<dim3((MT*2 + 3)/4, 1, 1), 256, 0, stream>>>(
            mid, p2, x, (int)XROWS, CC, FFN, 1, MT, 2);
    }

    head_kernel<<<BB, 128, 0, stream>>>(x, nfg, nfb, Wc1, bc1, Wc2, bc2, out);
}

// Round 5
// 659.113 us; speedup vs baseline: 2.0426x; 1.2642x over previous
//
#include <hip/hip_runtime.h>
#include <hip/hip_bf16.h>

#define BB 16
#define NPG 512
#define CC 128
#define HH 8
#define LL 4
#define FFN 512
#define NCLS 4
#define DD 16
#define TT 513            // NPG + 1
#define EE 131072         // B * 8192
#define NNODES 8192       // B * NPG
#define ROWS (BB * TT)    // 8208 CSR rows keyed by (g, sl=query)
#define ECAP 64           // entries per bucket; Poisson(16), P(>=64) ~ 3e-22
#define SP 544            // padded s extent (34 tiles of 16)

static constexpr size_t XROWS = (size_t)BB * TT;   // 8208
static constexpr size_t XSZ   = XROWS * CC;        // 1,050,624
static constexpr size_t MIDSZ = XROWS * FFN;       // 4,202,496
static constexpr size_t VTSZ  = (size_t)BB * HH * DD * SP;  // 1,114,112

typedef unsigned short ushort_t;
typedef __attribute__((ext_vector_type(8))) short short8;
typedef __attribute__((ext_vector_type(4))) float floatx4;

__device__ __forceinline__ float gelu_exact(float v) {
    return 0.5f * v * (1.0f + erff(v * 0.70710678118654752440f));
}
__device__ __forceinline__ ushort_t f2bf(float f) {
    union { float f; unsigned u; } c; c.f = f;
    unsigned u = c.u;
    return (ushort_t)((u + 0x7FFFu + ((u >> 16) & 1u)) >> 16);   // RNE
}

// ---------------- degree count + query-keyed CSR build (merged) ----------------
__global__ __launch_bounds__(256) void deg_csr_kernel(const int* __restrict__ ei,
                                                      const int* __restrict__ ea,
                                                      int* __restrict__ deg_in,
                                                      int* __restrict__ deg_out,
                                                      int* __restrict__ cnt,
                                                      int* __restrict__ ebuf) {
    int e = blockIdx.x * 256 + threadIdx.x;
    if (e >= EE) return;
    int src = ei[e], dst = ei[EE + e];
    atomicAdd(&deg_out[src], 1);
    atomicAdd(&deg_in[dst], 1);
    int g = src >> 9;
    int sl = src - (g << 9) + 1;     // query index 1..512
    int dl = dst - (g << 9) + 1;     // key   index 1..512
    int a = ea[e];
    a = (a < 0) ? 0 : (a > 9 ? 9 : a);
    a += 1;                          // ebt row 1..10
    int row = g * TT + sl;           // query-keyed bucket
    int pos = atomicAdd(&cnt[row], 1);
    if (pos < ECAP) ebuf[(size_t)row * ECAP + pos] = dl | (a << 16);
}

// ---------------- node encode + graph token ----------------
__global__ __launch_bounds__(256) void encode_kernel(const float* __restrict__ nf,
                                                     const float* __restrict__ Wn,
                                                     const float* __restrict__ bn,
                                                     const float* __restrict__ gt,
                                                     const float* __restrict__ ide,
                                                     const float* __restrict__ ode,
                                                     const int* __restrict__ deg_in,
                                                     const int* __restrict__ deg_out,
                                                     float* __restrict__ x) {
    int gid = blockIdx.x * 256 + threadIdx.x;
    if (gid >= (int)(XROWS * CC)) return;
    int c = gid & (CC - 1);
    int row = gid >> 7;
    int b = row / TT;
    int t = row - b * TT;
    float val;
    if (t == 0) {
        val = gt[c];
    } else {
        int i = b * NPG + t - 1;
        val = bn[c] + nf[i*3+0]*Wn[0*CC + c] + nf[i*3+1]*Wn[1*CC + c] + nf[i*3+2]*Wn[2*CC + c];
        int di = min(deg_in[i], 511);
        int dq = min(deg_out[i], 511);
        val += ide[(size_t)di * CC + c] + ode[(size_t)dq * CC + c];
    }
    x[(size_t)row * CC + c] = val;
}

// ---------------- LDS-tiled weight transpose + bf16: Wt[n][k] = W[k][n] ----------------
struct TrDesc {
    const float* src[24];
    ushort_t*    dst[24];
    int          K[24];
    int          N[24];
};
__global__ __launch_bounds__(256) void tr_kernel(TrDesc d) {
    int z = blockIdx.z;
    int K = d.K[z], N = d.N[z];
    int tilesN = N >> 6;
    int ntile = (K >> 6) * tilesN;
    int tile = blockIdx.x;
    if (tile >= ntile) return;
    int k0 = (tile / tilesN) << 6;
    int n0 = (tile - (tile / tilesN) * tilesN) << 6;
    const float* src = d.src[z];
    ushort_t* dst = d.dst[z];
    __shared__ float t[64][65];
    int tid = threadIdx.x;
    int c = tid & 63, rb = tid >> 6;
    #pragma unroll
    for (int kk = 0; kk < 64; kk += 4)
        t[kk + rb][c] = src[(size_t)(k0 + kk + rb) * N + n0 + c];
    __syncthreads();
    #pragma unroll
    for (int nn = 0; nn < 64; nn += 4)
        dst[(size_t)(n0 + nn + rb) * K + k0 + c] = f2bf(t[c][nn + rb]);
}

// ---------------- VT pad-zero: s in [513, 544) ----------------
__global__ __launch_bounds__(256) void vtpad_kernel(ushort_t* __restrict__ vt) {
    int i = blockIdx.x * 256 + threadIdx.x;
    if (i >= BB * HH * DD * (SP - TT)) return;
    int row = i / (SP - TT), s = TT + i - row * (SP - TT);
    vt[(size_t)row * SP + s] = 0;
}

// ---------------- LayerNorm (2 rows / 256-thread block), f32 in -> bf16 out ----------------
__global__ __launch_bounds__(256) void ln_kernel(const float* __restrict__ in,
                                                 ushort_t* __restrict__ out,
                                                 const float* __restrict__ gg,
                                                 const float* __restrict__ bb) {
    int tid = threadIdx.x;
    int r2 = tid >> 7;
    int c = tid & 127;
    int row = blockIdx.x * 2 + r2;
    float v = in[(size_t)row * CC + c];
    float s1 = v, s2 = v * v;
    #pragma unroll
    for (int m = 32; m >= 1; m >>= 1) {
        s1 += __shfl_xor(s1, m, 64);
        s2 += __shfl_xor(s2, m, 64);
    }
    __shared__ float red[8];
    int w = tid >> 6;
    if ((tid & 63) == 0) { red[w*2] = s1; red[w*2+1] = s2; }
    __syncthreads();
    int wb = r2 * 4;
    float S1 = red[wb] + red[wb+2], S2 = red[wb+1] + red[wb+3];
    float mn = S1 * (1.0f/CC);
    float var = S2 * (1.0f/CC) - mn * mn;
    float rs = rsqrtf(var + 1e-5f);
    out[(size_t)row * CC + c] = f2bf((v - mn) * rs * gg[c] + bb[c]);
}

// ---------------- per-wave 32x64-tile MFMA bf16 GEMM ----------------
// md per z: 0 = (acc+bias)*scl -> bf16 ; 1 = acc+bias+res -> f32 ;
//           2 = gelu(acc+bias) -> bf16 ; 3 = acc+bias -> VT[bh][d][s] bf16
struct GP {
    const ushort_t* Wt[3];
    const float*    bias[3];
    float*          outF[3];
    ushort_t*       outB[3];
    float           scl[3];
    int             md[3];
};
__global__ __launch_bounds__(256) void gemm_wave(const ushort_t* __restrict__ A, GP p,
                                                 const float* __restrict__ res,
                                                 int M, int N, int K,
                                                 int mtiles, int ntiles) {
    int z = blockIdx.z;
    int wid = blockIdx.x * 4 + (threadIdx.x >> 6);
    if (wid >= mtiles * ntiles) return;
    int tm = wid / ntiles, tn = wid - tm * ntiles;
    int m0 = tm * 32, n0 = tn * 64;
    int lane = threadIdx.x & 63, lq = lane & 15, quad = lane >> 4;
    const short* Wt = (const short*)p.Wt[z];
    const short* Ab = (const short*)A;
    const float* bias = p.bias[z];

    size_t rA[2];
    #pragma unroll
    for (int mi = 0; mi < 2; ++mi) {
        int r = m0 + mi * 16 + lq;
        rA[mi] = (size_t)(r < M ? r : M - 1) * K;
    }
    floatx4 acc[8];
    #pragma unroll
    for (int i = 0; i < 8; ++i) acc[i] = (floatx4){0.f, 0.f, 0.f, 0.f};

    for (int k0 = 0; k0 < K; k0 += 32) {
        short8 af[2], bf[4];
        #pragma unroll
        for (int mi = 0; mi < 2; ++mi)
            af[mi] = *(const short8*)(Ab + rA[mi] + k0 + quad * 8);
        #pragma unroll
        for (int ni = 0; ni < 4; ++ni)
            bf[ni] = *(const short8*)(Wt + (size_t)(n0 + ni * 16 + lq) * K + k0 + quad * 8);
        #pragma unroll
        for (int mi = 0; mi < 2; ++mi)
            #pragma unroll
            for (int ni = 0; ni < 4; ++ni)
                acc[mi*4+ni] = __builtin_amdgcn_mfma_f32_16x16x32_bf16(af[mi], bf[ni], acc[mi*4+ni], 0, 0, 0);
    }

    int mode = p.md[z];
    float scl = p.scl[z];
    float* outF = p.outF[z];
    ushort_t* outB = p.outB[z];
    #pragma unroll
    for (int ni = 0; ni < 4; ++ni) {
        int c = n0 + ni * 16 + lq;
        float bv = bias[c];
        #pragma unroll
        for (int mi = 0; mi < 2; ++mi) {
            #pragma unroll
            for (int rg = 0; rg < 4; ++rg) {
                int r = m0 + mi * 16 + quad * 4 + rg;
                if (r >= M) continue;
                float v = acc[mi*4+ni][rg] + bv;
                if (mode == 0)      outB[(size_t)r * N + c] = f2bf(v * scl);
                else if (mode == 1) outF[(size_t)r * N + c] = v + res[(size_t)r * N + c];
                else if (mode == 2) outB[(size_t)r * N + c] = f2bf(gelu_exact(v));
                else {
                    int bq = r / TT;
                    int s = r - bq * TT;
                    outB[((size_t)(bq * HH + (c >> 4)) * DD + (c & 15)) * SP + s] = f2bf(v);
                }
            }
        }
    }
}

// ---------------- MFMA fused attention: one block per (bh, 16-query tile) ----------------
// Grid (128, 33), 256 thr = 4 waves. No K/V LDS staging: K frags read from
// global kb (L1/L2), V^T frags from pre-transposed global vt. LDS holds the
// per-q-tile f32 bias strip [513][17] (zero + CSR scatter, once per block),
// per-wave P-pack pools, reduction buffers. Waves split the 17 s-pairs.
// Q pre-scaled by 0.25 (exact, folded into QKV epilogue).
__global__ __launch_bounds__(256) void attn_kernel(const ushort_t* __restrict__ qb,
                                                   const ushort_t* __restrict__ kb,
                                                   const ushort_t* __restrict__ vt,
                                                   const int* __restrict__ cnt,
                                                   const int* __restrict__ ebuf,
                                                   const float* __restrict__ ebt,
                                                   const float* __restrict__ vnode,
                                                   ushort_t* __restrict__ ob) {
    int bh = blockIdx.x;
    int qt = blockIdx.y;
    int b = bh >> 3, h = bh & (HH - 1);
    int tid = threadIdx.x;
    int wave = tid >> 6, lane = tid & 63, lq = lane & 15, quad = lane >> 4;

    __shared__ float bstrip[TT * 17];   // [s][q], stride 17 breaks quad aliasing
    __shared__ float pool[1280];        // per-wave 1280B: Pb bf16[16][40] alias ored f32[16][17]
    __shared__ float lsumS[64];
    __shared__ float ebtab[88];

    if (tid < 88) ebtab[tid] = ebt[tid];
    for (int i = tid; i < TT * 17; i += 256) bstrip[i] = 0.f;
    __syncthreads();

    // vnode bias on s==0 (q>0; q==0 row is uniform over s -> cancels in softmax)
    if (tid < 16) {
        int q = qt * 16 + tid;
        if (q > 0 && q < TT) bstrip[tid] = vnode[h];
    }
    // scatter this q-tile's edges (edges never have dl==0, so no race with above)
    {
        int ql = tid >> 4, e0 = tid & 15;
        int q = qt * 16 + ql;
        if (q > 0 && q < TT) {
            int row = b * TT + q;
            int cn = min(cnt[row], ECAP);
            for (int j = e0; j < cn; j += 16) {
                int e = ebuf[(size_t)row * ECAP + j];
                int dl = e & 0xFFFF, a = e >> 16;
                atomicAdd(&bstrip[dl * 17 + ql], ebtab[a * 8 + h]);
            }
        }
    }
    __syncthreads();

    // Q fragment (B-operand): lane holds Q[qt*16+lq][d=quad*8..+7], quads 2,3 zero
    int qg = qt * 16 + lq;
    int qr = qg < TT ? qg : TT - 1;
    short8 qf = {0,0,0,0,0,0,0,0};
    if (quad < 2)
        qf = *(const short8*)(qb + ((size_t)(b * TT + qr)) * CC + h * DD + quad * 8);

    ushort_t* Pbw = (ushort_t*)(pool + wave * 320);
    const short* kbS = (const short*)kb;
    const short* vtS = (const short*)(vt + (size_t)bh * DD * SP);

    floatx4 oacc = {0.f, 0.f, 0.f, 0.f};
    float lsum = 0.f;

    for (int sp = wave; sp < 17; sp += 4) {
        #pragma unroll
        for (int t = 0; t < 2; ++t) {
            int st = sp * 2 + t;                      // s-tile 0..33
            int kr = b * TT + st * 16 + lq;
            kr = kr < (int)XROWS ? kr : (int)XROWS - 1;
            short8 af = {0,0,0,0,0,0,0,0};
            if (quad < 2)
                af = *(const short8*)(kbS + (size_t)kr * CC + h * DD + quad * 8);
            floatx4 c = __builtin_amdgcn_mfma_f32_16x16x32_bf16(
                af, qf, (floatx4){0.f, 0.f, 0.f, 0.f}, 0, 0, 0);
            float pr[4];
            #pragma unroll
            for (int rg = 0; rg < 4; ++rg) {
                int s = st * 16 + quad * 4 + rg;
                float p = 0.f;
                if (s < TT) p = __expf(c[rg] + bstrip[s * 17 + lq]);
                lsum += p;
                pr[rg] = p;
            }
            unsigned* pw = (unsigned*)(Pbw + lq * 40 + t * 16 + quad * 4);
            pw[0] = (unsigned)f2bf(pr[0]) | ((unsigned)f2bf(pr[1]) << 16);
            pw[1] = (unsigned)f2bf(pr[2]) | ((unsigned)f2bf(pr[3]) << 16);
        }
        short8 vf = *(const short8*)(vtS + (size_t)lq * SP + sp * 32 + quad * 8);
        short8 pf = *(const short8*)(Pbw + lq * 40 + quad * 8);
        oacc = __builtin_amdgcn_mfma_f32_16x16x32_bf16(vf, pf, oacc, 0, 0, 0);
    }

    // reduce expsum across quads; stash O^T partials (alias over Pb, wave-local)
    lsum += __shfl_xor(lsum, 16, 64);
    lsum += __shfl_xor(lsum, 32, 64);
    float* redw = pool + wave * 320;
    #pragma unroll
    for (int rg = 0; rg < 4; ++rg)
        redw[(quad * 4 + rg) * 17 + lq] = oacc[rg];
    if (quad == 0) lsumS[wave * 16 + lq] = lsum;
    __syncthreads();

    // cross-wave combine + store: thread (q=tid>>4, d=tid&15), d contiguous
    {
        int q = tid >> 4, d = tid & 15;
        float o = 0.f, L = 0.f;
        #pragma unroll
        for (int w = 0; w < 4; ++w) {
            o += pool[w * 320 + d * 17 + q];
            L += lsumS[w * 16 + q];
        }
        int qq = qt * 16 + q;
        if (qq < TT)
            ob[((size_t)(b * TT + qq)) * CC + h * DD + d] = f2bf(o / L);
    }
}

// ---------------- final LN on graph tokens + classifier ----------------
__global__ __launch_bounds__(128) void head_kernel(const float* __restrict__ x,
                                                   const float* __restrict__ ng,
                                                   const float* __restrict__ nb,
                                                   const float* __restrict__ Wc1,
                                                   const float* __restrict__ bc1,
                                                   const float* __restrict__ Wc2,
                                                   const float* __restrict__ bc2,
                                                   float* __restrict__ out) {
    int b = blockIdx.x;
    int c = threadIdx.x;
    __shared__ float xfs[CC];
    __shared__ float c1s[64];
    __shared__ float red[4];

    float v = x[((size_t)b * TT) * CC + c];
    float s1 = v, s2 = v * v;
    #pragma unroll
    for (int m = 32; m >= 1; m >>= 1) {
        s1 += __shfl_xor(s1, m, 64);
        s2 += __shfl_xor(s2, m, 64);
    }
    int w = c >> 6;
    if ((c & 63) == 0) { red[w*2] = s1; red[w*2+1] = s2; }
    __syncthreads();
    float S1 = red[0] + red[2], S2 = red[1] + red[3];
    float mn = S1 * (1.0f/CC);
    float var = S2 * (1.0f/CC) - mn * mn;
    float rs = rsqrtf(var + 1e-5f);
    xfs[c] = (v - mn) * rs * ng[c] + nb[c];
    __syncthreads();
    if (c < 64) {
        float a = bc1[c];
        #pragma unroll 4
        for (int k = 0; k < CC; ++k) a = fmaf(xfs[k], Wc1[(size_t)k * 64 + c], a);
        c1s[c] = gelu_exact(a);
    }
    __syncthreads();
    if (c < NCLS) {
        float a = bc2[c];
        #pragma unroll 4
        for (int j = 0; j < 64; ++j) a = fmaf(c1s[j], Wc2[(size_t)j * NCLS + c], a);
        out[(size_t)b * NCLS + c] = a;
    }
}

extern "C" void kernel_launch(void* const* d_in, const int* in_sizes, int n_in,
                              void* d_out, int out_size, void* d_ws, size_t ws_size,
                              hipStream_t stream) {
    const float* node_feats = (const float*)d_in[0];
    const int*   edge_index = (const int*)d_in[1];
    const int*   edge_attr  = (const int*)d_in[2];
    const float* W_node  = (const float*)d_in[4];
    const float* b_node  = (const float*)d_in[5];
    const float* g_token = (const float*)d_in[6];
    const float* ebt     = (const float*)d_in[7];
    const float* ide     = (const float*)d_in[8];
    const float* ode     = (const float*)d_in[9];
    const float* vnode   = (const float*)d_in[10];
    const float* Wq = (const float*)d_in[11];
    const float* bq = (const float*)d_in[12];
    const float* Wk = (const float*)d_in[13];
    const float* bk = (const float*)d_in[14];
    const float* Wv = (const float*)d_in[15];
    const float* bv = (const float*)d_in[16];
    const float* Wo = (const float*)d_in[17];
    const float* bo = (const float*)d_in[18];
    const float* ln1g = (const float*)d_in[19];
    const float* ln1b = (const float*)d_in[20];
    const float* ln2g = (const float*)d_in[21];
    const float* ln2b = (const float*)d_in[22];
    const float* W1 = (const float*)d_in[23];
    const float* b1 = (const float*)d_in[24];
    const float* W2 = (const float*)d_in[25];
    const float* b2 = (const float*)d_in[26];
    const float* nfg = (const float*)d_in[27];
    const float* nfb = (const float*)d_in[28];
    const float* Wc1 = (const float*)d_in[29];
    const float* bc1 = (const float*)d_in[30];
    const float* Wc2 = (const float*)d_in[31];
    const float* bc2 = (const float*)d_in[32];
    float* out = (float*)d_out;

    // ---- workspace (all chunks 16B-aligned) ----
    char* base = (char*)d_ws;
    float* x      = (float*)base;     base += XSZ * 4;
    ushort_t* hbf = (ushort_t*)base;  base += XSZ * 2;
    ushort_t* qb  = (ushort_t*)base;  base += XSZ * 2;
    ushort_t* kb  = (ushort_t*)base;  base += XSZ * 2;
    ushort_t* vt  = (ushort_t*)base;  base += VTSZ * 2;
    ushort_t* obf = (ushort_t*)base;  base += XSZ * 2;
    ushort_t* mid = (ushort_t*)base;  base += MIDSZ * 2;
    ushort_t* wtqkvo = (ushort_t*)base; base += (size_t)16 * 16384 * 2;
    ushort_t* wt1 = (ushort_t*)base;  base += (size_t)4 * 65536 * 2;
    ushort_t* wt2 = (ushort_t*)base;  base += (size_t)4 * 65536 * 2;
    int* deg_in  = (int*)base;        base += NNODES * 4;
    int* deg_out = (int*)base;        base += NNODES * 4;
    int* cnt     = (int*)base;        base += (size_t)ROWS * 4;
    int* ebuf    = (int*)base;        base += (size_t)ROWS * ECAP * 4;

    hipMemsetAsync(deg_in, 0, (size_t)(2 * NNODES + ROWS) * 4, stream);
    deg_csr_kernel<<<EE / 256, 256, 0, stream>>>(edge_index, edge_attr,
                                                 deg_in, deg_out, cnt, ebuf);
    encode_kernel<<<(int)((XROWS * CC + 255) / 256), 256, 0, stream>>>(
        node_feats, W_node, b_node, g_token, ide, ode, deg_in, deg_out, x);
    vtpad_kernel<<<(BB*HH*DD*(SP-TT) + 255) / 256, 256, 0, stream>>>(vt);

    TrDesc td;
    for (int l = 0; l < LL; ++l) {
        const float* srcs[4] = {Wq + (size_t)l*CC*CC, Wk + (size_t)l*CC*CC,
                                Wv + (size_t)l*CC*CC, Wo + (size_t)l*CC*CC};
        for (int k = 0; k < 4; ++k) {
            int slot = k * 4 + l;
            td.src[slot] = srcs[k];
            td.dst[slot] = wtqkvo + (size_t)slot * 16384;
            td.K[slot] = CC; td.N[slot] = CC;
        }
        td.src[16 + l] = W1 + (size_t)l*CC*FFN;
        td.dst[16 + l] = wt1 + (size_t)l*65536;
        td.K[16 + l] = CC; td.N[16 + l] = FFN;
        td.src[20 + l] = W2 + (size_t)l*FFN*CC;
        td.dst[20 + l] = wt2 + (size_t)l*65536;
        td.K[20 + l] = FFN; td.N[20 + l] = CC;
    }
    tr_kernel<<<dim3(16, 1, 24), 256, 0, stream>>>(td);

    const int MT = (int)((XROWS + 31) / 32);   // 257 m-tiles of 32 rows

    for (int l = 0; l < LL; ++l) {
        ln_kernel<<<(int)(XROWS / 2), 256, 0, stream>>>(x, hbf, ln1g + l*CC, ln1b + l*CC);

        GP pq = {};
        pq.Wt[0] = wtqkvo + (size_t)(0*4+l)*16384;
        pq.Wt[1] = wtqkvo + (size_t)(1*4+l)*16384;
        pq.Wt[2] = wtqkvo + (size_t)(2*4+l)*16384;
        pq.bias[0] = bq + l*CC; pq.bias[1] = bk + l*CC; pq.bias[2] = bv + l*CC;
        pq.outB[0] = qb; pq.outB[1] = kb; pq.outB[2] = vt;
        pq.scl[0] = 0.25f; pq.scl[1] = 1.0f; pq.scl[2] = 1.0f;  // fold 1/sqrt(D) into Q
        pq.md[0] = 0; pq.md[1] = 0; pq.md[2] = 3;               // V written transposed
        gemm_wave<<<dim3((MT*2 + 3)/4, 1, 3), 256, 0, stream>>>(
            hbf, pq, nullptr, (int)XROWS, CC, CC, MT, 2);

        attn_kernel<<<dim3(BB*HH, 33), 256, 0, stream>>>(
            qb, kb, vt, cnt, ebuf, ebt, vnode, obf);

        GP po = {};
        po.Wt[0] = wtqkvo + (size_t)(3*4+l)*16384;
        po.bias[0] = bo + l*CC; po.outF[0] = x; po.scl[0] = 1.0f; po.md[0] = 1;
        gemm_wave<<<dim3((MT*2 + 3)/4, 1, 1), 256, 0, stream>>>(
            obf, po, x, (int)XROWS, CC, CC, MT, 2);

        ln_kernel<<<(int)(XROWS / 2), 256, 0, stream>>>(x, hbf, ln2g + l*CC, ln2b + l*CC);

        GP p1 = {};
        p1.Wt[0] = wt1 + (size_t)l*65536;
        p1.bias[0] = b1 + l*FFN; p1.outB[0] = mid; p1.scl[0] = 1.0f; p1.md[0] = 2;
        gemm_wave<<<dim3((MT*8 + 3)/4, 1, 1), 256, 0, stream>>>(
            hbf, p1, nullptr, (int)XROWS, FFN, CC, MT, 8);

        GP p2 = {};
        p2.Wt[0] = wt2 + (size_t)l*65536;
        p2.bias[0] = b2 + l*CC; p2.outF[0] = x; p2.scl[0] = 1.0f; p2.md[0] = 1;
        gemm_wave<<<dim3((MT*2 + 3)/4, 1, 1), 256, 0, stream>>>(
            mid, p2, x, (int)XROWS, CC, FFN, MT, 2);
    }

    head_kernel<<<BB, 128, 0, stream>>>(x, nfg, nfb, Wc1, bc1, Wc2, bc2, out);
}

// Round 6
// 574.032 us; speedup vs baseline: 2.3453x; 1.1482x over previous
//
#include <hip/hip_runtime.h>
#include <hip/hip_bf16.h>

#define BB 16
#define NPG 512
#define CC 128
#define HH 8
#define LL 4
#define FFN 512
#define NCLS 4
#define DD 16
#define TT 513            // NPG + 1
#define EE 131072         // B * 8192
#define NNODES 8192       // B * NPG
#define ROWS (BB * TT)    // 8208 CSR rows keyed by (g, sl=query)
#define ECAP 64           // entries per bucket; Poisson(16), P(>=64) ~ 3e-22
#define SP 544            // padded s extent (34 tiles of 16)

static constexpr size_t XROWS = (size_t)BB * TT;   // 8208 (= 513 * 16 exactly)
static constexpr size_t XSZ   = XROWS * CC;        // 1,050,624
static constexpr size_t MIDSZ = XROWS * FFN;       // 4,202,496
static constexpr size_t VTSZ  = (size_t)BB * HH * DD * SP;  // 1,114,112

typedef unsigned short ushort_t;
typedef __attribute__((ext_vector_type(8))) short short8;
typedef __attribute__((ext_vector_type(4))) float floatx4;

__device__ __forceinline__ float gelu_exact(float v) {
    return 0.5f * v * (1.0f + erff(v * 0.70710678118654752440f));
}
__device__ __forceinline__ ushort_t f2bf(float f) {
    union { float f; unsigned u; } c; c.f = f;
    unsigned u = c.u;
    return (ushort_t)((u + 0x7FFFu + ((u >> 16) & 1u)) >> 16);   // RNE
}

// ---------------- degree count + query-keyed CSR build (merged) ----------------
__global__ __launch_bounds__(256) void deg_csr_kernel(const int* __restrict__ ei,
                                                      const int* __restrict__ ea,
                                                      int* __restrict__ deg_in,
                                                      int* __restrict__ deg_out,
                                                      int* __restrict__ cnt,
                                                      int* __restrict__ ebuf) {
    int e = blockIdx.x * 256 + threadIdx.x;
    if (e >= EE) return;
    int src = ei[e], dst = ei[EE + e];
    atomicAdd(&deg_out[src], 1);
    atomicAdd(&deg_in[dst], 1);
    int g = src >> 9;
    int sl = src - (g << 9) + 1;     // query index 1..512
    int dl = dst - (g << 9) + 1;     // key   index 1..512
    int a = ea[e];
    a = (a < 0) ? 0 : (a > 9 ? 9 : a);
    a += 1;                          // ebt row 1..10
    int row = g * TT + sl;           // query-keyed bucket
    int pos = atomicAdd(&cnt[row], 1);
    if (pos < ECAP) ebuf[(size_t)row * ECAP + pos] = dl | (a << 16);
}

// ---------------- node encode + graph token ----------------
__global__ __launch_bounds__(256) void encode_kernel(const float* __restrict__ nf,
                                                     const float* __restrict__ Wn,
                                                     const float* __restrict__ bn,
                                                     const float* __restrict__ gt,
                                                     const float* __restrict__ ide,
                                                     const float* __restrict__ ode,
                                                     const int* __restrict__ deg_in,
                                                     const int* __restrict__ deg_out,
                                                     float* __restrict__ x) {
    int gid = blockIdx.x * 256 + threadIdx.x;
    if (gid >= (int)(XROWS * CC)) return;
    int c = gid & (CC - 1);
    int row = gid >> 7;
    int b = row / TT;
    int t = row - b * TT;
    float val;
    if (t == 0) {
        val = gt[c];
    } else {
        int i = b * NPG + t - 1;
        val = bn[c] + nf[i*3+0]*Wn[0*CC + c] + nf[i*3+1]*Wn[1*CC + c] + nf[i*3+2]*Wn[2*CC + c];
        int di = min(deg_in[i], 511);
        int dq = min(deg_out[i], 511);
        val += ide[(size_t)di * CC + c] + ode[(size_t)dq * CC + c];
    }
    x[(size_t)row * CC + c] = val;
}

// ---------------- LDS-tiled weight transpose + bf16: Wt[n][k] = W[k][n] ----------------
struct TrDesc {
    const float* src[24];
    ushort_t*    dst[24];
    int          K[24];
    int          N[24];
};
__global__ __launch_bounds__(256) void tr_kernel(TrDesc d) {
    int z = blockIdx.z;
    int K = d.K[z], N = d.N[z];
    int tilesN = N >> 6;
    int ntile = (K >> 6) * tilesN;
    int tile = blockIdx.x;
    if (tile >= ntile) return;
    int k0 = (tile / tilesN) << 6;
    int n0 = (tile - (tile / tilesN) * tilesN) << 6;
    const float* src = d.src[z];
    ushort_t* dst = d.dst[z];
    __shared__ float t[64][65];
    int tid = threadIdx.x;
    int c = tid & 63, rb = tid >> 6;
    #pragma unroll
    for (int kk = 0; kk < 64; kk += 4)
        t[kk + rb][c] = src[(size_t)(k0 + kk + rb) * N + n0 + c];
    __syncthreads();
    #pragma unroll
    for (int nn = 0; nn < 64; nn += 4)
        dst[(size_t)(n0 + nn + rb) * K + k0 + c] = f2bf(t[c][nn + rb]);
}

// ---------------- VT pad-zero: s in [513, 544) ----------------
__global__ __launch_bounds__(256) void vtpad_kernel(ushort_t* __restrict__ vt) {
    int i = blockIdx.x * 256 + threadIdx.x;
    if (i >= BB * HH * DD * (SP - TT)) return;
    int row = i / (SP - TT), s = TT + i - row * (SP - TT);
    vt[(size_t)row * SP + s] = 0;
}

// ---------------- LayerNorm (2 rows / 256-thread block), f32 in -> bf16 out ----------------
__global__ __launch_bounds__(256) void ln_kernel(const float* __restrict__ in,
                                                 ushort_t* __restrict__ out,
                                                 const float* __restrict__ gg,
                                                 const float* __restrict__ bb) {
    int tid = threadIdx.x;
    int r2 = tid >> 7;
    int c = tid & 127;
    int row = blockIdx.x * 2 + r2;
    float v = in[(size_t)row * CC + c];
    float s1 = v, s2 = v * v;
    #pragma unroll
    for (int m = 32; m >= 1; m >>= 1) {
        s1 += __shfl_xor(s1, m, 64);
        s2 += __shfl_xor(s2, m, 64);
    }
    __shared__ float red[8];
    int w = tid >> 6;
    if ((tid & 63) == 0) { red[w*2] = s1; red[w*2+1] = s2; }
    __syncthreads();
    int wb = r2 * 4;
    float S1 = red[wb] + red[wb+2], S2 = red[wb+1] + red[wb+3];
    float mn = S1 * (1.0f/CC);
    float var = S2 * (1.0f/CC) - mn * mn;
    float rs = rsqrtf(var + 1e-5f);
    out[(size_t)row * CC + c] = f2bf((v - mn) * rs * gg[c] + bb[c]);
}

// ---------------- per-wave 16x32-tile MFMA bf16 GEMM ----------------
// Each wave owns one 16(m) x 32(n) tile; block = 4 waves, wid = bid*4+wave.
// With ntiles==4 a block's 4 waves cover one 16-row tile x full N=128 -> mode 4
// can fuse residual + LayerNorm (cross-wave stats via 512B LDS).
// md: 0 = (acc+bias)*scl -> bf16 ; 1 = acc+bias+res -> f32 ;
//     2 = gelu(acc+bias) -> bf16 ; 3 = acc+bias -> VT[bh][d][s] bf16 ;
//     4 = acc+bias+res -> f32 out AND LN(bf16) out (requires N=128, ntiles=4)
struct GP {
    const ushort_t* Wt[3];
    const float*    bias[3];
    float*          outF[3];
    ushort_t*       outB[3];
    const float*    lng[3];
    const float*    lnb[3];
    float           scl[3];
    int             md[3];
};
__global__ __launch_bounds__(256) void gemm_wave(const ushort_t* __restrict__ A, GP p,
                                                 const float* __restrict__ res,
                                                 int M, int N, int K,
                                                 int mtiles, int ntiles) {
    int z = blockIdx.z;
    int wave = threadIdx.x >> 6;
    int wid = blockIdx.x * 4 + wave;
    int maxw = mtiles * ntiles;
    int widc = wid < maxw ? wid : maxw - 1;
    bool act = wid < maxw;
    int tm = widc / ntiles, tn = widc - tm * ntiles;
    int m0 = tm * 16, n0 = tn * 32;
    int lane = threadIdx.x & 63, lq = lane & 15, quad = lane >> 4;
    const short* Wt = (const short*)p.Wt[z];
    const short* Ab = (const short*)A;

    __shared__ float sred[4][16][2];

    size_t rowA  = (size_t)(m0 + lq) * K;
    size_t rowB0 = (size_t)(n0 + lq) * K;
    size_t rowB1 = (size_t)(n0 + 16 + lq) * K;

    floatx4 acc0 = {0.f, 0.f, 0.f, 0.f}, acc1 = acc0;
    for (int k0 = 0; k0 < K; k0 += 32) {
        short8 af = *(const short8*)(Ab + rowA + k0 + quad * 8);
        short8 b0 = *(const short8*)(Wt + rowB0 + k0 + quad * 8);
        short8 b1 = *(const short8*)(Wt + rowB1 + k0 + quad * 8);
        acc0 = __builtin_amdgcn_mfma_f32_16x16x32_bf16(af, b0, acc0, 0, 0, 0);
        acc1 = __builtin_amdgcn_mfma_f32_16x16x32_bf16(af, b1, acc1, 0, 0, 0);
    }

    int mode = p.md[z];
    float scl = p.scl[z];
    float* outF = p.outF[z];
    ushort_t* outB = p.outB[z];
    int c0 = n0 + lq, c1 = n0 + 16 + lq;
    float bv0 = p.bias[z][c0], bv1 = p.bias[z][c1];

    if (mode == 4) {
        // fused residual + LayerNorm (block covers full rows; N == 128)
        float vv0[4], vv1[4];
        #pragma unroll
        for (int rg = 0; rg < 4; ++rg) {
            int r = m0 + quad * 4 + rg;
            float a0 = acc0[rg] + bv0 + res[(size_t)r * N + c0];
            float a1 = acc1[rg] + bv1 + res[(size_t)r * N + c1];
            outF[(size_t)r * N + c0] = a0;
            outF[(size_t)r * N + c1] = a1;
            vv0[rg] = a0; vv1[rg] = a1;
        }
        #pragma unroll
        for (int rg = 0; rg < 4; ++rg) {
            float s1 = vv0[rg] + vv1[rg];
            float s2 = vv0[rg]*vv0[rg] + vv1[rg]*vv1[rg];
            #pragma unroll
            for (int m = 1; m < 16; m <<= 1) {
                s1 += __shfl_xor(s1, m, 64);
                s2 += __shfl_xor(s2, m, 64);
            }
            if (lq == 0) { sred[wave][quad*4+rg][0] = s1; sred[wave][quad*4+rg][1] = s2; }
        }
        __syncthreads();
        const float* gg = p.lng[z];
        const float* bb = p.lnb[z];
        float g0 = gg[c0], g1 = gg[c1], lb0 = bb[c0], lb1 = bb[c1];
        #pragma unroll
        for (int rg = 0; rg < 4; ++rg) {
            int row = quad * 4 + rg;
            float S1 = sred[0][row][0] + sred[1][row][0] + sred[2][row][0] + sred[3][row][0];
            float S2 = sred[0][row][1] + sred[1][row][1] + sred[2][row][1] + sred[3][row][1];
            float mn = S1 * (1.0f/CC);
            float var = S2 * (1.0f/CC) - mn * mn;
            float rs = rsqrtf(var + 1e-5f);
            int r = m0 + row;
            outB[(size_t)r * N + c0] = f2bf((vv0[rg] - mn) * rs * g0 + lb0);
            outB[(size_t)r * N + c1] = f2bf((vv1[rg] - mn) * rs * g1 + lb1);
        }
        return;
    }

    if (!act) return;
    #pragma unroll
    for (int rg = 0; rg < 4; ++rg) {
        int r = m0 + quad * 4 + rg;
        if (r >= M) continue;
        float a0 = acc0[rg] + bv0;
        float a1 = acc1[rg] + bv1;
        if (mode == 0) {
            outB[(size_t)r * N + c0] = f2bf(a0 * scl);
            outB[(size_t)r * N + c1] = f2bf(a1 * scl);
        } else if (mode == 1) {
            outF[(size_t)r * N + c0] = a0 + res[(size_t)r * N + c0];
            outF[(size_t)r * N + c1] = a1 + res[(size_t)r * N + c1];
        } else if (mode == 2) {
            outB[(size_t)r * N + c0] = f2bf(gelu_exact(a0));
            outB[(size_t)r * N + c1] = f2bf(gelu_exact(a1));
        } else {
            int bq = r / TT;
            int s = r - bq * TT;
            outB[((size_t)(bq * HH + (c0 >> 4)) * DD + (c0 & 15)) * SP + s] = f2bf(a0);
            outB[((size_t)(bq * HH + (c1 >> 4)) * DD + (c1 & 15)) * SP + s] = f2bf(a1);
        }
    }
}

// ---------------- MFMA fused attention: one block per (bh, 16-query tile) ----------------
// Grid (128, 33), 256 thr = 4 waves. K frags from global kb (L1/L2), V^T frags
// from pre-transposed global vt. LDS: per-q-tile f32 bias strip [513][17]
// (zero + CSR scatter, once per block), per-wave P-pack pool, reduction bufs.
// Q pre-scaled by 0.25 (exact). ebt read straight from global (L1-resident).
__global__ __launch_bounds__(256) void attn_kernel(const ushort_t* __restrict__ qb,
                                                   const ushort_t* __restrict__ kb,
                                                   const ushort_t* __restrict__ vt,
                                                   const int* __restrict__ cnt,
                                                   const int* __restrict__ ebuf,
                                                   const float* __restrict__ ebt,
                                                   const float* __restrict__ vnode,
                                                   ushort_t* __restrict__ ob) {
    int bh = blockIdx.x;
    int qt = blockIdx.y;
    int b = bh >> 3, h = bh & (HH - 1);
    int tid = threadIdx.x;
    int wave = tid >> 6, lane = tid & 63, lq = lane & 15, quad = lane >> 4;

    __shared__ float bstrip[TT * 17];   // [s][q], stride 17 breaks quad aliasing
    __shared__ float pool[1280];        // per-wave 1280B: Pb bf16[16][40] alias red f32[16][17]
    __shared__ float lsumS[64];

    // hoisted global loads (latency overlaps the strip build below)
    int qg = qt * 16 + lq;
    int qr = qg < TT ? qg : TT - 1;
    short8 qf = {0,0,0,0,0,0,0,0};
    if (quad < 2)
        qf = *(const short8*)(qb + ((size_t)(b * TT + qr)) * CC + h * DD + quad * 8);
    float vbh = vnode[h];
    int ql = tid >> 4, e0 = tid & 15;
    int qs = qt * 16 + ql;
    int crow = b * TT + (qs < TT ? qs : 0);
    int cn = (qs > 0 && qs < TT) ? min(cnt[crow], ECAP) : 0;

    for (int i = tid; i < TT * 17; i += 256) bstrip[i] = 0.f;
    __syncthreads();

    // vnode bias on s==0 (q>0; q==0 row uniform over s -> cancels in softmax)
    if (tid < 16) {
        int q = qt * 16 + tid;
        if (q > 0 && q < TT) bstrip[tid] = vbh;
    }
    // scatter this q-tile's edges (dl never 0, so no race with the line above)
    for (int j = e0; j < cn; j += 16) {
        int e = ebuf[(size_t)crow * ECAP + j];
        int dl = e & 0xFFFF, a = e >> 16;
        atomicAdd(&bstrip[dl * 17 + ql], ebt[a * 8 + h]);
    }
    __syncthreads();

    ushort_t* Pbw = (ushort_t*)(pool + wave * 320);
    const short* kbS = (const short*)kb;
    const short* vtS = (const short*)(vt + (size_t)bh * DD * SP);

    floatx4 oacc = {0.f, 0.f, 0.f, 0.f};
    float lsum = 0.f;

    for (int sp = wave; sp < 17; sp += 4) {
        #pragma unroll
        for (int t = 0; t < 2; ++t) {
            int st = sp * 2 + t;                      // s-tile 0..33
            int kr = b * TT + st * 16 + lq;
            kr = kr < (int)XROWS ? kr : (int)XROWS - 1;
            short8 af = {0,0,0,0,0,0,0,0};
            if (quad < 2)
                af = *(const short8*)(kbS + (size_t)kr * CC + h * DD + quad * 8);
            floatx4 c = __builtin_amdgcn_mfma_f32_16x16x32_bf16(
                af, qf, (floatx4){0.f, 0.f, 0.f, 0.f}, 0, 0, 0);
            float pr[4];
            #pragma unroll
            for (int rg = 0; rg < 4; ++rg) {
                int s = st * 16 + quad * 4 + rg;
                float p = 0.f;
                if (s < TT) p = __expf(c[rg] + bstrip[s * 17 + lq]);
                lsum += p;
                pr[rg] = p;
            }
            unsigned* pw = (unsigned*)(Pbw + lq * 40 + t * 16 + quad * 4);
            pw[0] = (unsigned)f2bf(pr[0]) | ((unsigned)f2bf(pr[1]) << 16);
            pw[1] = (unsigned)f2bf(pr[2]) | ((unsigned)f2bf(pr[3]) << 16);
        }
        short8 vf = *(const short8*)(vtS + (size_t)lq * SP + sp * 32 + quad * 8);
        short8 pf = *(const short8*)(Pbw + lq * 40 + quad * 8);
        oacc = __builtin_amdgcn_mfma_f32_16x16x32_bf16(vf, pf, oacc, 0, 0, 0);
    }

    // reduce expsum across quads; stash O^T partials (alias over Pb, wave-local)
    lsum += __shfl_xor(lsum, 16, 64);
    lsum += __shfl_xor(lsum, 32, 64);
    float* redw = pool + wave * 320;
    #pragma unroll
    for (int rg = 0; rg < 4; ++rg)
        redw[(quad * 4 + rg) * 17 + lq] = oacc[rg];
    if (quad == 0) lsumS[wave * 16 + lq] = lsum;
    __syncthreads();

    // cross-wave combine + store: thread (q=tid>>4, d=tid&15), d contiguous
    {
        int q = tid >> 4, d = tid & 15;
        float o = 0.f, L = 0.f;
        #pragma unroll
        for (int w = 0; w < 4; ++w) {
            o += pool[w * 320 + d * 17 + q];
            L += lsumS[w * 16 + q];
        }
        int qq = qt * 16 + q;
        if (qq < TT)
            ob[((size_t)(b * TT + qq)) * CC + h * DD + d] = f2bf(o / L);
    }
}

// ---------------- final LN on graph tokens + classifier ----------------
__global__ __launch_bounds__(128) void head_kernel(const float* __restrict__ x,
                                                   const float* __restrict__ ng,
                                                   const float* __restrict__ nb,
                                                   const float* __restrict__ Wc1,
                                                   const float* __restrict__ bc1,
                                                   const float* __restrict__ Wc2,
                                                   const float* __restrict__ bc2,
                                                   float* __restrict__ out) {
    int b = blockIdx.x;
    int c = threadIdx.x;
    __shared__ float xfs[CC];
    __shared__ float c1s[64];
    __shared__ float red[4];

    float v = x[((size_t)b * TT) * CC + c];
    float s1 = v, s2 = v * v;
    #pragma unroll
    for (int m = 32; m >= 1; m >>= 1) {
        s1 += __shfl_xor(s1, m, 64);
        s2 += __shfl_xor(s2, m, 64);
    }
    int w = c >> 6;
    if ((c & 63) == 0) { red[w*2] = s1; red[w*2+1] = s2; }
    __syncthreads();
    float S1 = red[0] + red[2], S2 = red[1] + red[3];
    float mn = S1 * (1.0f/CC);
    float var = S2 * (1.0f/CC) - mn * mn;
    float rs = rsqrtf(var + 1e-5f);
    xfs[c] = (v - mn) * rs * ng[c] + nb[c];
    __syncthreads();
    if (c < 64) {
        float a = bc1[c];
        #pragma unroll 4
        for (int k = 0; k < CC; ++k) a = fmaf(xfs[k], Wc1[(size_t)k * 64 + c], a);
        c1s[c] = gelu_exact(a);
    }
    __syncthreads();
    if (c < NCLS) {
        float a = bc2[c];
        #pragma unroll 4
        for (int j = 0; j < 64; ++j) a = fmaf(c1s[j], Wc2[(size_t)j * NCLS + c], a);
        out[(size_t)b * NCLS + c] = a;
    }
}

extern "C" void kernel_launch(void* const* d_in, const int* in_sizes, int n_in,
                              void* d_out, int out_size, void* d_ws, size_t ws_size,
                              hipStream_t stream) {
    const float* node_feats = (const float*)d_in[0];
    const int*   edge_index = (const int*)d_in[1];
    const int*   edge_attr  = (const int*)d_in[2];
    const float* W_node  = (const float*)d_in[4];
    const float* b_node  = (const float*)d_in[5];
    const float* g_token = (const float*)d_in[6];
    const float* ebt     = (const float*)d_in[7];
    const float* ide     = (const float*)d_in[8];
    const float* ode     = (const float*)d_in[9];
    const float* vnode   = (const float*)d_in[10];
    const float* Wq = (const float*)d_in[11];
    const float* bq = (const float*)d_in[12];
    const float* Wk = (const float*)d_in[13];
    const float* bk = (const float*)d_in[14];
    const float* Wv = (const float*)d_in[15];
    const float* bv = (const float*)d_in[16];
    const float* Wo = (const float*)d_in[17];
    const float* bo = (const float*)d_in[18];
    const float* ln1g = (const float*)d_in[19];
    const float* ln1b = (const float*)d_in[20];
    const float* ln2g = (const float*)d_in[21];
    const float* ln2b = (const float*)d_in[22];
    const float* W1 = (const float*)d_in[23];
    const float* b1 = (const float*)d_in[24];
    const float* W2 = (const float*)d_in[25];
    const float* b2 = (const float*)d_in[26];
    const float* nfg = (const float*)d_in[27];
    const float* nfb = (const float*)d_in[28];
    const float* Wc1 = (const float*)d_in[29];
    const float* bc1 = (const float*)d_in[30];
    const float* Wc2 = (const float*)d_in[31];
    const float* bc2 = (const float*)d_in[32];
    float* out = (float*)d_out;

    // ---- workspace (all chunks 16B-aligned) ----
    char* base = (char*)d_ws;
    float* x      = (float*)base;     base += XSZ * 4;
    ushort_t* hbf = (ushort_t*)base;  base += XSZ * 2;
    ushort_t* qb  = (ushort_t*)base;  base += XSZ * 2;
    ushort_t* kb  = (ushort_t*)base;  base += XSZ * 2;
    ushort_t* vt  = (ushort_t*)base;  base += VTSZ * 2;
    ushort_t* obf = (ushort_t*)base;  base += XSZ * 2;
    ushort_t* mid = (ushort_t*)base;  base += MIDSZ * 2;
    ushort_t* wtqkvo = (ushort_t*)base; base += (size_t)16 * 16384 * 2;
    ushort_t* wt1 = (ushort_t*)base;  base += (size_t)4 * 65536 * 2;
    ushort_t* wt2 = (ushort_t*)base;  base += (size_t)4 * 65536 * 2;
    int* deg_in  = (int*)base;        base += NNODES * 4;
    int* deg_out = (int*)base;        base += NNODES * 4;
    int* cnt     = (int*)base;        base += (size_t)ROWS * 4;
    int* ebuf    = (int*)base;        base += (size_t)ROWS * ECAP * 4;

    hipMemsetAsync(deg_in, 0, (size_t)(2 * NNODES + ROWS) * 4, stream);
    deg_csr_kernel<<<EE / 256, 256, 0, stream>>>(edge_index, edge_attr,
                                                 deg_in, deg_out, cnt, ebuf);
    encode_kernel<<<(int)((XROWS * CC + 255) / 256), 256, 0, stream>>>(
        node_feats, W_node, b_node, g_token, ide, ode, deg_in, deg_out, x);
    vtpad_kernel<<<(BB*HH*DD*(SP-TT) + 255) / 256, 256, 0, stream>>>(vt);

    TrDesc td;
    for (int l = 0; l < LL; ++l) {
        const float* srcs[4] = {Wq + (size_t)l*CC*CC, Wk + (size_t)l*CC*CC,
                                Wv + (size_t)l*CC*CC, Wo + (size_t)l*CC*CC};
        for (int k = 0; k < 4; ++k) {
            int slot = k * 4 + l;
            td.src[slot] = srcs[k];
            td.dst[slot] = wtqkvo + (size_t)slot * 16384;
            td.K[slot] = CC; td.N[slot] = CC;
        }
        td.src[16 + l] = W1 + (size_t)l*CC*FFN;
        td.dst[16 + l] = wt1 + (size_t)l*65536;
        td.K[16 + l] = CC; td.N[16 + l] = FFN;
        td.src[20 + l] = W2 + (size_t)l*FFN*CC;
        td.dst[20 + l] = wt2 + (size_t)l*65536;
        td.K[20 + l] = FFN; td.N[20 + l] = CC;
    }
    tr_kernel<<<dim3(16, 1, 24), 256, 0, stream>>>(td);

    const int MT16 = (int)(XROWS / 16);   // 513 m-tiles of 16 rows (exact)

    // layer 0's ln1 is standalone; later ln1's are fused into ffn2 epilogues
    ln_kernel<<<(int)(XROWS / 2), 256, 0, stream>>>(x, hbf, ln1g, ln1b);

    for (int l = 0; l < LL; ++l) {
        GP pq = {};
        pq.Wt[0] = wtqkvo + (size_t)(0*4+l)*16384;
        pq.Wt[1] = wtqkvo + (size_t)(1*4+l)*16384;
        pq.Wt[2] = wtqkvo + (size_t)(2*4+l)*16384;
        pq.bias[0] = bq + l*CC; pq.bias[1] = bk + l*CC; pq.bias[2] = bv + l*CC;
        pq.outB[0] = qb; pq.outB[1] = kb; pq.outB[2] = vt;
        pq.scl[0] = 0.25f; pq.scl[1] = 1.0f; pq.scl[2] = 1.0f;  // fold 1/sqrt(D) into Q
        pq.md[0] = 0; pq.md[1] = 0; pq.md[2] = 3;               // V written transposed
        gemm_wave<<<dim3(MT16, 1, 3), 256, 0, stream>>>(
            hbf, pq, nullptr, (int)XROWS, CC, CC, MT16, 4);

        attn_kernel<<<dim3(BB*HH, 33), 256, 0, stream>>>(
            qb, kb, vt, cnt, ebuf, ebt, vnode, obf);

        // O-proj + residual + ln2 fused
        GP po = {};
        po.Wt[0] = wtqkvo + (size_t)(3*4+l)*16384;
        po.bias[0] = bo + l*CC; po.outF[0] = x; po.outB[0] = hbf;
        po.lng[0] = ln2g + l*CC; po.lnb[0] = ln2b + l*CC;
        po.scl[0] = 1.0f; po.md[0] = 4;
        gemm_wave<<<dim3(MT16, 1, 1), 256, 0, stream>>>(
            obf, po, x, (int)XROWS, CC, CC, MT16, 4);

        GP p1 = {};
        p1.Wt[0] = wt1 + (size_t)l*65536;
        p1.bias[0] = b1 + l*FFN; p1.outB[0] = mid; p1.scl[0] = 1.0f; p1.md[0] = 2;
        gemm_wave<<<dim3(MT16*4, 1, 1), 256, 0, stream>>>(
            hbf, p1, nullptr, (int)XROWS, FFN, CC, MT16, 16);

        // FFN2 + residual + next layer's ln1 fused (l==3 output unused; head reads x)
        int ln_next = (l + 1) % LL;
        GP p2 = {};
        p2.Wt[0] = wt2 + (size_t)l*65536;
        p2.bias[0] = b2 + l*CC; p2.outF[0] = x; p2.outB[0] = hbf;
        p2.lng[0] = ln1g + ln_next*CC; p2.lnb[0] = ln1b + ln_next*CC;
        p2.scl[0] = 1.0f; p2.md[0] = 4;
        gemm_wave<<<dim3(MT16, 1, 1), 256, 0, stream>>>(
            mid, p2, x, (int)XROWS, CC, FFN, MT16, 4);
    }

    head_kernel<<<BB, 128, 0, stream>>>(x, nfg, nfb, Wc1, bc1, Wc2, bc2, out);
}

// Round 7
// 513.497 us; speedup vs baseline: 2.6218x; 1.1179x over previous
//
#include <hip/hip_runtime.h>
#include <hip/hip_bf16.h>

#define BB 16
#define NPG 512
#define CC 128
#define HH 8
#define LL 4
#define FFN 512
#define NCLS 4
#define DD 16
#define TT 513            // NPG + 1
#define EE 131072         // B * 8192
#define NNODES 8192       // B * NPG
#define ROWS (BB * TT)    // 8208 CSR rows keyed by (g, sl=query)
#define ECAP 64           // entries per bucket; Poisson(16), P(>=64) ~ 3e-22
#define SP 544            // padded s extent (34 tiles of 16)
#define BSTR 292          // bias strip stride (floats), mult of 4 for b128

static constexpr size_t XROWS = (size_t)BB * TT;   // 8208 (= 513 * 16 exactly)
static constexpr size_t XSZ   = XROWS * CC;        // 1,050,624
static constexpr size_t MIDSZ = XROWS * FFN;       // 4,202,496
static constexpr size_t VTSZ  = (size_t)BB * HH * DD * SP;  // 1,114,112

typedef unsigned short ushort_t;
typedef __attribute__((ext_vector_type(8))) short short8;
typedef __attribute__((ext_vector_type(4))) float floatx4;

__device__ __forceinline__ float gelu_exact(float v) {
    return 0.5f * v * (1.0f + erff(v * 0.70710678118654752440f));
}
__device__ __forceinline__ ushort_t f2bf(float f) {
    union { float f; unsigned u; } c; c.f = f;
    unsigned u = c.u;
    return (ushort_t)((u + 0x7FFFu + ((u >> 16) & 1u)) >> 16);   // RNE
}

// ---------------- degree count + query-keyed CSR build (merged) ----------------
__global__ __launch_bounds__(256) void deg_csr_kernel(const int* __restrict__ ei,
                                                      const int* __restrict__ ea,
                                                      int* __restrict__ deg_in,
                                                      int* __restrict__ deg_out,
                                                      int* __restrict__ cnt,
                                                      int* __restrict__ ebuf) {
    int e = blockIdx.x * 256 + threadIdx.x;
    if (e >= EE) return;
    int src = ei[e], dst = ei[EE + e];
    atomicAdd(&deg_out[src], 1);
    atomicAdd(&deg_in[dst], 1);
    int g = src >> 9;
    int sl = src - (g << 9) + 1;     // query index 1..512
    int dl = dst - (g << 9) + 1;     // key   index 1..512
    int a = ea[e];
    a = (a < 0) ? 0 : (a > 9 ? 9 : a);
    a += 1;                          // ebt row 1..10
    int row = g * TT + sl;           // query-keyed bucket
    int pos = atomicAdd(&cnt[row], 1);
    if (pos < ECAP) ebuf[(size_t)row * ECAP + pos] = dl | (a << 16);
}

// ---------------- node encode + graph token ----------------
__global__ __launch_bounds__(256) void encode_kernel(const float* __restrict__ nf,
                                                     const float* __restrict__ Wn,
                                                     const float* __restrict__ bn,
                                                     const float* __restrict__ gt,
                                                     const float* __restrict__ ide,
                                                     const float* __restrict__ ode,
                                                     const int* __restrict__ deg_in,
                                                     const int* __restrict__ deg_out,
                                                     float* __restrict__ x) {
    int gid = blockIdx.x * 256 + threadIdx.x;
    if (gid >= (int)(XROWS * CC)) return;
    int c = gid & (CC - 1);
    int row = gid >> 7;
    int b = row / TT;
    int t = row - b * TT;
    float val;
    if (t == 0) {
        val = gt[c];
    } else {
        int i = b * NPG + t - 1;
        val = bn[c] + nf[i*3+0]*Wn[0*CC + c] + nf[i*3+1]*Wn[1*CC + c] + nf[i*3+2]*Wn[2*CC + c];
        int di = min(deg_in[i], 511);
        int dq = min(deg_out[i], 511);
        val += ide[(size_t)di * CC + c] + ode[(size_t)dq * CC + c];
    }
    x[(size_t)row * CC + c] = val;
}

// ---------------- LDS-tiled weight transpose + bf16: Wt[n][k] = W[k][n] ----------------
struct TrDesc {
    const float* src[24];
    ushort_t*    dst[24];
    int          K[24];
    int          N[24];
};
__global__ __launch_bounds__(256) void tr_kernel(TrDesc d) {
    int z = blockIdx.z;
    int K = d.K[z], N = d.N[z];
    int tilesN = N >> 6;
    int ntile = (K >> 6) * tilesN;
    int tile = blockIdx.x;
    if (tile >= ntile) return;
    int k0 = (tile / tilesN) << 6;
    int n0 = (tile - (tile / tilesN) * tilesN) << 6;
    const float* src = d.src[z];
    ushort_t* dst = d.dst[z];
    __shared__ float t[64][65];
    int tid = threadIdx.x;
    int c = tid & 63, rb = tid >> 6;
    #pragma unroll
    for (int kk = 0; kk < 64; kk += 4)
        t[kk + rb][c] = src[(size_t)(k0 + kk + rb) * N + n0 + c];
    __syncthreads();
    #pragma unroll
    for (int nn = 0; nn < 64; nn += 4)
        dst[(size_t)(n0 + nn + rb) * K + k0 + c] = f2bf(t[c][nn + rb]);
}

// ---------------- LayerNorm (2 rows / 256-thread block), f32 in -> bf16 out ----------------
__global__ __launch_bounds__(256) void ln_kernel(const float* __restrict__ in,
                                                 ushort_t* __restrict__ out,
                                                 const float* __restrict__ gg,
                                                 const float* __restrict__ bb) {
    int tid = threadIdx.x;
    int r2 = tid >> 7;
    int c = tid & 127;
    int row = blockIdx.x * 2 + r2;
    float v = in[(size_t)row * CC + c];
    float s1 = v, s2 = v * v;
    #pragma unroll
    for (int m = 32; m >= 1; m >>= 1) {
        s1 += __shfl_xor(s1, m, 64);
        s2 += __shfl_xor(s2, m, 64);
    }
    __shared__ float red[8];
    int w = tid >> 6;
    if ((tid & 63) == 0) { red[w*2] = s1; red[w*2+1] = s2; }
    __syncthreads();
    int wb = r2 * 4;
    float S1 = red[wb] + red[wb+2], S2 = red[wb+1] + red[wb+3];
    float mn = S1 * (1.0f/CC);
    float var = S2 * (1.0f/CC) - mn * mn;
    float rs = rsqrtf(var + 1e-5f);
    out[(size_t)row * CC + c] = f2bf((v - mn) * rs * gg[c] + bb[c]);
}

// ---------------- per-wave 16x32-tile MFMA bf16 GEMM (compile-time K) ----------------
// md: 0 = (acc+bias)*scl -> bf16 ; 1 = acc+bias+res -> f32 ;
//     2 = gelu(acc+bias) -> bf16 ; 3 = acc+bias -> VT[bh][d][s] bf16 ;
//     4 = acc+bias+res -> f32 out AND LN(bf16) out (requires N=128, ntiles=4)
struct GP {
    const ushort_t* Wt[3];
    const float*    bias[3];
    float*          outF[3];
    ushort_t*       outB[3];
    const float*    lng[3];
    const float*    lnb[3];
    float           scl[3];
    int             md[3];
};
template<int K>
__global__ __launch_bounds__(256) void gemm_wave(const ushort_t* __restrict__ A, GP p,
                                                 const float* __restrict__ res,
                                                 int M, int N,
                                                 int mtiles, int ntiles) {
    int z = blockIdx.z;
    int wave = threadIdx.x >> 6;
    int wid = blockIdx.x * 4 + wave;
    int maxw = mtiles * ntiles;
    int widc = wid < maxw ? wid : maxw - 1;
    bool act = wid < maxw;
    int tm = widc / ntiles, tn = widc - tm * ntiles;
    int m0 = tm * 16, n0 = tn * 32;
    int lane = threadIdx.x & 63, lq = lane & 15, quad = lane >> 4;
    const short* Wt = (const short*)p.Wt[z];
    const short* Ab = (const short*)A;

    __shared__ float sred[4][16][2];

    size_t rowA  = (size_t)(m0 + lq) * K;
    size_t rowB0 = (size_t)(n0 + lq) * K;
    size_t rowB1 = (size_t)(n0 + 16 + lq) * K;

    floatx4 acc0 = {0.f, 0.f, 0.f, 0.f}, acc1 = acc0;
    #pragma unroll 4
    for (int k0 = 0; k0 < K; k0 += 32) {
        short8 af = *(const short8*)(Ab + rowA + k0 + quad * 8);
        short8 b0 = *(const short8*)(Wt + rowB0 + k0 + quad * 8);
        short8 b1 = *(const short8*)(Wt + rowB1 + k0 + quad * 8);
        acc0 = __builtin_amdgcn_mfma_f32_16x16x32_bf16(af, b0, acc0, 0, 0, 0);
        acc1 = __builtin_amdgcn_mfma_f32_16x16x32_bf16(af, b1, acc1, 0, 0, 0);
    }

    int mode = p.md[z];
    float scl = p.scl[z];
    float* outF = p.outF[z];
    ushort_t* outB = p.outB[z];
    int c0 = n0 + lq, c1 = n0 + 16 + lq;
    float bv0 = p.bias[z][c0], bv1 = p.bias[z][c1];

    if (mode == 4) {
        // fused residual + LayerNorm (block covers full rows; N == 128)
        float vv0[4], vv1[4];
        #pragma unroll
        for (int rg = 0; rg < 4; ++rg) {
            int r = m0 + quad * 4 + rg;
            float a0 = acc0[rg] + bv0 + res[(size_t)r * N + c0];
            float a1 = acc1[rg] + bv1 + res[(size_t)r * N + c1];
            outF[(size_t)r * N + c0] = a0;
            outF[(size_t)r * N + c1] = a1;
            vv0[rg] = a0; vv1[rg] = a1;
        }
        #pragma unroll
        for (int rg = 0; rg < 4; ++rg) {
            float s1 = vv0[rg] + vv1[rg];
            float s2 = vv0[rg]*vv0[rg] + vv1[rg]*vv1[rg];
            #pragma unroll
            for (int m = 1; m < 16; m <<= 1) {
                s1 += __shfl_xor(s1, m, 64);
                s2 += __shfl_xor(s2, m, 64);
            }
            if (lq == 0) { sred[wave][quad*4+rg][0] = s1; sred[wave][quad*4+rg][1] = s2; }
        }
        __syncthreads();
        const float* gg = p.lng[z];
        const float* bb = p.lnb[z];
        float g0 = gg[c0], g1 = gg[c1], lb0 = bb[c0], lb1 = bb[c1];
        #pragma unroll
        for (int rg = 0; rg < 4; ++rg) {
            int row = quad * 4 + rg;
            float S1 = sred[0][row][0] + sred[1][row][0] + sred[2][row][0] + sred[3][row][0];
            float S2 = sred[0][row][1] + sred[1][row][1] + sred[2][row][1] + sred[3][row][1];
            float mn = S1 * (1.0f/CC);
            float var = S2 * (1.0f/CC) - mn * mn;
            float rs = rsqrtf(var + 1e-5f);
            int r = m0 + row;
            outB[(size_t)r * N + c0] = f2bf((vv0[rg] - mn) * rs * g0 + lb0);
            outB[(size_t)r * N + c1] = f2bf((vv1[rg] - mn) * rs * g1 + lb1);
        }
        return;
    }

    if (!act) return;
    #pragma unroll
    for (int rg = 0; rg < 4; ++rg) {
        int r = m0 + quad * 4 + rg;
        if (r >= M) continue;
        float a0 = acc0[rg] + bv0;
        float a1 = acc1[rg] + bv1;
        if (mode == 0) {
            outB[(size_t)r * N + c0] = f2bf(a0 * scl);
            outB[(size_t)r * N + c1] = f2bf(a1 * scl);
        } else if (mode == 1) {
            outF[(size_t)r * N + c0] = a0 + res[(size_t)r * N + c0];
            outF[(size_t)r * N + c1] = a1 + res[(size_t)r * N + c1];
        } else if (mode == 2) {
            outB[(size_t)r * N + c0] = f2bf(gelu_exact(a0));
            outB[(size_t)r * N + c1] = f2bf(gelu_exact(a1));
        } else {
            int bq = r / TT;
            int s = r - bq * TT;
            outB[((size_t)(bq * HH + (c0 >> 4)) * DD + (c0 & 15)) * SP + s] = f2bf(a0);
            outB[((size_t)(bq * HH + (c1 >> 4)) * DD + (c1 & 15)) * SP + s] = f2bf(a1);
        }
    }
}

// ---------------- MFMA fused attention: one block per (bh, 16-query tile) ----------------
// Grid (128, 33), 256 thr = 4 waves. K frags from global kb, V^T frags from
// pre-transposed global vt (both L1/L2). Bias strip in LDS [q][s], 2 s-chunks
// (<=288 rows) -> 18.7 KB total, ~7 blocks/CU. P C->B layout via 8 shfls (no
// LDS round-trip). Depth-1 K/V prefetch. Q pre-scaled 0.25 in QKV epilogue.
__global__ __launch_bounds__(256) void attn_kernel(const ushort_t* __restrict__ qb,
                                                   const ushort_t* __restrict__ kb,
                                                   const ushort_t* __restrict__ vt,
                                                   const int* __restrict__ cnt,
                                                   const int* __restrict__ ebuf,
                                                   const float* __restrict__ ebt,
                                                   const float* __restrict__ vnode,
                                                   ushort_t* __restrict__ ob) {
    int bh = blockIdx.x;
    int qt = blockIdx.y;
    int b = bh >> 3, h = bh & (HH - 1);
    int tid = threadIdx.x;
    int wave = tid >> 6, lane = tid & 63, lq = lane & 15, quad = lane >> 4;

    __shared__ float arena[16 * BSTR];   // strip [q][s] (aliased by epilogue bufs)
    float* bstrip = arena;

    // hoisted global loads (latency overlaps strip build)
    int qg = qt * 16 + lq;
    int qr = qg < TT ? qg : TT - 1;
    short8 qf = {0,0,0,0,0,0,0,0};
    if (quad < 2)
        qf = *(const short8*)(qb + ((size_t)(b * TT + qr)) * CC + h * DD + quad * 8);
    float vbh = vnode[h];
    int ql = tid >> 4, e0 = tid & 15;
    int qs = qt * 16 + ql;
    int crow = b * TT + (qs < TT ? qs : 0);
    int cn = (qs > 0 && qs < TT) ? min(cnt[crow], ECAP) : 0;

    const short* kbS = (const short*)kb;
    const short* vtS = (const short*)(vt + (size_t)bh * DD * SP);

    floatx4 oacc = {0.f, 0.f, 0.f, 0.f};
    float lsum = 0.f;

    #pragma unroll
    for (int ch = 0; ch < 2; ++ch) {
        int sp_lo = ch ? 9 : 0;
        int sp_hi = ch ? 17 : 9;
        int s_lo  = ch ? 288 : 0;
        int nrows = ch ? 256 : 288;

        // prefetch first sp of this chunk (strip-independent)
        int sp = sp_lo + wave;
        short8 af0 = {0,0,0,0,0,0,0,0}, af1 = af0, vf = af0;
        if (sp < sp_hi) {
            int st0 = sp * 2, st1 = sp * 2 + 1;
            int kr0 = min(b * TT + st0 * 16 + lq, (int)XROWS - 1);
            int kr1 = min(b * TT + st1 * 16 + lq, (int)XROWS - 1);
            if (quad < 2) {
                af0 = *(const short8*)(kbS + (size_t)kr0 * CC + h * DD + quad * 8);
                af1 = *(const short8*)(kbS + (size_t)kr1 * CC + h * DD + quad * 8);
            }
            vf = *(const short8*)(vtS + (size_t)lq * SP + sp * 32 + quad * 8);
        }

        // zero strip (float4)
        for (int i = tid; i < 16 * BSTR / 4; i += 256)
            ((float4*)bstrip)[i] = make_float4(0.f, 0.f, 0.f, 0.f);
        __syncthreads();
        // vnode bias on s==0 (chunk 0 only; q==0 row uniform over s -> cancels)
        if (ch == 0 && tid < 16) {
            int q = qt * 16 + tid;
            if (q > 0 && q < TT) bstrip[tid * BSTR] = vbh;
        }
        // scatter this q-tile's edges falling in [s_lo, s_lo+nrows)   (dl >= 1)
        for (int j = e0; j < cn; j += 16) {
            int e = ebuf[(size_t)crow * ECAP + j];
            int dl = e & 0xFFFF, a = e >> 16;
            int loc = dl - s_lo;
            if (loc >= 0 && loc < nrows)
                atomicAdd(&bstrip[ql * BSTR + loc], ebt[a * 8 + h]);
        }
        __syncthreads();

        for (; sp < sp_hi; sp += 4) {
            int spn = sp + 4;
            short8 nf0 = {0,0,0,0,0,0,0,0}, nf1 = nf0, nvf = nf0;
            if (spn < sp_hi) {
                int st0 = spn * 2, st1 = spn * 2 + 1;
                int kr0 = min(b * TT + st0 * 16 + lq, (int)XROWS - 1);
                int kr1 = min(b * TT + st1 * 16 + lq, (int)XROWS - 1);
                if (quad < 2) {
                    nf0 = *(const short8*)(kbS + (size_t)kr0 * CC + h * DD + quad * 8);
                    nf1 = *(const short8*)(kbS + (size_t)kr1 * CC + h * DD + quad * 8);
                }
                nvf = *(const short8*)(vtS + (size_t)lq * SP + spn * 32 + quad * 8);
            }

            unsigned pw[2][2];
            #pragma unroll
            for (int t = 0; t < 2; ++t) {
                int st = sp * 2 + t;
                floatx4 c = __builtin_amdgcn_mfma_f32_16x16x32_bf16(
                    t ? af1 : af0, qf, (floatx4){0.f, 0.f, 0.f, 0.f}, 0, 0, 0);
                float4 bi = *(const float4*)(bstrip + lq * BSTR + (st * 16 - s_lo) + quad * 4);
                float biv[4] = {bi.x, bi.y, bi.z, bi.w};
                float pr[4];
                #pragma unroll
                for (int rg = 0; rg < 4; ++rg) {
                    int s = st * 16 + quad * 4 + rg;
                    float p = 0.f;
                    if (s < TT) p = __expf(c[rg] + biv[rg]);
                    lsum += p;
                    pr[rg] = p;
                }
                pw[t][0] = (unsigned)f2bf(pr[0]) | ((unsigned)f2bf(pr[1]) << 16);
                pw[t][1] = (unsigned)f2bf(pr[2]) | ((unsigned)f2bf(pr[3]) << 16);
            }
            // C-layout -> B-layout: quad permutation among lanes sharing lq
            int srcA = lq + (((2 * quad) & 3) << 4);
            int srcB = lq + (((2 * quad + 1) & 3) << 4);
            int a00 = __shfl((int)pw[0][0], srcA, 64);
            int a01 = __shfl((int)pw[0][1], srcA, 64);
            int a10 = __shfl((int)pw[1][0], srcA, 64);
            int a11 = __shfl((int)pw[1][1], srcA, 64);
            int b00 = __shfl((int)pw[0][0], srcB, 64);
            int b01 = __shfl((int)pw[0][1], srcB, 64);
            int b10 = __shfl((int)pw[1][0], srcB, 64);
            int b11 = __shfl((int)pw[1][1], srcB, 64);
            union { int u[4]; short8 s8; } pu;
            bool lo = quad < 2;
            pu.u[0] = lo ? a00 : a10;
            pu.u[1] = lo ? a01 : a11;
            pu.u[2] = lo ? b00 : b10;
            pu.u[3] = lo ? b01 : b11;
            oacc = __builtin_amdgcn_mfma_f32_16x16x32_bf16(vf, pu.s8, oacc, 0, 0, 0);

            af0 = nf0; af1 = nf1; vf = nvf;
        }
        __syncthreads();   // strip rebuilt next chunk / aliased by epilogue
    }

    // reduce expsum across quads
    lsum += __shfl_xor(lsum, 16, 64);
    lsum += __shfl_xor(lsum, 32, 64);
    // epilogue buffers alias the strip arena (all strip reads done)
    float* redw = arena;               // [w][d=16][q stride 17] = 1088 floats
    float* lsumS = arena + 1088;       // [w][16]
    #pragma unroll
    for (int rg = 0; rg < 4; ++rg)
        redw[wave * 272 + (quad * 4 + rg) * 17 + lq] = oacc[rg];
    if (quad == 0) lsumS[wave * 16 + lq] = lsum;
    __syncthreads();

    // cross-wave combine + store: thread (q=tid>>4, d=tid&15), d contiguous
    {
        int q = tid >> 4, d = tid & 15;
        float o = 0.f, L = 0.f;
        #pragma unroll
        for (int w = 0; w < 4; ++w) {
            o += redw[w * 272 + d * 17 + q];
            L += lsumS[w * 16 + q];
        }
        int qq = qt * 16 + q;
        if (qq < TT)
            ob[((size_t)(b * TT + qq)) * CC + h * DD + d] = f2bf(o / L);
    }
}

// ---------------- final LN on graph tokens + classifier ----------------
__global__ __launch_bounds__(128) void head_kernel(const float* __restrict__ x,
                                                   const float* __restrict__ ng,
                                                   const float* __restrict__ nb,
                                                   const float* __restrict__ Wc1,
                                                   const float* __restrict__ bc1,
                                                   const float* __restrict__ Wc2,
                                                   const float* __restrict__ bc2,
                                                   float* __restrict__ out) {
    int b = blockIdx.x;
    int c = threadIdx.x;
    __shared__ float xfs[CC];
    __shared__ float c1s[64];
    __shared__ float red[4];

    float v = x[((size_t)b * TT) * CC + c];
    float s1 = v, s2 = v * v;
    #pragma unroll
    for (int m = 32; m >= 1; m >>= 1) {
        s1 += __shfl_xor(s1, m, 64);
        s2 += __shfl_xor(s2, m, 64);
    }
    int w = c >> 6;
    if ((c & 63) == 0) { red[w*2] = s1; red[w*2+1] = s2; }
    __syncthreads();
    float S1 = red[0] + red[2], S2 = red[1] + red[3];
    float mn = S1 * (1.0f/CC);
    float var = S2 * (1.0f/CC) - mn * mn;
    float rs = rsqrtf(var + 1e-5f);
    xfs[c] = (v - mn) * rs * ng[c] + nb[c];
    __syncthreads();
    if (c < 64) {
        float a = bc1[c];
        #pragma unroll 4
        for (int k = 0; k < CC; ++k) a = fmaf(xfs[k], Wc1[(size_t)k * 64 + c], a);
        c1s[c] = gelu_exact(a);
    }
    __syncthreads();
    if (c < NCLS) {
        float a = bc2[c];
        #pragma unroll 4
        for (int j = 0; j < 64; ++j) a = fmaf(c1s[j], Wc2[(size_t)j * NCLS + c], a);
        out[(size_t)b * NCLS + c] = a;
    }
}

extern "C" void kernel_launch(void* const* d_in, const int* in_sizes, int n_in,
                              void* d_out, int out_size, void* d_ws, size_t ws_size,
                              hipStream_t stream) {
    const float* node_feats = (const float*)d_in[0];
    const int*   edge_index = (const int*)d_in[1];
    const int*   edge_attr  = (const int*)d_in[2];
    const float* W_node  = (const float*)d_in[4];
    const float* b_node  = (const float*)d_in[5];
    const float* g_token = (const float*)d_in[6];
    const float* ebt     = (const float*)d_in[7];
    const float* ide     = (const float*)d_in[8];
    const float* ode     = (const float*)d_in[9];
    const float* vnode   = (const float*)d_in[10];
    const float* Wq = (const float*)d_in[11];
    const float* bq = (const float*)d_in[12];
    const float* Wk = (const float*)d_in[13];
    const float* bk = (const float*)d_in[14];
    const float* Wv = (const float*)d_in[15];
    const float* bv = (const float*)d_in[16];
    const float* Wo = (const float*)d_in[17];
    const float* bo = (const float*)d_in[18];
    const float* ln1g = (const float*)d_in[19];
    const float* ln1b = (const float*)d_in[20];
    const float* ln2g = (const float*)d_in[21];
    const float* ln2b = (const float*)d_in[22];
    const float* W1 = (const float*)d_in[23];
    const float* b1 = (const float*)d_in[24];
    const float* W2 = (const float*)d_in[25];
    const float* b2 = (const float*)d_in[26];
    const float* nfg = (const float*)d_in[27];
    const float* nfb = (const float*)d_in[28];
    const float* Wc1 = (const float*)d_in[29];
    const float* bc1 = (const float*)d_in[30];
    const float* Wc2 = (const float*)d_in[31];
    const float* bc2 = (const float*)d_in[32];
    float* out = (float*)d_out;

    // ---- workspace (all chunks 16B-aligned) ----
    char* base = (char*)d_ws;
    float* x      = (float*)base;     base += XSZ * 4;
    ushort_t* hbf = (ushort_t*)base;  base += XSZ * 2;
    ushort_t* qb  = (ushort_t*)base;  base += XSZ * 2;
    ushort_t* kb  = (ushort_t*)base;  base += XSZ * 2;
    ushort_t* vt  = (ushort_t*)base;  base += VTSZ * 2;
    ushort_t* obf = (ushort_t*)base;  base += XSZ * 2;
    ushort_t* mid = (ushort_t*)base;  base += MIDSZ * 2;
    ushort_t* wtqkvo = (ushort_t*)base; base += (size_t)16 * 16384 * 2;
    ushort_t* wt1 = (ushort_t*)base;  base += (size_t)4 * 65536 * 2;
    ushort_t* wt2 = (ushort_t*)base;  base += (size_t)4 * 65536 * 2;
    int* deg_in  = (int*)base;        base += NNODES * 4;
    int* deg_out = (int*)base;        base += NNODES * 4;
    int* cnt     = (int*)base;        base += (size_t)ROWS * 4;
    int* ebuf    = (int*)base;        base += (size_t)ROWS * ECAP * 4;

    hipMemsetAsync(deg_in, 0, (size_t)(2 * NNODES + ROWS) * 4, stream);
    deg_csr_kernel<<<EE / 256, 256, 0, stream>>>(edge_index, edge_attr,
                                                 deg_in, deg_out, cnt, ebuf);
    encode_kernel<<<(int)((XROWS * CC + 255) / 256), 256, 0, stream>>>(
        node_feats, W_node, b_node, g_token, ide, ode, deg_in, deg_out, x);

    TrDesc td;
    for (int l = 0; l < LL; ++l) {
        const float* srcs[4] = {Wq + (size_t)l*CC*CC, Wk + (size_t)l*CC*CC,
                                Wv + (size_t)l*CC*CC, Wo + (size_t)l*CC*CC};
        for (int k = 0; k < 4; ++k) {
            int slot = k * 4 + l;
            td.src[slot] = srcs[k];
            td.dst[slot] = wtqkvo + (size_t)slot * 16384;
            td.K[slot] = CC; td.N[slot] = CC;
        }
        td.src[16 + l] = W1 + (size_t)l*CC*FFN;
        td.dst[16 + l] = wt1 + (size_t)l*65536;
        td.K[16 + l] = CC; td.N[16 + l] = FFN;
        td.src[20 + l] = W2 + (size_t)l*FFN*CC;
        td.dst[20 + l] = wt2 + (size_t)l*65536;
        td.K[20 + l] = FFN; td.N[20 + l] = CC;
    }
    tr_kernel<<<dim3(16, 1, 24), 256, 0, stream>>>(td);

    const int MT16 = (int)(XROWS / 16);   // 513 m-tiles of 16 rows (exact)

    // layer 0's ln1 is standalone; later ln1's are fused into ffn2 epilogues
    ln_kernel<<<(int)(XROWS / 2), 256, 0, stream>>>(x, hbf, ln1g, ln1b);

    for (int l = 0; l < LL; ++l) {
        GP pq = {};
        pq.Wt[0] = wtqkvo + (size_t)(0*4+l)*16384;
        pq.Wt[1] = wtqkvo + (size_t)(1*4+l)*16384;
        pq.Wt[2] = wtqkvo + (size_t)(2*4+l)*16384;
        pq.bias[0] = bq + l*CC; pq.bias[1] = bk + l*CC; pq.bias[2] = bv + l*CC;
        pq.outB[0] = qb; pq.outB[1] = kb; pq.outB[2] = vt;
        pq.scl[0] = 0.25f; pq.scl[1] = 1.0f; pq.scl[2] = 1.0f;  // fold 1/sqrt(D) into Q
        pq.md[0] = 0; pq.md[1] = 0; pq.md[2] = 3;               // V written transposed
        gemm_wave<CC><<<dim3(MT16, 1, 3), 256, 0, stream>>>(
            hbf, pq, nullptr, (int)XROWS, CC, MT16, 4);

        attn_kernel<<<dim3(BB*HH, 33), 256, 0, stream>>>(
            qb, kb, vt, cnt, ebuf, ebt, vnode, obf);

        // O-proj + residual + ln2 fused
        GP po = {};
        po.Wt[0] = wtqkvo + (size_t)(3*4+l)*16384;
        po.bias[0] = bo + l*CC; po.outF[0] = x; po.outB[0] = hbf;
        po.lng[0] = ln2g + l*CC; po.lnb[0] = ln2b + l*CC;
        po.scl[0] = 1.0f; po.md[0] = 4;
        gemm_wave<CC><<<dim3(MT16, 1, 1), 256, 0, stream>>>(
            obf, po, x, (int)XROWS, CC, MT16, 4);

        GP p1 = {};
        p1.Wt[0] = wt1 + (size_t)l*65536;
        p1.bias[0] = b1 + l*FFN; p1.outB[0] = mid; p1.scl[0] = 1.0f; p1.md[0] = 2;
        gemm_wave<CC><<<dim3(MT16*4, 1, 1), 256, 0, stream>>>(
            hbf, p1, nullptr, (int)XROWS, FFN, MT16, 16);

        // FFN2 + residual + next layer's ln1 fused (l==3 output unused; head reads x)
        int ln_next = (l + 1) % LL;
        GP p2 = {};
        p2.Wt[0] = wt2 + (size_t)l*65536;
        p2.bias[0] = b2 + l*CC; p2.outF[0] = x; p2.outB[0] = hbf;
        p2.lng[0] = ln1g + ln_next*CC; p2.lnb[0] = ln1b + ln_next*CC;
        p2.scl[0] = 1.0f; p2.md[0] = 4;
        gemm_wave<FFN><<<dim3(MT16, 1, 1), 256, 0, stream>>>(
            mid, p2, x, (int)XROWS, CC, MT16, 4);
    }

    head_kernel<<<BB, 128, 0, stream>>>(x, nfg, nfb, Wc1, bc1, Wc2, bc2, out);
}

// Round 8
// 452.168 us; speedup vs baseline: 2.9774x; 1.1356x over previous
//
#include <hip/hip_runtime.h>
#include <hip/hip_bf16.h>

#define BB 16
#define NPG 512
#define CC 128
#define HH 8
#define LL 4
#define FFN 512
#define NCLS 4
#define DD 16
#define TT 513            // NPG + 1
#define EE 131072         // B * 8192
#define NNODES 8192       // B * NPG
#define ROWS (BB * TT)    // 8208 CSR rows keyed by (g, sl=query)
#define ECAP 64           // entries per bucket; Poisson(16), P(>=64) ~ 3e-22
#define SP 544            // padded s extent (34 tiles of 16)
#define BSTR 292          // bias strip stride (floats), mult of 4 for b128

static constexpr size_t XROWS = (size_t)BB * TT;   // 8208 (= 513 * 16 exactly)
static constexpr size_t XSZ   = XROWS * CC;        // 1,050,624
static constexpr size_t VTSZ  = (size_t)BB * HH * DD * SP;  // 1,114,112

typedef unsigned short ushort_t;
typedef __attribute__((ext_vector_type(8))) short short8;
typedef __attribute__((ext_vector_type(4))) float floatx4;

__device__ __forceinline__ float gelu_exact(float v) {
    return 0.5f * v * (1.0f + erff(v * 0.70710678118654752440f));
}
__device__ __forceinline__ ushort_t f2bf(float f) {
    union { float f; unsigned u; } c; c.f = f;
    unsigned u = c.u;
    return (ushort_t)((u + 0x7FFFu + ((u >> 16) & 1u)) >> 16);   // RNE
}
// XOR-swizzled LDS offset (16B granules); stride in shorts, multiple of 8
__device__ __forceinline__ int swz(int row, int col, int stride) {
    int kb = col >> 3;
    return row * stride + (((kb ^ (row & 7)) << 3) | (col & 7));
}

// ---------------- degree count + query-keyed CSR build (merged) ----------------
__global__ __launch_bounds__(256) void deg_csr_kernel(const int* __restrict__ ei,
                                                      const int* __restrict__ ea,
                                                      int* __restrict__ deg_in,
                                                      int* __restrict__ deg_out,
                                                      int* __restrict__ cnt,
                                                      int* __restrict__ ebuf) {
    int e = blockIdx.x * 256 + threadIdx.x;
    if (e >= EE) return;
    int src = ei[e], dst = ei[EE + e];
    atomicAdd(&deg_out[src], 1);
    atomicAdd(&deg_in[dst], 1);
    int g = src >> 9;
    int sl = src - (g << 9) + 1;     // query index 1..512
    int dl = dst - (g << 9) + 1;     // key   index 1..512
    int a = ea[e];
    a = (a < 0) ? 0 : (a > 9 ? 9 : a);
    a += 1;                          // ebt row 1..10
    int row = g * TT + sl;           // query-keyed bucket
    int pos = atomicAdd(&cnt[row], 1);
    if (pos < ECAP) ebuf[(size_t)row * ECAP + pos] = dl | (a << 16);
}

// ---------------- node encode + graph token ----------------
__global__ __launch_bounds__(256) void encode_kernel(const float* __restrict__ nf,
                                                     const float* __restrict__ Wn,
                                                     const float* __restrict__ bn,
                                                     const float* __restrict__ gt,
                                                     const float* __restrict__ ide,
                                                     const float* __restrict__ ode,
                                                     const int* __restrict__ deg_in,
                                                     const int* __restrict__ deg_out,
                                                     float* __restrict__ x) {
    int gid = blockIdx.x * 256 + threadIdx.x;
    if (gid >= (int)(XROWS * CC)) return;
    int c = gid & (CC - 1);
    int row = gid >> 7;
    int b = row / TT;
    int t = row - b * TT;
    float val;
    if (t == 0) {
        val = gt[c];
    } else {
        int i = b * NPG + t - 1;
        val = bn[c] + nf[i*3+0]*Wn[0*CC + c] + nf[i*3+1]*Wn[1*CC + c] + nf[i*3+2]*Wn[2*CC + c];
        int di = min(deg_in[i], 511);
        int dq = min(deg_out[i], 511);
        val += ide[(size_t)di * CC + c] + ode[(size_t)dq * CC + c];
    }
    x[(size_t)row * CC + c] = val;
}

// ---------------- LDS-tiled weight transpose + bf16: Wt[n][k] = W[k][n] ----------------
struct TrDesc {
    const float* src[24];
    ushort_t*    dst[24];
    int          K[24];
    int          N[24];
};
__global__ __launch_bounds__(256) void tr_kernel(TrDesc d) {
    int z = blockIdx.z;
    int K = d.K[z], N = d.N[z];
    int tilesN = N >> 6;
    int ntile = (K >> 6) * tilesN;
    int tile = blockIdx.x;
    if (tile >= ntile) return;
    int k0 = (tile / tilesN) << 6;
    int n0 = (tile - (tile / tilesN) * tilesN) << 6;
    const float* src = d.src[z];
    ushort_t* dst = d.dst[z];
    __shared__ float t[64][65];
    int tid = threadIdx.x;
    int c = tid & 63, rb = tid >> 6;
    #pragma unroll
    for (int kk = 0; kk < 64; kk += 4)
        t[kk + rb][c] = src[(size_t)(k0 + kk + rb) * N + n0 + c];
    __syncthreads();
    #pragma unroll
    for (int nn = 0; nn < 64; nn += 4)
        dst[(size_t)(n0 + nn + rb) * K + k0 + c] = f2bf(t[c][nn + rb]);
}

// ---------------- LayerNorm (2 rows / 256-thread block), f32 in -> bf16 out ----------------
__global__ __launch_bounds__(256) void ln_kernel(const float* __restrict__ in,
                                                 ushort_t* __restrict__ out,
                                                 const float* __restrict__ gg,
                                                 const float* __restrict__ bb) {
    int tid = threadIdx.x;
    int r2 = tid >> 7;
    int c = tid & 127;
    int row = blockIdx.x * 2 + r2;
    float v = in[(size_t)row * CC + c];
    float s1 = v, s2 = v * v;
    #pragma unroll
    for (int m = 32; m >= 1; m >>= 1) {
        s1 += __shfl_xor(s1, m, 64);
        s2 += __shfl_xor(s2, m, 64);
    }
    __shared__ float red[8];
    int w = tid >> 6;
    if ((tid & 63) == 0) { red[w*2] = s1; red[w*2+1] = s2; }
    __syncthreads();
    int wb = r2 * 4;
    float S1 = red[wb] + red[wb+2], S2 = red[wb+1] + red[wb+3];
    float mn = S1 * (1.0f/CC);
    float var = S2 * (1.0f/CC) - mn * mn;
    float rs = rsqrtf(var + 1e-5f);
    out[(size_t)row * CC + c] = f2bf((v - mn) * rs * gg[c] + bb[c]);
}

// ---------------- per-wave 16x32-tile MFMA bf16 GEMM (QKV) ----------------
// md: 0 = (acc+bias)*scl -> bf16 ; 3 = acc+bias -> VT[bh][d][s] bf16
struct GP {
    const ushort_t* Wt[3];
    const float*    bias[3];
    ushort_t*       outB[3];
    float           scl[3];
    int             md[3];
};
template<int K>
__global__ __launch_bounds__(256) void gemm_wave(const ushort_t* __restrict__ A, GP p,
                                                 int M, int N,
                                                 int mtiles, int ntiles) {
    int z = blockIdx.z;
    int wave = threadIdx.x >> 6;
    int wid = blockIdx.x * 4 + wave;
    int maxw = mtiles * ntiles;
    if (wid >= maxw) return;
    int tm = wid / ntiles, tn = wid - tm * ntiles;
    int m0 = tm * 16, n0 = tn * 32;
    int lane = threadIdx.x & 63, lq = lane & 15, quad = lane >> 4;
    const short* Wt = (const short*)p.Wt[z];
    const short* Ab = (const short*)A;

    size_t rowA  = (size_t)(m0 + lq) * K;
    size_t rowB0 = (size_t)(n0 + lq) * K;
    size_t rowB1 = (size_t)(n0 + 16 + lq) * K;

    floatx4 acc0 = {0.f, 0.f, 0.f, 0.f}, acc1 = acc0;
    #pragma unroll 4
    for (int k0 = 0; k0 < K; k0 += 32) {
        short8 af = *(const short8*)(Ab + rowA + k0 + quad * 8);
        short8 b0 = *(const short8*)(Wt + rowB0 + k0 + quad * 8);
        short8 b1 = *(const short8*)(Wt + rowB1 + k0 + quad * 8);
        acc0 = __builtin_amdgcn_mfma_f32_16x16x32_bf16(af, b0, acc0, 0, 0, 0);
        acc1 = __builtin_amdgcn_mfma_f32_16x16x32_bf16(af, b1, acc1, 0, 0, 0);
    }

    int mode = p.md[z];
    float scl = p.scl[z];
    ushort_t* outB = p.outB[z];
    int c0 = n0 + lq, c1 = n0 + 16 + lq;
    float bv0 = p.bias[z][c0], bv1 = p.bias[z][c1];

    #pragma unroll
    for (int rg = 0; rg < 4; ++rg) {
        int r = m0 + quad * 4 + rg;
        float a0 = acc0[rg] + bv0;
        float a1 = acc1[rg] + bv1;
        if (mode == 0) {
            outB[(size_t)r * N + c0] = f2bf(a0 * scl);
            outB[(size_t)r * N + c1] = f2bf(a1 * scl);
        } else {
            int bq = r / TT;
            int s = r - bq * TT;
            outB[((size_t)(bq * HH + (c0 >> 4)) * DD + (c0 & 15)) * SP + s] = f2bf(a0);
            outB[((size_t)(bq * HH + (c1 >> 4)) * DD + (c1 & 15)) * SP + s] = f2bf(a1);
        }
    }
}

// ---------------- mega kernel: o-proj + res + ln2 + ffn1 + gelu + ffn2 + res + ln1next ----
// Block = one 16-row tile (grid 513), 256 thr = 4 waves (wave n0 = wave*32).
// o-proj residual kept in registers through the FFN (same thread<->element map);
// h and mid tiles in LDS with XOR-16B-block swizzle (conflict-free A-frags).
__global__ __launch_bounds__(256) void mega_kernel(const ushort_t* __restrict__ obf,
                                                   const ushort_t* __restrict__ WtO,
                                                   const float* __restrict__ bo_,
                                                   const float* __restrict__ ln2g_,
                                                   const float* __restrict__ ln2b_,
                                                   const ushort_t* __restrict__ Wt1_,
                                                   const float* __restrict__ b1_,
                                                   const ushort_t* __restrict__ Wt2_,
                                                   const float* __restrict__ b2_,
                                                   const float* __restrict__ ln1g_,
                                                   const float* __restrict__ ln1b_,
                                                   float* __restrict__ x_,
                                                   ushort_t* __restrict__ hbf_) {
    int m0 = blockIdx.x * 16;
    int tid = threadIdx.x;
    int wave = tid >> 6, lane = tid & 63, lq = lane & 15, quad = lane >> 4;

    __shared__ ushort_t hs[16 * 128];    // ln2(h) tile, swizzled
    __shared__ ushort_t ms[16 * 512];    // gelu(mid) tile, swizzled
    __shared__ float sred[4][16][2];

    int n0 = wave * 32;
    int c0 = n0 + lq, c1 = n0 + 16 + lq;
    float vv0[4], vv1[4];   // o-proj residual, reused in ffn2 epilogue

    // ---- stage 1: o-proj (16x32 per wave, K=128) + res + ln2 -> hs ----
    {
        const short* Ab = (const short*)obf;
        const short* W = (const short*)WtO;
        size_t rowA = (size_t)(m0 + lq) * CC;
        size_t rB0 = (size_t)(n0 + lq) * CC, rB1 = (size_t)(n0 + 16 + lq) * CC;
        floatx4 a0 = {0.f,0.f,0.f,0.f}, a1 = a0;
        #pragma unroll
        for (int k0 = 0; k0 < CC; k0 += 32) {
            short8 af = *(const short8*)(Ab + rowA + k0 + quad * 8);
            short8 b0 = *(const short8*)(W + rB0 + k0 + quad * 8);
            short8 b1 = *(const short8*)(W + rB1 + k0 + quad * 8);
            a0 = __builtin_amdgcn_mfma_f32_16x16x32_bf16(af, b0, a0, 0, 0, 0);
            a1 = __builtin_amdgcn_mfma_f32_16x16x32_bf16(af, b1, a1, 0, 0, 0);
        }
        float bv0 = bo_[c0], bv1 = bo_[c1];
        #pragma unroll
        for (int rg = 0; rg < 4; ++rg) {
            int r = m0 + quad * 4 + rg;
            vv0[rg] = a0[rg] + bv0 + x_[(size_t)r * CC + c0];
            vv1[rg] = a1[rg] + bv1 + x_[(size_t)r * CC + c1];
        }
        #pragma unroll
        for (int rg = 0; rg < 4; ++rg) {
            float s1 = vv0[rg] + vv1[rg];
            float s2 = vv0[rg]*vv0[rg] + vv1[rg]*vv1[rg];
            #pragma unroll
            for (int m = 1; m < 16; m <<= 1) {
                s1 += __shfl_xor(s1, m, 64);
                s2 += __shfl_xor(s2, m, 64);
            }
            if (lq == 0) { sred[wave][quad*4+rg][0] = s1; sred[wave][quad*4+rg][1] = s2; }
        }
        __syncthreads();
        float g0 = ln2g_[c0], g1 = ln2g_[c1], lb0 = ln2b_[c0], lb1 = ln2b_[c1];
        #pragma unroll
        for (int rg = 0; rg < 4; ++rg) {
            int row = quad * 4 + rg;
            float S1 = sred[0][row][0] + sred[1][row][0] + sred[2][row][0] + sred[3][row][0];
            float S2 = sred[0][row][1] + sred[1][row][1] + sred[2][row][1] + sred[3][row][1];
            float mn = S1 * (1.0f/CC);
            float var = S2 * (1.0f/CC) - mn * mn;
            float rs = rsqrtf(var + 1e-5f);
            hs[swz(row, c0, 128)] = f2bf((vv0[rg] - mn) * rs * g0 + lb0);
            hs[swz(row, c1, 128)] = f2bf((vv1[rg] - mn) * rs * g1 + lb1);
        }
    }
    __syncthreads();

    // ---- stage 2: ffn1 (wave covers mid cols wave*128..+127, K=128) + gelu -> ms ----
    {
        const short* hsS = (const short*)hs;
        const short* W = (const short*)Wt1_;
        #pragma unroll
        for (int nt = 0; nt < 4; ++nt) {
            int n = wave * 128 + nt * 32;
            size_t rB0 = (size_t)(n + lq) * CC, rB1 = (size_t)(n + 16 + lq) * CC;
            floatx4 a0 = {0.f,0.f,0.f,0.f}, a1 = a0;
            #pragma unroll
            for (int k0 = 0; k0 < CC; k0 += 32) {
                short8 af = *(const short8*)(hsS + swz(lq, k0 + quad * 8, 128));
                short8 b0 = *(const short8*)(W + rB0 + k0 + quad * 8);
                short8 b1 = *(const short8*)(W + rB1 + k0 + quad * 8);
                a0 = __builtin_amdgcn_mfma_f32_16x16x32_bf16(af, b0, a0, 0, 0, 0);
                a1 = __builtin_amdgcn_mfma_f32_16x16x32_bf16(af, b1, a1, 0, 0, 0);
            }
            float bb0 = b1_[n + lq], bb1 = b1_[n + 16 + lq];
            #pragma unroll
            for (int rg = 0; rg < 4; ++rg) {
                int row = quad * 4 + rg;
                ms[swz(row, n + lq, 512)]      = f2bf(gelu_exact(a0[rg] + bb0));
                ms[swz(row, n + 16 + lq, 512)] = f2bf(gelu_exact(a1[rg] + bb1));
            }
        }
    }
    __syncthreads();

    // ---- stage 3: ffn2 (16x32 per wave, K=512 from ms) + res + ln1next ----
    {
        const short* msS = (const short*)ms;
        const short* W = (const short*)Wt2_;
        size_t rB0 = (size_t)(n0 + lq) * FFN, rB1 = (size_t)(n0 + 16 + lq) * FFN;
        floatx4 a0 = {0.f,0.f,0.f,0.f}, a1 = a0;
        #pragma unroll 4
        for (int k0 = 0; k0 < FFN; k0 += 32) {
            short8 af = *(const short8*)(msS + swz(lq, k0 + quad * 8, 512));
            short8 b0 = *(const short8*)(W + rB0 + k0 + quad * 8);
            short8 b1 = *(const short8*)(W + rB1 + k0 + quad * 8);
            a0 = __builtin_amdgcn_mfma_f32_16x16x32_bf16(af, b0, a0, 0, 0, 0);
            a1 = __builtin_amdgcn_mfma_f32_16x16x32_bf16(af, b1, a1, 0, 0, 0);
        }
        float bv0 = b2_[c0], bv1 = b2_[c1];
        float w0[4], w1[4];
        #pragma unroll
        for (int rg = 0; rg < 4; ++rg) {
            int r = m0 + quad * 4 + rg;
            w0[rg] = a0[rg] + bv0 + vv0[rg];
            w1[rg] = a1[rg] + bv1 + vv1[rg];
            x_[(size_t)r * CC + c0] = w0[rg];
            x_[(size_t)r * CC + c1] = w1[rg];
        }
        #pragma unroll
        for (int rg = 0; rg < 4; ++rg) {
            float s1 = w0[rg] + w1[rg];
            float s2 = w0[rg]*w0[rg] + w1[rg]*w1[rg];
            #pragma unroll
            for (int m = 1; m < 16; m <<= 1) {
                s1 += __shfl_xor(s1, m, 64);
                s2 += __shfl_xor(s2, m, 64);
            }
            if (lq == 0) { sred[wave][quad*4+rg][0] = s1; sred[wave][quad*4+rg][1] = s2; }
        }
        __syncthreads();
        float g0 = ln1g_[c0], g1 = ln1g_[c1], lb0 = ln1b_[c0], lb1 = ln1b_[c1];
        #pragma unroll
        for (int rg = 0; rg < 4; ++rg) {
            int row = quad * 4 + rg;
            float S1 = sred[0][row][0] + sred[1][row][0] + sred[2][row][0] + sred[3][row][0];
            float S2 = sred[0][row][1] + sred[1][row][1] + sred[2][row][1] + sred[3][row][1];
            float mn = S1 * (1.0f/CC);
            float var = S2 * (1.0f/CC) - mn * mn;
            float rs = rsqrtf(var + 1e-5f);
            int r = m0 + row;
            hbf_[(size_t)r * CC + c0] = f2bf((w0[rg] - mn) * rs * g0 + lb0);
            hbf_[(size_t)r * CC + c1] = f2bf((w1[rg] - mn) * rs * g1 + lb1);
        }
    }
}

// ---------------- MFMA fused attention: one block per (bh, 16-query tile) ----------------
__global__ __launch_bounds__(256) void attn_kernel(const ushort_t* __restrict__ qb,
                                                   const ushort_t* __restrict__ kb,
                                                   const ushort_t* __restrict__ vt,
                                                   const int* __restrict__ cnt,
                                                   const int* __restrict__ ebuf,
                                                   const float* __restrict__ ebt,
                                                   const float* __restrict__ vnode,
                                                   ushort_t* __restrict__ ob) {
    int bh = blockIdx.x;
    int qt = blockIdx.y;
    int b = bh >> 3, h = bh & (HH - 1);
    int tid = threadIdx.x;
    int wave = tid >> 6, lane = tid & 63, lq = lane & 15, quad = lane >> 4;

    __shared__ float arena[16 * BSTR];   // strip [q][s] (aliased by epilogue bufs)
    float* bstrip = arena;

    int qg = qt * 16 + lq;
    int qr = qg < TT ? qg : TT - 1;
    short8 qf = {0,0,0,0,0,0,0,0};
    if (quad < 2)
        qf = *(const short8*)(qb + ((size_t)(b * TT + qr)) * CC + h * DD + quad * 8);
    float vbh = vnode[h];
    int ql = tid >> 4, e0 = tid & 15;
    int qs = qt * 16 + ql;
    int crow = b * TT + (qs < TT ? qs : 0);
    int cn = (qs > 0 && qs < TT) ? min(cnt[crow], ECAP) : 0;

    const short* kbS = (const short*)kb;
    const short* vtS = (const short*)(vt + (size_t)bh * DD * SP);

    floatx4 oacc = {0.f, 0.f, 0.f, 0.f};
    float lsum = 0.f;

    #pragma unroll
    for (int ch = 0; ch < 2; ++ch) {
        int sp_lo = ch ? 9 : 0;
        int sp_hi = ch ? 17 : 9;
        int s_lo  = ch ? 288 : 0;
        int nrows = ch ? 256 : 288;

        int sp = sp_lo + wave;
        short8 af0 = {0,0,0,0,0,0,0,0}, af1 = af0, vf = af0;
        if (sp < sp_hi) {
            int st0 = sp * 2, st1 = sp * 2 + 1;
            int kr0 = min(b * TT + st0 * 16 + lq, (int)XROWS - 1);
            int kr1 = min(b * TT + st1 * 16 + lq, (int)XROWS - 1);
            if (quad < 2) {
                af0 = *(const short8*)(kbS + (size_t)kr0 * CC + h * DD + quad * 8);
                af1 = *(const short8*)(kbS + (size_t)kr1 * CC + h * DD + quad * 8);
            }
            vf = *(const short8*)(vtS + (size_t)lq * SP + sp * 32 + quad * 8);
        }

        for (int i = tid; i < 16 * BSTR / 4; i += 256)
            ((float4*)bstrip)[i] = make_float4(0.f, 0.f, 0.f, 0.f);
        __syncthreads();
        if (ch == 0 && tid < 16) {
            int q = qt * 16 + tid;
            if (q > 0 && q < TT) bstrip[tid * BSTR] = vbh;
        }
        for (int j = e0; j < cn; j += 16) {
            int e = ebuf[(size_t)crow * ECAP + j];
            int dl = e & 0xFFFF, a = e >> 16;
            int loc = dl - s_lo;
            if (loc >= 0 && loc < nrows)
                atomicAdd(&bstrip[ql * BSTR + loc], ebt[a * 8 + h]);
        }
        __syncthreads();

        for (; sp < sp_hi; sp += 4) {
            int spn = sp + 4;
            short8 nf0 = {0,0,0,0,0,0,0,0}, nf1 = nf0, nvf = nf0;
            if (spn < sp_hi) {
                int st0 = spn * 2, st1 = spn * 2 + 1;
                int kr0 = min(b * TT + st0 * 16 + lq, (int)XROWS - 1);
                int kr1 = min(b * TT + st1 * 16 + lq, (int)XROWS - 1);
                if (quad < 2) {
                    nf0 = *(const short8*)(kbS + (size_t)kr0 * CC + h * DD + quad * 8);
                    nf1 = *(const short8*)(kbS + (size_t)kr1 * CC + h * DD + quad * 8);
                }
                nvf = *(const short8*)(vtS + (size_t)lq * SP + spn * 32 + quad * 8);
            }

            unsigned pw[2][2];
            #pragma unroll
            for (int t = 0; t < 2; ++t) {
                int st = sp * 2 + t;
                floatx4 c = __builtin_amdgcn_mfma_f32_16x16x32_bf16(
                    t ? af1 : af0, qf, (floatx4){0.f, 0.f, 0.f, 0.f}, 0, 0, 0);
                float4 bi = *(const float4*)(bstrip + lq * BSTR + (st * 16 - s_lo) + quad * 4);
                float biv[4] = {bi.x, bi.y, bi.z, bi.w};
                float pr[4];
                #pragma unroll
                for (int rg = 0; rg < 4; ++rg) {
                    int s = st * 16 + quad * 4 + rg;
                    float p = 0.f;
                    if (s < TT) p = __expf(c[rg] + biv[rg]);
                    lsum += p;
                    pr[rg] = p;
                }
                pw[t][0] = (unsigned)f2bf(pr[0]) | ((unsigned)f2bf(pr[1]) << 16);
                pw[t][1] = (unsigned)f2bf(pr[2]) | ((unsigned)f2bf(pr[3]) << 16);
            }
            int srcA = lq + (((2 * quad) & 3) << 4);
            int srcB = lq + (((2 * quad + 1) & 3) << 4);
            int a00 = __shfl((int)pw[0][0], srcA, 64);
            int a01 = __shfl((int)pw[0][1], srcA, 64);
            int a10 = __shfl((int)pw[1][0], srcA, 64);
            int a11 = __shfl((int)pw[1][1], srcA, 64);
            int b00 = __shfl((int)pw[0][0], srcB, 64);
            int b01 = __shfl((int)pw[0][1], srcB, 64);
            int b10 = __shfl((int)pw[1][0], srcB, 64);
            int b11 = __shfl((int)pw[1][1], srcB, 64);
            union { int u[4]; short8 s8; } pu;
            bool lo = quad < 2;
            pu.u[0] = lo ? a00 : a10;
            pu.u[1] = lo ? a01 : a11;
            pu.u[2] = lo ? b00 : b10;
            pu.u[3] = lo ? b01 : b11;
            oacc = __builtin_amdgcn_mfma_f32_16x16x32_bf16(vf, pu.s8, oacc, 0, 0, 0);

            af0 = nf0; af1 = nf1; vf = nvf;
        }
        __syncthreads();
    }

    lsum += __shfl_xor(lsum, 16, 64);
    lsum += __shfl_xor(lsum, 32, 64);
    float* redw = arena;
    float* lsumS = arena + 1088;
    #pragma unroll
    for (int rg = 0; rg < 4; ++rg)
        redw[wave * 272 + (quad * 4 + rg) * 17 + lq] = oacc[rg];
    if (quad == 0) lsumS[wave * 16 + lq] = lsum;
    __syncthreads();

    {
        int q = tid >> 4, d = tid & 15;
        float o = 0.f, L = 0.f;
        #pragma unroll
        for (int w = 0; w < 4; ++w) {
            o += redw[w * 272 + d * 17 + q];
            L += lsumS[w * 16 + q];
        }
        int qq = qt * 16 + q;
        if (qq < TT)
            ob[((size_t)(b * TT + qq)) * CC + h * DD + d] = f2bf(o / L);
    }
}

// ---------------- final LN on graph tokens + classifier ----------------
__global__ __launch_bounds__(128) void head_kernel(const float* __restrict__ x,
                                                   const float* __restrict__ ng,
                                                   const float* __restrict__ nb,
                                                   const float* __restrict__ Wc1,
                                                   const float* __restrict__ bc1,
                                                   const float* __restrict__ Wc2,
                                                   const float* __restrict__ bc2,
                                                   float* __restrict__ out) {
    int b = blockIdx.x;
    int c = threadIdx.x;
    __shared__ float xfs[CC];
    __shared__ float c1s[64];
    __shared__ float red[4];

    float v = x[((size_t)b * TT) * CC + c];
    float s1 = v, s2 = v * v;
    #pragma unroll
    for (int m = 32; m >= 1; m >>= 1) {
        s1 += __shfl_xor(s1, m, 64);
        s2 += __shfl_xor(s2, m, 64);
    }
    int w = c >> 6;
    if ((c & 63) == 0) { red[w*2] = s1; red[w*2+1] = s2; }
    __syncthreads();
    float S1 = red[0] + red[2], S2 = red[1] + red[3];
    float mn = S1 * (1.0f/CC);
    float var = S2 * (1.0f/CC) - mn * mn;
    float rs = rsqrtf(var + 1e-5f);
    xfs[c] = (v - mn) * rs * ng[c] + nb[c];
    __syncthreads();
    if (c < 64) {
        float a = bc1[c];
        #pragma unroll 4
        for (int k = 0; k < CC; ++k) a = fmaf(xfs[k], Wc1[(size_t)k * 64 + c], a);
        c1s[c] = gelu_exact(a);
    }
    __syncthreads();
    if (c < NCLS) {
        float a = bc2[c];
        #pragma unroll 4
        for (int j = 0; j < 64; ++j) a = fmaf(c1s[j], Wc2[(size_t)j * NCLS + c], a);
        out[(size_t)b * NCLS + c] = a;
    }
}

extern "C" void kernel_launch(void* const* d_in, const int* in_sizes, int n_in,
                              void* d_out, int out_size, void* d_ws, size_t ws_size,
                              hipStream_t stream) {
    const float* node_feats = (const float*)d_in[0];
    const int*   edge_index = (const int*)d_in[1];
    const int*   edge_attr  = (const int*)d_in[2];
    const float* W_node  = (const float*)d_in[4];
    const float* b_node  = (const float*)d_in[5];
    const float* g_token = (const float*)d_in[6];
    const float* ebt     = (const float*)d_in[7];
    const float* ide     = (const float*)d_in[8];
    const float* ode     = (const float*)d_in[9];
    const float* vnode   = (const float*)d_in[10];
    const float* Wq = (const float*)d_in[11];
    const float* bq = (const float*)d_in[12];
    const float* Wk = (const float*)d_in[13];
    const float* bk = (const float*)d_in[14];
    const float* Wv = (const float*)d_in[15];
    const float* bv = (const float*)d_in[16];
    const float* Wo = (const float*)d_in[17];
    const float* bo = (const float*)d_in[18];
    const float* ln1g = (const float*)d_in[19];
    const float* ln1b = (const float*)d_in[20];
    const float* ln2g = (const float*)d_in[21];
    const float* ln2b = (const float*)d_in[22];
    const float* W1 = (const float*)d_in[23];
    const float* b1 = (const float*)d_in[24];
    const float* W2 = (const float*)d_in[25];
    const float* b2 = (const float*)d_in[26];
    const float* nfg = (const float*)d_in[27];
    const float* nfb = (const float*)d_in[28];
    const float* Wc1 = (const float*)d_in[29];
    const float* bc1 = (const float*)d_in[30];
    const float* Wc2 = (const float*)d_in[31];
    const float* bc2 = (const float*)d_in[32];
    float* out = (float*)d_out;

    // ---- workspace (all chunks 16B-aligned) ----
    char* base = (char*)d_ws;
    float* x      = (float*)base;     base += XSZ * 4;
    ushort_t* hbf = (ushort_t*)base;  base += XSZ * 2;
    ushort_t* qb  = (ushort_t*)base;  base += XSZ * 2;
    ushort_t* kb  = (ushort_t*)base;  base += XSZ * 2;
    ushort_t* vt  = (ushort_t*)base;  base += VTSZ * 2;
    ushort_t* obf = (ushort_t*)base;  base += XSZ * 2;
    ushort_t* wtqkvo = (ushort_t*)base; base += (size_t)16 * 16384 * 2;
    ushort_t* wt1 = (ushort_t*)base;  base += (size_t)4 * 65536 * 2;
    ushort_t* wt2 = (ushort_t*)base;  base += (size_t)4 * 65536 * 2;
    int* deg_in  = (int*)base;        base += NNODES * 4;
    int* deg_out = (int*)base;        base += NNODES * 4;
    int* cnt     = (int*)base;        base += (size_t)ROWS * 4;
    int* ebuf    = (int*)base;        base += (size_t)ROWS * ECAP * 4;

    hipMemsetAsync(deg_in, 0, (size_t)(2 * NNODES + ROWS) * 4, stream);
    deg_csr_kernel<<<EE / 256, 256, 0, stream>>>(edge_index, edge_attr,
                                                 deg_in, deg_out, cnt, ebuf);
    encode_kernel<<<(int)((XROWS * CC + 255) / 256), 256, 0, stream>>>(
        node_feats, W_node, b_node, g_token, ide, ode, deg_in, deg_out, x);

    TrDesc td;
    for (int l = 0; l < LL; ++l) {
        const float* srcs[4] = {Wq + (size_t)l*CC*CC, Wk + (size_t)l*CC*CC,
                                Wv + (size_t)l*CC*CC, Wo + (size_t)l*CC*CC};
        for (int k = 0; k < 4; ++k) {
            int slot = k * 4 + l;
            td.src[slot] = srcs[k];
            td.dst[slot] = wtqkvo + (size_t)slot * 16384;
            td.K[slot] = CC; td.N[slot] = CC;
        }
        td.src[16 + l] = W1 + (size_t)l*CC*FFN;
        td.dst[16 + l] = wt1 + (size_t)l*65536;
        td.K[16 + l] = CC; td.N[16 + l] = FFN;
        td.src[20 + l] = W2 + (size_t)l*FFN*CC;
        td.dst[20 + l] = wt2 + (size_t)l*65536;
        td.K[20 + l] = FFN; td.N[20 + l] = CC;
    }
    tr_kernel<<<dim3(16, 1, 24), 256, 0, stream>>>(td);

    const int MT16 = (int)(XROWS / 16);   // 513 m-tiles of 16 rows (exact)

    // layer 0's ln1 is standalone; later ln1's are fused into mega epilogues
    ln_kernel<<<(int)(XROWS / 2), 256, 0, stream>>>(x, hbf, ln1g, ln1b);

    for (int l = 0; l < LL; ++l) {
        GP pq = {};
        pq.Wt[0] = wtqkvo + (size_t)(0*4+l)*16384;
        pq.Wt[1] = wtqkvo + (size_t)(1*4+l)*16384;
        pq.Wt[2] = wtqkvo + (size_t)(2*4+l)*16384;
        pq.bias[0] = bq + l*CC; pq.bias[1] = bk + l*CC; pq.bias[2] = bv + l*CC;
        pq.outB[0] = qb; pq.outB[1] = kb; pq.outB[2] = vt;
        pq.scl[0] = 0.25f; pq.scl[1] = 1.0f; pq.scl[2] = 1.0f;  // fold 1/sqrt(D) into Q
        pq.md[0] = 0; pq.md[1] = 0; pq.md[2] = 3;               // V written transposed
        gemm_wave<CC><<<dim3(MT16, 1, 3), 256, 0, stream>>>(
            hbf, pq, (int)XROWS, CC, MT16, 4);

        attn_kernel<<<dim3(BB*HH, 33), 256, 0, stream>>>(
            qb, kb, vt, cnt, ebuf, ebt, vnode, obf);

        int ln_next = (l + 1) % LL;
        mega_kernel<<<MT16, 256, 0, stream>>>(
            obf,
            wtqkvo + (size_t)(3*4+l)*16384, bo + l*CC,
            ln2g + l*CC, ln2b + l*CC,
            wt1 + (size_t)l*65536, b1 + l*FFN,
            wt2 + (size_t)l*65536, b2 + l*CC,
            ln1g + ln_next*CC, ln1b + ln_next*CC,
            x, hbf);
    }

    head_kernel<<<BB, 128, 0, stream>>>(x, nfg, nfb, Wc1, bc1, Wc2, bc2, out);
}

// Round 9
// 436.012 us; speedup vs baseline: 3.0877x; 1.0371x over previous
//
#include <hip/hip_runtime.h>
#include <hip/hip_bf16.h>

#define BB 16
#define NPG 512
#define CC 128
#define HH 8
#define LL 4
#define FFN 512
#define NCLS 4
#define DD 16
#define TT 513            // NPG + 1
#define EE 131072         // B * 8192
#define NNODES 8192       // B * NPG
#define ROWS (BB * TT)    // 8208 CSR rows keyed by (g, sl=query)
#define ECAP 64           // entries per bucket; Poisson(16), P(>=64) ~ 3e-22
#define SP 544            // padded s extent (34 tiles of 16)
#define BSTR 292          // bias strip stride (floats), mult of 4 for b128

static constexpr size_t XROWS = (size_t)BB * TT;   // 8208 (= 513 * 16 exactly)
static constexpr size_t XSZ   = XROWS * CC;        // 1,050,624
static constexpr size_t VTSZ  = (size_t)BB * HH * DD * SP;  // 1,114,112

typedef unsigned short ushort_t;
typedef __attribute__((ext_vector_type(8))) short short8;
typedef __attribute__((ext_vector_type(4))) float floatx4;

__device__ __forceinline__ float gelu_exact(float v) {
    return 0.5f * v * (1.0f + erff(v * 0.70710678118654752440f));
}
__device__ __forceinline__ ushort_t f2bf(float f) {
    union { float f; unsigned u; } c; c.f = f;
    unsigned u = c.u;
    return (ushort_t)((u + 0x7FFFu + ((u >> 16) & 1u)) >> 16);   // RNE
}
// XOR-swizzled LDS offset (16B granules); stride in shorts, multiple of 8
__device__ __forceinline__ int swz(int row, int col, int stride) {
    int kb = col >> 3;
    return row * stride + (((kb ^ (row & 7)) << 3) | (col & 7));
}

// ---- shared QKV stage: hs (swizzled 16x128 ln1 tile) -> qb, kb, vt ----
// Wave covers cols n0=wave*32 of each of Q/K/V for rows m0..m0+15.
__device__ __forceinline__ void qkv_stage(const ushort_t* hs,
                                          const ushort_t* Wtq, const float* bq_,
                                          const ushort_t* Wtk, const float* bk_,
                                          const ushort_t* Wtv, const float* bv_,
                                          ushort_t* qb, ushort_t* kb, ushort_t* vt,
                                          int m0, int wave, int lq, int quad) {
    const short* hsS = (const short*)hs;
    int n0 = wave * 32;
    int c0 = n0 + lq, c1 = n0 + 16 + lq;
    const short* Ws[3] = {(const short*)Wtq, (const short*)Wtk, (const short*)Wtv};
    const float* bs[3] = {bq_, bk_, bv_};
    size_t rB0 = (size_t)(n0 + lq) * CC, rB1 = (size_t)(n0 + 16 + lq) * CC;

    #pragma unroll
    for (int m = 0; m < 3; ++m) {
        const short* W = Ws[m];
        floatx4 a0 = {0.f,0.f,0.f,0.f}, a1 = a0;
        #pragma unroll
        for (int k0 = 0; k0 < CC; k0 += 32) {
            short8 af = *(const short8*)(hsS + swz(lq, k0 + quad * 8, 128));
            short8 b0 = *(const short8*)(W + rB0 + k0 + quad * 8);
            short8 b1 = *(const short8*)(W + rB1 + k0 + quad * 8);
            a0 = __builtin_amdgcn_mfma_f32_16x16x32_bf16(af, b0, a0, 0, 0, 0);
            a1 = __builtin_amdgcn_mfma_f32_16x16x32_bf16(af, b1, a1, 0, 0, 0);
        }
        float bv0 = bs[m][c0], bv1 = bs[m][c1];
        #pragma unroll
        for (int rg = 0; rg < 4; ++rg) {
            int r = m0 + quad * 4 + rg;
            float v0 = a0[rg] + bv0;
            float v1 = a1[rg] + bv1;
            if (m == 0) {        // Q: fold 1/sqrt(D)=0.25 (exact)
                qb[(size_t)r * CC + c0] = f2bf(v0 * 0.25f);
                qb[(size_t)r * CC + c1] = f2bf(v1 * 0.25f);
            } else if (m == 1) { // K
                kb[(size_t)r * CC + c0] = f2bf(v0);
                kb[(size_t)r * CC + c1] = f2bf(v1);
            } else {             // V, written transposed VT[bh][d][s]
                int bg = r / TT;
                int s = r - bg * TT;
                vt[((size_t)(bg * HH + (c0 >> 4)) * DD + (c0 & 15)) * SP + s] = f2bf(v0);
                vt[((size_t)(bg * HH + (c1 >> 4)) * DD + (c1 & 15)) * SP + s] = f2bf(v1);
            }
        }
    }
}

// ---------------- degree count + query-keyed CSR build (merged) ----------------
__global__ __launch_bounds__(256) void deg_csr_kernel(const int* __restrict__ ei,
                                                      const int* __restrict__ ea,
                                                      int* __restrict__ deg_in,
                                                      int* __restrict__ deg_out,
                                                      int* __restrict__ cnt,
                                                      int* __restrict__ ebuf) {
    int e = blockIdx.x * 256 + threadIdx.x;
    if (e >= EE) return;
    int src = ei[e], dst = ei[EE + e];
    atomicAdd(&deg_out[src], 1);
    atomicAdd(&deg_in[dst], 1);
    int g = src >> 9;
    int sl = src - (g << 9) + 1;     // query index 1..512
    int dl = dst - (g << 9) + 1;     // key   index 1..512
    int a = ea[e];
    a = (a < 0) ? 0 : (a > 9 ? 9 : a);
    a += 1;                          // ebt row 1..10
    int row = g * TT + sl;           // query-keyed bucket
    int pos = atomicAdd(&cnt[row], 1);
    if (pos < ECAP) ebuf[(size_t)row * ECAP + pos] = dl | (a << 16);
}

// ---------------- node encode + graph token ----------------
__global__ __launch_bounds__(256) void encode_kernel(const float* __restrict__ nf,
                                                     const float* __restrict__ Wn,
                                                     const float* __restrict__ bn,
                                                     const float* __restrict__ gt,
                                                     const float* __restrict__ ide,
                                                     const float* __restrict__ ode,
                                                     const int* __restrict__ deg_in,
                                                     const int* __restrict__ deg_out,
                                                     float* __restrict__ x) {
    int gid = blockIdx.x * 256 + threadIdx.x;
    if (gid >= (int)(XROWS * CC)) return;
    int c = gid & (CC - 1);
    int row = gid >> 7;
    int b = row / TT;
    int t = row - b * TT;
    float val;
    if (t == 0) {
        val = gt[c];
    } else {
        int i = b * NPG + t - 1;
        val = bn[c] + nf[i*3+0]*Wn[0*CC + c] + nf[i*3+1]*Wn[1*CC + c] + nf[i*3+2]*Wn[2*CC + c];
        int di = min(deg_in[i], 511);
        int dq = min(deg_out[i], 511);
        val += ide[(size_t)di * CC + c] + ode[(size_t)dq * CC + c];
    }
    x[(size_t)row * CC + c] = val;
}

// ---------------- LDS-tiled weight transpose + bf16: Wt[n][k] = W[k][n] ----------------
struct TrDesc {
    const float* src[24];
    ushort_t*    dst[24];
    int          K[24];
    int          N[24];
};
__global__ __launch_bounds__(256) void tr_kernel(TrDesc d) {
    int z = blockIdx.z;
    int K = d.K[z], N = d.N[z];
    int tilesN = N >> 6;
    int ntile = (K >> 6) * tilesN;
    int tile = blockIdx.x;
    if (tile >= ntile) return;
    int k0 = (tile / tilesN) << 6;
    int n0 = (tile - (tile / tilesN) * tilesN) << 6;
    const float* src = d.src[z];
    ushort_t* dst = d.dst[z];
    __shared__ float t[64][65];
    int tid = threadIdx.x;
    int c = tid & 63, rb = tid >> 6;
    #pragma unroll
    for (int kk = 0; kk < 64; kk += 4)
        t[kk + rb][c] = src[(size_t)(k0 + kk + rb) * N + n0 + c];
    __syncthreads();
    #pragma unroll
    for (int nn = 0; nn < 64; nn += 4)
        dst[(size_t)(n0 + nn + rb) * K + k0 + c] = f2bf(t[c][nn + rb]);
}

// ---------------- pre kernel: ln1(layer 0) + QKV(layer 0) ----------------
__global__ __launch_bounds__(256) void pre_kernel(const float* __restrict__ x_,
                                                  const float* __restrict__ ln1g_,
                                                  const float* __restrict__ ln1b_,
                                                  const ushort_t* __restrict__ Wtq,
                                                  const float* __restrict__ bq_,
                                                  const ushort_t* __restrict__ Wtk,
                                                  const float* __restrict__ bk_,
                                                  const ushort_t* __restrict__ Wtv,
                                                  const float* __restrict__ bv_,
                                                  ushort_t* __restrict__ qb,
                                                  ushort_t* __restrict__ kb,
                                                  ushort_t* __restrict__ vt) {
    int m0 = blockIdx.x * 16;
    int tid = threadIdx.x;
    int wave = tid >> 6, lane = tid & 63, lq = lane & 15, quad = lane >> 4;

    __shared__ ushort_t hs[16 * 128];
    __shared__ float sred[4][16][2];

    int n0 = wave * 32;
    int c0 = n0 + lq, c1 = n0 + 16 + lq;
    float w0[4], w1[4];
    #pragma unroll
    for (int rg = 0; rg < 4; ++rg) {
        int r = m0 + quad * 4 + rg;
        w0[rg] = x_[(size_t)r * CC + c0];
        w1[rg] = x_[(size_t)r * CC + c1];
    }
    #pragma unroll
    for (int rg = 0; rg < 4; ++rg) {
        float s1 = w0[rg] + w1[rg];
        float s2 = w0[rg]*w0[rg] + w1[rg]*w1[rg];
        #pragma unroll
        for (int m = 1; m < 16; m <<= 1) {
            s1 += __shfl_xor(s1, m, 64);
            s2 += __shfl_xor(s2, m, 64);
        }
        if (lq == 0) { sred[wave][quad*4+rg][0] = s1; sred[wave][quad*4+rg][1] = s2; }
    }
    __syncthreads();
    float g0 = ln1g_[c0], g1 = ln1g_[c1], lb0 = ln1b_[c0], lb1 = ln1b_[c1];
    #pragma unroll
    for (int rg = 0; rg < 4; ++rg) {
        int row = quad * 4 + rg;
        float S1 = sred[0][row][0] + sred[1][row][0] + sred[2][row][0] + sred[3][row][0];
        float S2 = sred[0][row][1] + sred[1][row][1] + sred[2][row][1] + sred[3][row][1];
        float mn = S1 * (1.0f/CC);
        float var = S2 * (1.0f/CC) - mn * mn;
        float rs = rsqrtf(var + 1e-5f);
        hs[swz(row, c0, 128)] = f2bf((w0[rg] - mn) * rs * g0 + lb0);
        hs[swz(row, c1, 128)] = f2bf((w1[rg] - mn) * rs * g1 + lb1);
    }
    __syncthreads();
    qkv_stage(hs, Wtq, bq_, Wtk, bk_, Wtv, bv_, qb, kb, vt, m0, wave, lq, quad);
}

// ---------------- mega kernel ----------------
// o-proj + res + ln2 + ffn1 + gelu + ffn2 + res + ln1next + QKVnext (if doQKV)
// Block = one 16-row tile (grid 513), 256 thr = 4 waves (wave n0 = wave*32).
__global__ __launch_bounds__(256) void mega_kernel(const ushort_t* __restrict__ obf,
                                                   const ushort_t* __restrict__ WtO,
                                                   const float* __restrict__ bo_,
                                                   const float* __restrict__ ln2g_,
                                                   const float* __restrict__ ln2b_,
                                                   const ushort_t* __restrict__ Wt1_,
                                                   const float* __restrict__ b1_,
                                                   const ushort_t* __restrict__ Wt2_,
                                                   const float* __restrict__ b2_,
                                                   const float* __restrict__ ln1g_,
                                                   const float* __restrict__ ln1b_,
                                                   const ushort_t* __restrict__ Wtq,
                                                   const float* __restrict__ bq_,
                                                   const ushort_t* __restrict__ Wtk,
                                                   const float* __restrict__ bk_,
                                                   const ushort_t* __restrict__ Wtv,
                                                   const float* __restrict__ bv_,
                                                   float* __restrict__ x_,
                                                   ushort_t* __restrict__ qb,
                                                   ushort_t* __restrict__ kb,
                                                   ushort_t* __restrict__ vt,
                                                   int doQKV) {
    int m0 = blockIdx.x * 16;
    int tid = threadIdx.x;
    int wave = tid >> 6, lane = tid & 63, lq = lane & 15, quad = lane >> 4;

    __shared__ ushort_t hs[16 * 128];    // ln2(h) tile then ln1next tile, swizzled
    __shared__ ushort_t ms[16 * 512];    // gelu(mid) tile, swizzled
    __shared__ float sred[4][16][2];

    int n0 = wave * 32;
    int c0 = n0 + lq, c1 = n0 + 16 + lq;
    float vv0[4], vv1[4];   // o-proj residual, reused in ffn2 epilogue

    // ---- stage 1: o-proj (16x32 per wave, K=128) + res + ln2 -> hs ----
    {
        const short* Ab = (const short*)obf;
        const short* W = (const short*)WtO;
        size_t rowA = (size_t)(m0 + lq) * CC;
        size_t rB0 = (size_t)(n0 + lq) * CC, rB1 = (size_t)(n0 + 16 + lq) * CC;
        floatx4 a0 = {0.f,0.f,0.f,0.f}, a1 = a0;
        #pragma unroll
        for (int k0 = 0; k0 < CC; k0 += 32) {
            short8 af = *(const short8*)(Ab + rowA + k0 + quad * 8);
            short8 b0 = *(const short8*)(W + rB0 + k0 + quad * 8);
            short8 b1 = *(const short8*)(W + rB1 + k0 + quad * 8);
            a0 = __builtin_amdgcn_mfma_f32_16x16x32_bf16(af, b0, a0, 0, 0, 0);
            a1 = __builtin_amdgcn_mfma_f32_16x16x32_bf16(af, b1, a1, 0, 0, 0);
        }
        float bv0 = bo_[c0], bv1 = bo_[c1];
        #pragma unroll
        for (int rg = 0; rg < 4; ++rg) {
            int r = m0 + quad * 4 + rg;
            vv0[rg] = a0[rg] + bv0 + x_[(size_t)r * CC + c0];
            vv1[rg] = a1[rg] + bv1 + x_[(size_t)r * CC + c1];
        }
        #pragma unroll
        for (int rg = 0; rg < 4; ++rg) {
            float s1 = vv0[rg] + vv1[rg];
            float s2 = vv0[rg]*vv0[rg] + vv1[rg]*vv1[rg];
            #pragma unroll
            for (int m = 1; m < 16; m <<= 1) {
                s1 += __shfl_xor(s1, m, 64);
                s2 += __shfl_xor(s2, m, 64);
            }
            if (lq == 0) { sred[wave][quad*4+rg][0] = s1; sred[wave][quad*4+rg][1] = s2; }
        }
        __syncthreads();
        float g0 = ln2g_[c0], g1 = ln2g_[c1], lb0 = ln2b_[c0], lb1 = ln2b_[c1];
        #pragma unroll
        for (int rg = 0; rg < 4; ++rg) {
            int row = quad * 4 + rg;
            float S1 = sred[0][row][0] + sred[1][row][0] + sred[2][row][0] + sred[3][row][0];
            float S2 = sred[0][row][1] + sred[1][row][1] + sred[2][row][1] + sred[3][row][1];
            float mn = S1 * (1.0f/CC);
            float var = S2 * (1.0f/CC) - mn * mn;
            float rs = rsqrtf(var + 1e-5f);
            hs[swz(row, c0, 128)] = f2bf((vv0[rg] - mn) * rs * g0 + lb0);
            hs[swz(row, c1, 128)] = f2bf((vv1[rg] - mn) * rs * g1 + lb1);
        }
    }
    __syncthreads();

    // ---- stage 2: ffn1 (wave covers mid cols wave*128..+127, K=128) + gelu -> ms ----
    {
        const short* hsS = (const short*)hs;
        const short* W = (const short*)Wt1_;
        #pragma unroll
        for (int nt = 0; nt < 4; ++nt) {
            int n = wave * 128 + nt * 32;
            size_t rB0 = (size_t)(n + lq) * CC, rB1 = (size_t)(n + 16 + lq) * CC;
            floatx4 a0 = {0.f,0.f,0.f,0.f}, a1 = a0;
            #pragma unroll
            for (int k0 = 0; k0 < CC; k0 += 32) {
                short8 af = *(const short8*)(hsS + swz(lq, k0 + quad * 8, 128));
                short8 b0 = *(const short8*)(W + rB0 + k0 + quad * 8);
                short8 b1 = *(const short8*)(W + rB1 + k0 + quad * 8);
                a0 = __builtin_amdgcn_mfma_f32_16x16x32_bf16(af, b0, a0, 0, 0, 0);
                a1 = __builtin_amdgcn_mfma_f32_16x16x32_bf16(af, b1, a1, 0, 0, 0);
            }
            float bb0 = b1_[n + lq], bb1 = b1_[n + 16 + lq];
            #pragma unroll
            for (int rg = 0; rg < 4; ++rg) {
                int row = quad * 4 + rg;
                ms[swz(row, n + lq, 512)]      = f2bf(gelu_exact(a0[rg] + bb0));
                ms[swz(row, n + 16 + lq, 512)] = f2bf(gelu_exact(a1[rg] + bb1));
            }
        }
    }
    __syncthreads();

    // ---- stage 3: ffn2 (16x32 per wave, K=512 from ms) + res + ln1next -> hs ----
    {
        const short* msS = (const short*)ms;
        const short* W = (const short*)Wt2_;
        size_t rB0 = (size_t)(n0 + lq) * FFN, rB1 = (size_t)(n0 + 16 + lq) * FFN;
        floatx4 a0 = {0.f,0.f,0.f,0.f}, a1 = a0;
        #pragma unroll 4
        for (int k0 = 0; k0 < FFN; k0 += 32) {
            short8 af = *(const short8*)(msS + swz(lq, k0 + quad * 8, 512));
            short8 b0 = *(const short8*)(W + rB0 + k0 + quad * 8);
            short8 b1 = *(const short8*)(W + rB1 + k0 + quad * 8);
            a0 = __builtin_amdgcn_mfma_f32_16x16x32_bf16(af, b0, a0, 0, 0, 0);
            a1 = __builtin_amdgcn_mfma_f32_16x16x32_bf16(af, b1, a1, 0, 0, 0);
        }
        float bv0 = b2_[c0], bv1 = b2_[c1];
        float w0[4], w1[4];
        #pragma unroll
        for (int rg = 0; rg < 4; ++rg) {
            int r = m0 + quad * 4 + rg;
            w0[rg] = a0[rg] + bv0 + vv0[rg];
            w1[rg] = a1[rg] + bv1 + vv1[rg];
            x_[(size_t)r * CC + c0] = w0[rg];
            x_[(size_t)r * CC + c1] = w1[rg];
        }
        if (!doQKV) return;
        #pragma unroll
        for (int rg = 0; rg < 4; ++rg) {
            float s1 = w0[rg] + w1[rg];
            float s2 = w0[rg]*w0[rg] + w1[rg]*w1[rg];
            #pragma unroll
            for (int m = 1; m < 16; m <<= 1) {
                s1 += __shfl_xor(s1, m, 64);
                s2 += __shfl_xor(s2, m, 64);
            }
            if (lq == 0) { sred[wave][quad*4+rg][0] = s1; sred[wave][quad*4+rg][1] = s2; }
        }
        __syncthreads();
        float g0 = ln1g_[c0], g1 = ln1g_[c1], lb0 = ln1b_[c0], lb1 = ln1b_[c1];
        #pragma unroll
        for (int rg = 0; rg < 4; ++rg) {
            int row = quad * 4 + rg;
            float S1 = sred[0][row][0] + sred[1][row][0] + sred[2][row][0] + sred[3][row][0];
            float S2 = sred[0][row][1] + sred[1][row][1] + sred[2][row][1] + sred[3][row][1];
            float mn = S1 * (1.0f/CC);
            float var = S2 * (1.0f/CC) - mn * mn;
            float rs = rsqrtf(var + 1e-5f);
            hs[swz(row, c0, 128)] = f2bf((w0[rg] - mn) * rs * g0 + lb0);
            hs[swz(row, c1, 128)] = f2bf((w1[rg] - mn) * rs * g1 + lb1);
        }
    }
    __syncthreads();

    // ---- stage 4: QKV for the next layer from hs ----
    qkv_stage(hs, Wtq, bq_, Wtk, bk_, Wtv, bv_, qb, kb, vt, m0, wave, lq, quad);
}

// ---------------- MFMA fused attention: one block per (bh, 16-query tile) ----------------
__global__ __launch_bounds__(256) void attn_kernel(const ushort_t* __restrict__ qb,
                                                   const ushort_t* __restrict__ kb,
                                                   const ushort_t* __restrict__ vt,
                                                   const int* __restrict__ cnt,
                                                   const int* __restrict__ ebuf,
                                                   const float* __restrict__ ebt,
                                                   const float* __restrict__ vnode,
                                                   ushort_t* __restrict__ ob) {
    int bh = blockIdx.x;
    int qt = blockIdx.y;
    int b = bh >> 3, h = bh & (HH - 1);
    int tid = threadIdx.x;
    int wave = tid >> 6, lane = tid & 63, lq = lane & 15, quad = lane >> 4;

    __shared__ float arena[16 * BSTR];   // strip [q][s] (aliased by epilogue bufs)
    float* bstrip = arena;

    int qg = qt * 16 + lq;
    int qr = qg < TT ? qg : TT - 1;
    short8 qf = {0,0,0,0,0,0,0,0};
    if (quad < 2)
        qf = *(const short8*)(qb + ((size_t)(b * TT + qr)) * CC + h * DD + quad * 8);
    float vbh = vnode[h];
    int ql = tid >> 4, e0 = tid & 15;
    int qs = qt * 16 + ql;
    int crow = b * TT + (qs < TT ? qs : 0);
    int cn = (qs > 0 && qs < TT) ? min(cnt[crow], ECAP) : 0;

    const short* kbS = (const short*)kb;
    const short* vtS = (const short*)(vt + (size_t)bh * DD * SP);

    floatx4 oacc = {0.f, 0.f, 0.f, 0.f};
    float lsum = 0.f;

    #pragma unroll
    for (int ch = 0; ch < 2; ++ch) {
        int sp_lo = ch ? 9 : 0;
        int sp_hi = ch ? 17 : 9;
        int s_lo  = ch ? 288 : 0;
        int nrows = ch ? 256 : 288;

        int sp = sp_lo + wave;
        short8 af0 = {0,0,0,0,0,0,0,0}, af1 = af0, vf = af0;
        if (sp < sp_hi) {
            int st0 = sp * 2, st1 = sp * 2 + 1;
            int kr0 = min(b * TT + st0 * 16 + lq, (int)XROWS - 1);
            int kr1 = min(b * TT + st1 * 16 + lq, (int)XROWS - 1);
            if (quad < 2) {
                af0 = *(const short8*)(kbS + (size_t)kr0 * CC + h * DD + quad * 8);
                af1 = *(const short8*)(kbS + (size_t)kr1 * CC + h * DD + quad * 8);
            }
            vf = *(const short8*)(vtS + (size_t)lq * SP + sp * 32 + quad * 8);
        }

        for (int i = tid; i < 16 * BSTR / 4; i += 256)
            ((float4*)bstrip)[i] = make_float4(0.f, 0.f, 0.f, 0.f);
        __syncthreads();
        if (ch == 0 && tid < 16) {
            int q = qt * 16 + tid;
            if (q > 0 && q < TT) bstrip[tid * BSTR] = vbh;
        }
        for (int j = e0; j < cn; j += 16) {
            int e = ebuf[(size_t)crow * ECAP + j];
            int dl = e & 0xFFFF, a = e >> 16;
            int loc = dl - s_lo;
            if (loc >= 0 && loc < nrows)
                atomicAdd(&bstrip[ql * BSTR + loc], ebt[a * 8 + h]);
        }
        __syncthreads();

        for (; sp < sp_hi; sp += 4) {
            int spn = sp + 4;
            short8 nf0 = {0,0,0,0,0,0,0,0}, nf1 = nf0, nvf = nf0;
            if (spn < sp_hi) {
                int st0 = spn * 2, st1 = spn * 2 + 1;
                int kr0 = min(b * TT + st0 * 16 + lq, (int)XROWS - 1);
                int kr1 = min(b * TT + st1 * 16 + lq, (int)XROWS - 1);
                if (quad < 2) {
                    nf0 = *(const short8*)(kbS + (size_t)kr0 * CC + h * DD + quad * 8);
                    nf1 = *(const short8*)(kbS + (size_t)kr1 * CC + h * DD + quad * 8);
                }
                nvf = *(const short8*)(vtS + (size_t)lq * SP + spn * 32 + quad * 8);
            }

            unsigned pw[2][2];
            #pragma unroll
            for (int t = 0; t < 2; ++t) {
                int st = sp * 2 + t;
                floatx4 c = __builtin_amdgcn_mfma_f32_16x16x32_bf16(
                    t ? af1 : af0, qf, (floatx4){0.f, 0.f, 0.f, 0.f}, 0, 0, 0);
                float4 bi = *(const float4*)(bstrip + lq * BSTR + (st * 16 - s_lo) + quad * 4);
                float biv[4] = {bi.x, bi.y, bi.z, bi.w};
                float pr[4];
                #pragma unroll
                for (int rg = 0; rg < 4; ++rg) {
                    int s = st * 16 + quad * 4 + rg;
                    float p = 0.f;
                    if (s < TT) p = __expf(c[rg] + biv[rg]);
                    lsum += p;
                    pr[rg] = p;
                }
                pw[t][0] = (unsigned)f2bf(pr[0]) | ((unsigned)f2bf(pr[1]) << 16);
                pw[t][1] = (unsigned)f2bf(pr[2]) | ((unsigned)f2bf(pr[3]) << 16);
            }
            int srcA = lq + (((2 * quad) & 3) << 4);
            int srcB = lq + (((2 * quad + 1) & 3) << 4);
            int a00 = __shfl((int)pw[0][0], srcA, 64);
            int a01 = __shfl((int)pw[0][1], srcA, 64);
            int a10 = __shfl((int)pw[1][0], srcA, 64);
            int a11 = __shfl((int)pw[1][1], srcA, 64);
            int b00 = __shfl((int)pw[0][0], srcB, 64);
            int b01 = __shfl((int)pw[0][1], srcB, 64);
            int b10 = __shfl((int)pw[1][0], srcB, 64);
            int b11 = __shfl((int)pw[1][1], srcB, 64);
            union { int u[4]; short8 s8; } pu;
            bool lo = quad < 2;
            pu.u[0] = lo ? a00 : a10;
            pu.u[1] = lo ? a01 : a11;
            pu.u[2] = lo ? b00 : b10;
            pu.u[3] = lo ? b01 : b11;
            oacc = __builtin_amdgcn_mfma_f32_16x16x32_bf16(vf, pu.s8, oacc, 0, 0, 0);

            af0 = nf0; af1 = nf1; vf = nvf;
        }
        __syncthreads();
    }

    lsum += __shfl_xor(lsum, 16, 64);
    lsum += __shfl_xor(lsum, 32, 64);
    float* redw = arena;
    float* lsumS = arena + 1088;
    #pragma unroll
    for (int rg = 0; rg < 4; ++rg)
        redw[wave * 272 + (quad * 4 + rg) * 17 + lq] = oacc[rg];
    if (quad == 0) lsumS[wave * 16 + lq] = lsum;
    __syncthreads();

    {
        int q = tid >> 4, d = tid & 15;
        float o = 0.f, L = 0.f;
        #pragma unroll
        for (int w = 0; w < 4; ++w) {
            o += redw[w * 272 + d * 17 + q];
            L += lsumS[w * 16 + q];
        }
        int qq = qt * 16 + q;
        if (qq < TT)
            ob[((size_t)(b * TT + qq)) * CC + h * DD + d] = f2bf(o / L);
    }
}

// ---------------- final LN on graph tokens + classifier ----------------
__global__ __launch_bounds__(128) void head_kernel(const float* __restrict__ x,
                                                   const float* __restrict__ ng,
                                                   const float* __restrict__ nb,
                                                   const float* __restrict__ Wc1,
                                                   const float* __restrict__ bc1,
                                                   const float* __restrict__ Wc2,
                                                   const float* __restrict__ bc2,
                                                   float* __restrict__ out) {
    int b = blockIdx.x;
    int c = threadIdx.x;
    __shared__ float xfs[CC];
    __shared__ float c1s[64];
    __shared__ float red[4];

    float v = x[((size_t)b * TT) * CC + c];
    float s1 = v, s2 = v * v;
    #pragma unroll
    for (int m = 32; m >= 1; m >>= 1) {
        s1 += __shfl_xor(s1, m, 64);
        s2 += __shfl_xor(s2, m, 64);
    }
    int w = c >> 6;
    if ((c & 63) == 0) { red[w*2] = s1; red[w*2+1] = s2; }
    __syncthreads();
    float S1 = red[0] + red[2], S2 = red[1] + red[3];
    float mn = S1 * (1.0f/CC);
    float var = S2 * (1.0f/CC) - mn * mn;
    float rs = rsqrtf(var + 1e-5f);
    xfs[c] = (v - mn) * rs * ng[c] + nb[c];
    __syncthreads();
    if (c < 64) {
        float a = bc1[c];
        #pragma unroll 4
        for (int k = 0; k < CC; ++k) a = fmaf(xfs[k], Wc1[(size_t)k * 64 + c], a);
        c1s[c] = gelu_exact(a);
    }
    __syncthreads();
    if (c < NCLS) {
        float a = bc2[c];
        #pragma unroll 4
        for (int j = 0; j < 64; ++j) a = fmaf(c1s[j], Wc2[(size_t)j * NCLS + c], a);
        out[(size_t)b * NCLS + c] = a;
    }
}

extern "C" void kernel_launch(void* const* d_in, const int* in_sizes, int n_in,
                              void* d_out, int out_size, void* d_ws, size_t ws_size,
                              hipStream_t stream) {
    const float* node_feats = (const float*)d_in[0];
    const int*   edge_index = (const int*)d_in[1];
    const int*   edge_attr  = (const int*)d_in[2];
    const float* W_node  = (const float*)d_in[4];
    const float* b_node  = (const float*)d_in[5];
    const float* g_token = (const float*)d_in[6];
    const float* ebt     = (const float*)d_in[7];
    const float* ide     = (const float*)d_in[8];
    const float* ode     = (const float*)d_in[9];
    const float* vnode   = (const float*)d_in[10];
    const float* Wq = (const float*)d_in[11];
    const float* bq = (const float*)d_in[12];
    const float* Wk = (const float*)d_in[13];
    const float* bk = (const float*)d_in[14];
    const float* Wv = (const float*)d_in[15];
    const float* bv = (const float*)d_in[16];
    const float* Wo = (const float*)d_in[17];
    const float* bo = (const float*)d_in[18];
    const float* ln1g = (const float*)d_in[19];
    const float* ln1b = (const float*)d_in[20];
    const float* ln2g = (const float*)d_in[21];
    const float* ln2b = (const float*)d_in[22];
    const float* W1 = (const float*)d_in[23];
    const float* b1 = (const float*)d_in[24];
    const float* W2 = (const float*)d_in[25];
    const float* b2 = (const float*)d_in[26];
    const float* nfg = (const float*)d_in[27];
    const float* nfb = (const float*)d_in[28];
    const float* Wc1 = (const float*)d_in[29];
    const float* bc1 = (const float*)d_in[30];
    const float* Wc2 = (const float*)d_in[31];
    const float* bc2 = (const float*)d_in[32];
    float* out = (float*)d_out;

    // ---- workspace (all chunks 16B-aligned) ----
    char* base = (char*)d_ws;
    float* x      = (float*)base;     base += XSZ * 4;
    ushort_t* qb  = (ushort_t*)base;  base += XSZ * 2;
    ushort_t* kb  = (ushort_t*)base;  base += XSZ * 2;
    ushort_t* vt  = (ushort_t*)base;  base += VTSZ * 2;
    ushort_t* obf = (ushort_t*)base;  base += XSZ * 2;
    ushort_t* wtqkvo = (ushort_t*)base; base += (size_t)16 * 16384 * 2;
    ushort_t* wt1 = (ushort_t*)base;  base += (size_t)4 * 65536 * 2;
    ushort_t* wt2 = (ushort_t*)base;  base += (size_t)4 * 65536 * 2;
    int* deg_in  = (int*)base;        base += NNODES * 4;
    int* deg_out = (int*)base;        base += NNODES * 4;
    int* cnt     = (int*)base;        base += (size_t)ROWS * 4;
    int* ebuf    = (int*)base;        base += (size_t)ROWS * ECAP * 4;

    hipMemsetAsync(deg_in, 0, (size_t)(2 * NNODES + ROWS) * 4, stream);
    deg_csr_kernel<<<EE / 256, 256, 0, stream>>>(edge_index, edge_attr,
                                                 deg_in, deg_out, cnt, ebuf);
    encode_kernel<<<(int)((XROWS * CC + 255) / 256), 256, 0, stream>>>(
        node_feats, W_node, b_node, g_token, ide, ode, deg_in, deg_out, x);

    TrDesc td;
    for (int l = 0; l < LL; ++l) {
        const float* srcs[4] = {Wq + (size_t)l*CC*CC, Wk + (size_t)l*CC*CC,
                                Wv + (size_t)l*CC*CC, Wo + (size_t)l*CC*CC};
        for (int k = 0; k < 4; ++k) {
            int slot = k * 4 + l;
            td.src[slot] = srcs[k];
            td.dst[slot] = wtqkvo + (size_t)slot * 16384;
            td.K[slot] = CC; td.N[slot] = CC;
        }
        td.src[16 + l] = W1 + (size_t)l*CC*FFN;
        td.dst[16 + l] = wt1 + (size_t)l*65536;
        td.K[16 + l] = CC; td.N[16 + l] = FFN;
        td.src[20 + l] = W2 + (size_t)l*FFN*CC;
        td.dst[20 + l] = wt2 + (size_t)l*65536;
        td.K[20 + l] = FFN; td.N[20 + l] = CC;
    }
    tr_kernel<<<dim3(16, 1, 24), 256, 0, stream>>>(td);

    const int MT16 = (int)(XROWS / 16);   // 513 m-tiles of 16 rows (exact)

    // layer 0: ln1 + QKV fused
    pre_kernel<<<MT16, 256, 0, stream>>>(
        x, ln1g, ln1b,
        wtqkvo + (size_t)(0*4+0)*16384, bq,
        wtqkvo + (size_t)(1*4+0)*16384, bk,
        wtqkvo + (size_t)(2*4+0)*16384, bv,
        qb, kb, vt);

    for (int l = 0; l < LL; ++l) {
        attn_kernel<<<dim3(BB*HH, 33), 256, 0, stream>>>(
            qb, kb, vt, cnt, ebuf, ebt, vnode, obf);

        int ln = (l + 1) % LL;   // next layer (unused when l==LL-1)
        mega_kernel<<<MT16, 256, 0, stream>>>(
            obf,
            wtqkvo + (size_t)(3*4+l)*16384, bo + l*CC,
            ln2g + l*CC, ln2b + l*CC,
            wt1 + (size_t)l*65536, b1 + l*FFN,
            wt2 + (size_t)l*65536, b2 + l*CC,
            ln1g + ln*CC, ln1b + ln*CC,
            wtqkvo + (size_t)(0*4+ln)*16384, bq + ln*CC,
            wtqkvo + (size_t)(1*4+ln)*16384, bk + ln*CC,
            wtqkvo + (size_t)(2*4+ln)*16384, bv + ln*CC,
            x, qb, kb, vt,
            (l < LL-1) ? 1 : 0);
    }

    head_kernel<<<BB, 128, 0, stream>>>(x, nfg, nfb, Wc1, bc1, Wc2, bc2, out);
}